// Round 4
// baseline (7870.945 us; speedup 1.0000x reference)
//
#include <hip/hip_runtime.h>

#define T_ 2048
#define H_ 1024
#define S_ 1024
#define V_ 32000
#define I_ 2048
#define NHD 1024   // NH*HD
#define KVD 512    // NKV*HD

typedef unsigned short u16;
typedef unsigned int u32;
typedef __attribute__((ext_vector_type(8))) short s16x8;
typedef __attribute__((ext_vector_type(4))) float f32x4;

__device__ __forceinline__ u16 f2b(float f){ u32 x=__builtin_bit_cast(u32,f); return (u16)((x+0x7fffu+((x>>16)&1u))>>16); }
__device__ __forceinline__ float b2f(u16 u){ return __builtin_bit_cast(float,(u32)u<<16); }
__device__ __forceinline__ u32 pk2(float lo,float hi){ return (u32)f2b(lo)|((u32)f2b(hi)<<16); }
__device__ __forceinline__ void sp2(float a,float b,u32&h,u32&l){
  u16 ha=f2b(a), hb=f2b(b);
  float ra=a-b2f(ha), rb=b-b2f(hb);
  h=(u32)ha|((u32)hb<<16); l=(u32)f2b(ra)|((u32)f2b(rb)<<16);
}
__device__ __forceinline__ float wsum(float v){ for(int o=32;o;o>>=1) v+=__shfl_xor(v,o); return v; }
__device__ __forceinline__ float wmax(float v){ for(int o=32;o;o>>=1) v=fmaxf(v,__shfl_xor(v,o)); return v; }

// ---------------- embedding gather ----------------
__global__ void k_embed(const int* __restrict__ ids, const float* __restrict__ emb, float* __restrict__ h){
  int t = blockIdx.x;
  long src = (long)ids[t]*H_;
  ((float4*)(h + (long)t*H_))[threadIdx.x] = ((const float4*)(emb+src))[threadIdx.x];
}

// ---------------- zero expert counters ----------------
__global__ void k_zero(int* c){ if(threadIdx.x<4) c[threadIdx.x]=0; }

// ---------------- rmsnorm: fp32 -> fp32 ----------------
__global__ void k_rms(const float* __restrict__ h, const float* __restrict__ w, float* __restrict__ out){
  int wid = threadIdx.x>>6, lane = threadIdx.x&63;
  int t = blockIdx.x*4 + wid;
  const float* row = h + (long)t*H_;
  float v[16]; float ss=0.f;
  #pragma unroll
  for(int j=0;j<16;j++){ v[j]=row[j*64+lane]; ss += v[j]*v[j]; }
  ss = wsum(ss);
  float rstd = rsqrtf(ss/(float)H_ + 1e-6f);
  float* orow = out + (long)t*H_;
  #pragma unroll
  for(int j=0;j<16;j++) orow[j*64+lane] = v[j]*rstd*w[j*64+lane];
}

// ---------------- router (fp32) + expert list build ----------------
__global__ void k_router(const float* __restrict__ h, const float* __restrict__ lw,
                         const float* __restrict__ gate, float* __restrict__ comb,
                         int* __restrict__ lists, int* __restrict__ cnt){
  int wid = threadIdx.x>>6, lane = threadIdx.x&63;
  int t = blockIdx.x*4+wid;
  const float* row = h + (long)t*H_;
  float v[16]; float ss=0.f;
  #pragma unroll
  for(int j=0;j<16;j++){ v[j]=row[j*64+lane]; ss+=v[j]*v[j]; }
  ss = wsum(ss);
  float rstd = rsqrtf(ss/(float)H_+1e-6f);
  float a0=0,a1=0,a2=0,a3=0;
  #pragma unroll
  for(int j=0;j<16;j++){
    int idx=j*64+lane;
    float xv = v[j]*rstd*lw[idx];
    float4 g4 = ((const float4*)gate)[idx];
    a0 += xv*g4.x; a1 += xv*g4.y; a2 += xv*g4.z; a3 += xv*g4.w;
  }
  a0=wsum(a0); a1=wsum(a1); a2=wsum(a2); a3=wsum(a3);
  if(lane==0){
    float p[4]={a0,a1,a2,a3};
    float m = fmaxf(fmaxf(p[0],p[1]),fmaxf(p[2],p[3]));
    float s=0; for(int e=0;e<4;e++){ p[e]=__expf(p[e]-m); s+=p[e]; }
    for(int e=0;e<4;e++) p[e]/=s;
    int i1=0; for(int e=1;e<4;e++) if(p[e]>p[i1]) i1=e;
    int i2=-1; for(int e=0;e<4;e++){ if(e==i1) continue; if(i2<0||p[e]>p[i2]) i2=e; }
    float* c = comb + (long)t*4;
    for(int e=0;e<4;e++) c[e] = (e==i1||e==i2)? p[e] : 0.f;
    int p1 = atomicAdd(&cnt[i1],1); lists[i1*T_+p1]=t;
    int p2 = atomicAdd(&cnt[i2],1); lists[i2*T_+p2]=t;
  }
}

// ---------------- causal row softmax (in-place, fp32) ----------------
__global__ void k_softmax(float* __restrict__ sc){
  int wid=threadIdx.x>>6, lane=threadIdx.x&63;
  int r = blockIdx.x*4+wid;
  float* row = sc + (long)blockIdx.y*((long)S_*S_) + (long)r*S_;
  float e[16]; float mx=-3.4e38f;
  #pragma unroll
  for(int j=0;j<16;j++){ int idx=j*64+lane; float vv=row[idx]; vv = (idx<=r)? vv : -3.4e38f; e[j]=vv; mx=fmaxf(mx,vv); }
  mx = wmax(mx);
  float s=0.f;
  #pragma unroll
  for(int j=0;j<16;j++){ int idx=j*64+lane; float vv = (idx<=r)? __expf(e[j]-mx) : 0.f; e[j]=vv; s+=vv; }
  s = wsum(s);
  float inv = 1.f/s;
  #pragma unroll
  for(int j=0;j<16;j++) row[j*64+lane] = e[j]*inv;
}

// ---------------- transpose+split: fp32 [R][C] -> bf16 hi(+lo) [C][R] ----------------
__global__ void k_transpose(const float* __restrict__ in, u16* __restrict__ hi, u16* __restrict__ lo,
                            int R, int C, long zi, long zo){
  __shared__ float tile[32][33];
  in += (long)blockIdx.z*zi; hi += (long)blockIdx.z*zo; if(lo) lo += (long)blockIdx.z*zo;
  int c0 = blockIdx.x*32, r0 = blockIdx.y*32;
  int tx = threadIdx.x, ty = threadIdx.y;
  #pragma unroll
  for(int i=0;i<4;i++) tile[ty+8*i][tx] = in[(long)(r0+ty+8*i)*C + c0+tx];
  __syncthreads();
  #pragma unroll
  for(int i=0;i<4;i++){
    int cc=ty+8*i; float v = tile[tx][cc];
    u16 hv = f2b(v);
    long idx = (long)(c0+cc)*R + r0+tx;
    hi[idx] = hv;
    if(lo) lo[idx] = f2b(v - b2f(hv));
  }
}

// ---------------- elementwise split fp32 -> hi(+lo) bf16 planes ----------------
__global__ void k_split(const float* __restrict__ in, u16* __restrict__ hi, u16* __restrict__ lo){
  long i = ((long)blockIdx.x*blockDim.x + threadIdx.x)*4;
  float4 v = *(const float4*)(in+i);
  u16 h0=f2b(v.x),h1=f2b(v.y),h2=f2b(v.z),h3=f2b(v.w);
  ushort4 H; H.x=h0; H.y=h1; H.z=h2; H.w=h3;
  *(ushort4*)(hi+i)=H;
  if(lo){
    ushort4 L; L.x=f2b(v.x-b2f(h0)); L.y=f2b(v.y-b2f(h1)); L.z=f2b(v.z-b2f(h2)); L.w=f2b(v.w-b2f(h3));
    *(ushort4*)(lo+i)=L;
  }
}

// ---------------- MFMA GEMM: C[M,N] = A[M,K] * B[N,K]^T ----------------
// ABT: 0 = A fp32 (sp2-split on the fly if SPL), 1 = A bf16 plane (requires !SPL)
// SPL: bf16x2 split precision (B hi/lo planes, 3 MFMAs)
// EPI: 1=store f32*scale, 2=f32 +=, 3=silu(acc)*U -> f32 (Cp aliases U),
//      4=f32 += comb[m,e]*acc, 5=store f32 transposed [b][col][tok],
//      6=sparse scatter: h[ridx[m]] += comb[ridx[m],e]*acc
// CM : 0=none, 1=skip blocks strictly above diagonal, 2=K-limit at m0+BM (causal PV)
// GATH: 0=dense, 1=gather A rows via ridx (+store guard), 2=compact A rows (+guard/scatter)
template<int BM,int BN,int WM,int WN,int ABT,bool SPL,int EPI,int CM,int GATH>
__launch_bounds__(WM*WN*64)
__global__ void k_gemm(const void* __restrict__ Ap, const u16* __restrict__ Bhip,
                       const u16* __restrict__ Blop, void* __restrict__ Cp,
                       const void* __restrict__ auxp,
                       const int* __restrict__ ridx, const int* __restrict__ cntp,
                       int Kdim, int lda, int ldb, int ldc,
                       long zA, long zB, int zBdiv, long zC,
                       float scale, int eidx)
{
  static_assert(!(ABT==1 && SPL), "bf16-A only for non-split");
  constexpr int NT = WM*WN*64;
  constexpr int BK = 32;
  constexpr int LK = BK+8;
  constexpr int WMT = BM/WM, WNT = BN/WN;
  constexpr int MF = WMT/16, NF = WNT/16;
  constexpr int ACH = (BM*BK)/(NT*8);
  constexpr int BCH = (BN*BK)/(NT*8);
  constexpr int PL = SPL?2:1;
  static_assert(ACH>=1 && BCH>=1, "staging chunks");
  __shared__ alignas(16) u16 As[PL*BM*LK];
  __shared__ alignas(16) u16 Bs[PL*BN*LK];
  const int m0 = blockIdx.x*BM, n0 = blockIdx.y*BN;
  if (CM==1 && n0 > m0) return;
  int cnt = 0;
  if constexpr (GATH>0){ cnt = cntp[0]; if (m0 >= cnt) return; }
  const int z = blockIdx.z;
  const int tid = threadIdx.x, lane = tid&63, w = tid>>6;
  const int wr = w/WN, wc = w%WN;
  const float* Af = (const float*)Ap + (long)z*zA;
  const u16*  Ab16 = (const u16*)Ap + (long)z*zA;
  const u16*  Bh  = Bhip + (long)(z/zBdiv)*zB;
  const u16*  Bl  = SPL ? (Blop + (long)(z/zBdiv)*zB) : (const u16*)nullptr;

  f32x4 acc[MF][NF];
  #pragma unroll
  for(int i=0;i<MF;i++)
    #pragma unroll
    for(int j=0;j<NF;j++){ f32x4 zv={0.f,0.f,0.f,0.f}; acc[i][j]=zv; }

  int ktend = Kdim/BK;
  if (CM==2){ int lim=(m0+BM)/BK; if(lim<ktend) ktend=lim; }

  for(int kt=0;kt<ktend;kt++){
    const int k0 = kt*BK;
    uint4 avh[ACH], avl[ACH], bvh[BCH], bvl[BCH];
    #pragma unroll
    for(int s=0;s<ACH;s++){
      int c = s*NT+tid; int row=c>>2; int kc=(c&3)*8;
      int arow = m0+row;
      if constexpr (GATH==1){ arow = ridx[arow < cnt ? arow : cnt-1]; }
      else if constexpr (GATH==2){ arow = arow < cnt ? arow : cnt-1; }
      if constexpr (ABT==1){
        avh[s] = *(const uint4*)(Ab16 + (long)arow*lda + k0+kc);
      } else {
        const float* pA = Af + (long)arow*lda + k0+kc;
        float4 X=*(const float4*)pA, Y=*(const float4*)(pA+4);
        if constexpr (SPL){
          sp2(X.x,X.y,avh[s].x,avl[s].x); sp2(X.z,X.w,avh[s].y,avl[s].y);
          sp2(Y.x,Y.y,avh[s].z,avl[s].z); sp2(Y.z,Y.w,avh[s].w,avl[s].w);
        } else {
          avh[s].x=pk2(X.x,X.y); avh[s].y=pk2(X.z,X.w); avh[s].z=pk2(Y.x,Y.y); avh[s].w=pk2(Y.z,Y.w);
        }
      }
    }
    #pragma unroll
    for(int s=0;s<BCH;s++){
      int c = s*NT+tid; int row=c>>2; int kc=(c&3)*8;
      bvh[s] = *(const uint4*)(Bh + (long)(n0+row)*ldb + k0+kc);
      if constexpr (SPL) bvl[s] = *(const uint4*)(Bl + (long)(n0+row)*ldb + k0+kc);
    }
    __syncthreads();
    #pragma unroll
    for(int s=0;s<ACH;s++){ int c=s*NT+tid; int row=c>>2; int kc=(c&3)*8;
      *(uint4*)&As[row*LK+kc] = avh[s];
      if constexpr (SPL) *(uint4*)&As[BM*LK + row*LK+kc] = avl[s]; }
    #pragma unroll
    for(int s=0;s<BCH;s++){ int c=s*NT+tid; int row=c>>2; int kc=(c&3)*8;
      *(uint4*)&Bs[row*LK+kc] = bvh[s];
      if constexpr (SPL) *(uint4*)&Bs[BN*LK + row*LK+kc] = bvl[s]; }
    __syncthreads();
    s16x8 ah[MF], bh[NF], al[MF], bl[NF];
    const int rA = lane&15, kg=(lane>>4)*8;
    #pragma unroll
    for(int i=0;i<MF;i++){
      ah[i]=*(const s16x8*)&As[(wr*WMT+i*16+rA)*LK+kg];
      if constexpr (SPL) al[i]=*(const s16x8*)&As[BM*LK+(wr*WMT+i*16+rA)*LK+kg];
    }
    #pragma unroll
    for(int j=0;j<NF;j++){
      bh[j]=*(const s16x8*)&Bs[(wc*WNT+j*16+rA)*LK+kg];
      if constexpr (SPL) bl[j]=*(const s16x8*)&Bs[BN*LK+(wc*WNT+j*16+rA)*LK+kg];
    }
    #pragma unroll
    for(int i=0;i<MF;i++)
      #pragma unroll
      for(int j=0;j<NF;j++){
        acc[i][j]=__builtin_amdgcn_mfma_f32_16x16x32_bf16(ah[i],bh[j],acc[i][j],0,0,0);
        if constexpr (SPL){
          acc[i][j]=__builtin_amdgcn_mfma_f32_16x16x32_bf16(ah[i],bl[j],acc[i][j],0,0,0);
          acc[i][j]=__builtin_amdgcn_mfma_f32_16x16x32_bf16(al[i],bh[j],acc[i][j],0,0,0);
        }
      }
  }

  #pragma unroll
  for(int i=0;i<MF;i++){
    #pragma unroll
    for(int j=0;j<NF;j++){
      const int gm0 = m0 + wr*WMT + i*16 + ((lane>>4)<<2);
      const int gn  = n0 + wc*WNT + j*16 + (lane&15);
      #pragma unroll
      for(int r=0;r<4;r++){
        const int gm = gm0+r;
        const float v = acc[i][j][r];
        const bool live = (GATH==0) || (gm < cnt);
        if constexpr (EPI==1){
          if(live) ((float*)Cp + (long)z*zC)[(long)gm*ldc+gn] = v*scale;
        } else if constexpr (EPI==2){
          float* C = (float*)Cp; C[(long)gm*ldc+gn] += v;
        } else if constexpr (EPI==3){
          if(live){
            const float* U = (const float*)auxp;
            float sg = v/(1.f+__expf(-v));
            ((float*)Cp)[(long)gm*ldc+gn] = sg*U[(long)gm*ldc+gn];
          }
        } else if constexpr (EPI==4){
          const float* cb = (const float*)auxp;
          ((float*)Cp)[(long)gm*ldc+gn] += cb[gm*4+eidx]*v;
        } else if constexpr (EPI==5){
          ((float*)Cp)[((long)(gm>>10)<<19) + (long)gn*S_ + (gm&1023)] = v;
        } else if constexpr (EPI==6){
          if(live){
            int t = ridx[gm];
            const float* cb = (const float*)auxp;
            ((float*)Cp)[(long)t*ldc+gn] += cb[t*4+eidx]*v;
          }
        }
      }
    }
  }
}

extern "C" void kernel_launch(void* const* d_in, const int* in_sizes, int n_in,
                              void* d_out, int out_size, void* d_ws, size_t ws_size,
                              hipStream_t stream)
{
  (void)in_sizes; (void)n_in; (void)out_size;
  const int*   ids   = (const int*)d_in[0];
  const float* emb   = (const float*)d_in[1];
  const float* Wq    = (const float*)d_in[2];
  const float* Wk    = (const float*)d_in[3];
  const float* Wv    = (const float*)d_in[4];
  const float* Wo    = (const float*)d_in[5];
  const float* ln1   = (const float*)d_in[6];
  const float* ln2   = (const float*)d_in[7];
  const float* gate  = (const float*)d_in[8];
  const float* Wg    = (const float*)d_in[9];
  const float* Wu    = (const float*)d_in[10];
  const float* Wd    = (const float*)d_in[11];
  const float* normw = (const float*)d_in[12];
  const float* lmh   = (const float*)d_in[13];

  char* p = (char*)d_ws;
  auto carve = [&](size_t bytes)->void*{ void* r=p; p += (bytes+255)&~(size_t)255; return r; };
  float* h    = (float*)carve((size_t)T_*H_*4);
  float* x    = (float*)carve((size_t)T_*H_*4);
  u16*   xh   = (u16*)  carve((size_t)T_*H_*2);
  float* q    = (float*)carve((size_t)T_*NHD*4);
  float* kf   = (float*)carve((size_t)T_*KVD*4);
  u16*   khi  = (u16*)  carve((size_t)T_*KVD*2);
  u16*   klo  = (u16*)  carve((size_t)T_*KVD*2);
  float* vT   = (float*)carve((size_t)T_*KVD*4);
  u16*   vthi = (u16*)  carve((size_t)T_*KVD*2);
  u16*   vtlo = (u16*)  carve((size_t)T_*KVD*2);
  float* o    = (float*)carve((size_t)T_*NHD*4);
  float* sc   = (float*)carve((size_t)8*S_*S_*4);
  float* comb = (float*)carve((size_t)T_*4*4);
  int*   cnt  = (int*)  carve((size_t)4*4);
  int*   lists= (int*)  carve((size_t)4*T_*4);
  float* gu   = (float*)carve((size_t)T_*I_*4);
  u16*   wp   = (u16*)  carve((size_t)56623104*2);   // weight hi/lo planes (also reused for lm_head)
  if ((size_t)(p - (char*)d_ws) > ws_size) return;

  u16 *WqTh = wp,            *WqTl = wp+1048576;
  u16 *WkTh = wp+2097152,    *WkTl = wp+2621440;
  u16 *WvTh = wp+3145728,    *WvTl = wp+3670016;
  u16 *WoTh = wp+4194304,    *WoTl = wp+5242880;
  u16 *WgTh = wp+6291456,    *WgTl = wp+14680064;
  u16 *WuTh = wp+23068672,   *WuTl = wp+31457280;
  u16 *WdTh = wp+39845888,   *WdTl = wp+48234496;

  dim3 tb(32,8);

  k_embed<<<T_,256,0,stream>>>(ids, emb, h);

  for(int l=0;l<4;l++){
    k_transpose<<<dim3(32,32),tb,0,stream>>>(Wq+(size_t)l*H_*NHD, WqTh, WqTl, H_, NHD, 0,0);
    k_transpose<<<dim3(16,32),tb,0,stream>>>(Wk+(size_t)l*H_*KVD, WkTh, WkTl, H_, KVD, 0,0);
    k_transpose<<<dim3(16,32),tb,0,stream>>>(Wv+(size_t)l*H_*KVD, WvTh, WvTl, H_, KVD, 0,0);
    k_transpose<<<dim3(32,32),tb,0,stream>>>(Wo+(size_t)l*NHD*H_, WoTh, WoTl, NHD, H_, 0,0);
    k_transpose<<<dim3(64,32,4),tb,0,stream>>>(Wg+(size_t)l*4*H_*I_, WgTh, WgTl, H_, I_, (long)H_*I_, (long)I_*H_);
    k_transpose<<<dim3(64,32,4),tb,0,stream>>>(Wu+(size_t)l*4*H_*I_, WuTh, WuTl, H_, I_, (long)H_*I_, (long)I_*H_);
    k_transpose<<<dim3(32,64,4),tb,0,stream>>>(Wd+(size_t)l*4*I_*H_, WdTh, WdTl, I_, H_, (long)I_*H_, (long)H_*I_);

    k_rms<<<T_/4,256,0,stream>>>(h, ln1+(size_t)l*H_, x);

    // QKV projections, split precision, fp32 outputs
    k_gemm<128,128,2,2,0,true,1,0,0><<<dim3(16,8,1),256,0,stream>>>(x, WqTh, WqTl, q, nullptr, nullptr, nullptr, H_, H_,H_,NHD, 0,0,1,0, 1.f,0);
    k_gemm<128,128,2,2,0,true,1,0,0><<<dim3(16,4,1),256,0,stream>>>(x, WkTh, WkTl, kf, nullptr, nullptr, nullptr, H_, H_,H_,KVD, 0,0,1,0, 1.f,0);
    k_gemm<128,128,2,2,0,true,5,0,0><<<dim3(16,4,1),256,0,stream>>>(x, WvTh, WvTl, vT, nullptr, nullptr, nullptr, H_, H_,H_,KVD, 0,0,1,0, 0.f,0);
    k_split<<<1024,256,0,stream>>>(kf, khi, klo);
    k_split<<<1024,256,0,stream>>>(vT, vthi, vtlo);

    for(int c=0;c<4;c++){
      int b = c>>1, qb=(c&1)*8, kb=qb>>1;
      const float* Aq = q + (size_t)b*S_*NHD + (size_t)qb*64;
      const u16* Bkh = khi + (size_t)b*S_*KVD + (size_t)kb*64;
      const u16* Bkl = klo + (size_t)b*S_*KVD + (size_t)kb*64;
      k_gemm<128,128,2,2,0,true,1,1,0><<<dim3(8,8,8),256,0,stream>>>(Aq, Bkh, Bkl, sc, nullptr, nullptr, nullptr, 64, NHD, KVD, S_, 64, 64, 2, (long)S_*S_, 0.125f, 0);
      k_softmax<<<dim3(256,8),256,0,stream>>>(sc);
      const u16* Bvh = vthi + (size_t)b*S_*KVD + (size_t)kb*64*S_;
      const u16* Bvl = vtlo + (size_t)b*S_*KVD + (size_t)kb*64*S_;
      float* Co = o + (size_t)b*S_*NHD + (size_t)qb*64;
      k_gemm<128,64,2,2,0,true,1,2,0><<<dim3(8,1,8),256,0,stream>>>(sc, Bvh, Bvl, Co, nullptr, nullptr, nullptr, S_, S_, S_, NHD, (long)S_*S_, (long)64*S_, 2, 64, 1.f, 0);
    }

    // o @ Wo += h
    k_gemm<128,128,2,2,0,true,2,0,0><<<dim3(16,8,1),256,0,stream>>>(o, WoTh, WoTl, h, nullptr, nullptr, nullptr, NHD, NHD,NHD,H_, 0,0,1,0, 0.f,0);

    k_zero<<<1,64,0,stream>>>(cnt);
    k_router<<<T_/4,256,0,stream>>>(h, ln2+(size_t)l*H_, gate+(size_t)l*H_*4, comb, lists, cnt);
    k_rms<<<T_/4,256,0,stream>>>(h, ln2+(size_t)l*H_, x);

    for(int e=0;e<4;e++){
      size_t eo = (size_t)e*H_*I_;
      const int* ridx = lists + (size_t)e*T_;
      // u: gather x rows -> gu (compact)
      k_gemm<128,128,2,2,0,true,1,0,1><<<dim3(16,16,1),256,0,stream>>>(x, WuTh+eo, WuTl+eo, gu, nullptr, ridx, cnt+e, H_, H_,H_,I_, 0,0,1,0, 1.f,0);
      // g: silu(g)*u in place (compact)
      k_gemm<128,128,2,2,0,true,3,0,1><<<dim3(16,16,1),256,0,stream>>>(x, WgTh+eo, WgTl+eo, gu, gu, ridx, cnt+e, H_, H_,H_,I_, 0,0,1,0, 0.f,0);
      // d: compact A -> scatter-add into h with comb weights
      k_gemm<128,128,2,2,0,true,6,0,2><<<dim3(16,8,1),256,0,stream>>>(gu, WdTh+eo, WdTl+eo, h, comb, ridx, cnt+e, I_, I_,I_,H_, 0,0,1,0, 0.f,e);
    }
  }

  k_rms<<<T_/4,256,0,stream>>>(h, normw, x);
  k_split<<<2048,256,0,stream>>>(x, xh, nullptr);
  k_transpose<<<dim3(1000,32),tb,0,stream>>>(lmh, wp, nullptr, H_, V_, 0,0);
  k_gemm<128,128,2,2,1,false,1,0,0><<<dim3(16,250,1),256,0,stream>>>(xh, wp, nullptr, (float*)d_out, nullptr, nullptr, nullptr, H_, H_,H_,V_, 0,0,1,0, 1.f,0);
}

// Round 5
// 5525.375 us; speedup vs baseline: 1.4245x; 1.4245x over previous
//
#include <hip/hip_runtime.h>

#define T_ 2048
#define H_ 1024
#define S_ 1024
#define V_ 32000
#define I_ 2048
#define NHD 1024   // NH*HD
#define KVD 512    // NKV*HD

typedef unsigned short u16;
typedef unsigned int u32;
typedef __attribute__((ext_vector_type(8))) short s16x8;
typedef __attribute__((ext_vector_type(4))) float f32x4;

__device__ __forceinline__ u16 f2b(float f){ u32 x=__builtin_bit_cast(u32,f); return (u16)((x+0x7fffu+((x>>16)&1u))>>16); }
__device__ __forceinline__ float b2f(u16 u){ return __builtin_bit_cast(float,(u32)u<<16); }
__device__ __forceinline__ u32 pk2(float lo,float hi){ return (u32)f2b(lo)|((u32)f2b(hi)<<16); }
__device__ __forceinline__ void sp2(float a,float b,u32&h,u32&l){
  u16 ha=f2b(a), hb=f2b(b);
  float ra=a-b2f(ha), rb=b-b2f(hb);
  h=(u32)ha|((u32)hb<<16); l=(u32)f2b(ra)|((u32)f2b(rb)<<16);
}
__device__ __forceinline__ float wsum(float v){ for(int o=32;o;o>>=1) v+=__shfl_xor(v,o); return v; }
__device__ __forceinline__ float wmax(float v){ for(int o=32;o;o>>=1) v=fmaxf(v,__shfl_xor(v,o)); return v; }

// ---------------- embedding gather ----------------
__global__ void k_embed(const int* __restrict__ ids, const float* __restrict__ emb, float* __restrict__ h){
  int t = blockIdx.x;
  long src = (long)ids[t]*H_;
  ((float4*)(h + (long)t*H_))[threadIdx.x] = ((const float4*)(emb+src))[threadIdx.x];
}

__global__ void k_zero(int* c){ if(threadIdx.x<4) c[threadIdx.x]=0; }

// ---------------- rmsnorm: fp32 -> fp32 ----------------
__global__ void k_rms(const float* __restrict__ h, const float* __restrict__ w, float* __restrict__ out){
  int wid = threadIdx.x>>6, lane = threadIdx.x&63;
  int t = blockIdx.x*4 + wid;
  const float* row = h + (long)t*H_;
  float v[16]; float ss=0.f;
  #pragma unroll
  for(int j=0;j<16;j++){ v[j]=row[j*64+lane]; ss += v[j]*v[j]; }
  ss = wsum(ss);
  float rstd = rsqrtf(ss/(float)H_ + 1e-6f);
  float* orow = out + (long)t*H_;
  #pragma unroll
  for(int j=0;j<16;j++) orow[j*64+lane] = v[j]*rstd*w[j*64+lane];
}

// ---------------- rmsnorm: fp32 -> bf16 hi/lo planes ----------------
__global__ void k_rms_sp(const float* __restrict__ h, const float* __restrict__ w,
                         u16* __restrict__ xhi, u16* __restrict__ xlo){
  int wid = threadIdx.x>>6, lane = threadIdx.x&63;
  int t = blockIdx.x*4 + wid;
  const float* row = h + (long)t*H_;
  float v[16]; float ss=0.f;
  #pragma unroll
  for(int j=0;j<16;j++){ v[j]=row[j*64+lane]; ss += v[j]*v[j]; }
  ss = wsum(ss);
  float rstd = rsqrtf(ss/(float)H_ + 1e-6f);
  #pragma unroll
  for(int j=0;j<16;j++){
    int idx=j*64+lane;
    float y = v[j]*rstd*w[idx];
    u16 hv = f2b(y);
    xhi[(long)t*H_+idx] = hv;
    xlo[(long)t*H_+idx] = f2b(y - b2f(hv));
  }
}

// ---------------- router (fp32) + expert list build ----------------
__global__ void k_router(const float* __restrict__ h, const float* __restrict__ lw,
                         const float* __restrict__ gate, float* __restrict__ comb,
                         int* __restrict__ lists, int* __restrict__ cnt, int2* __restrict__ epos){
  int wid = threadIdx.x>>6, lane = threadIdx.x&63;
  int t = blockIdx.x*4+wid;
  const float* row = h + (long)t*H_;
  float v[16]; float ss=0.f;
  #pragma unroll
  for(int j=0;j<16;j++){ v[j]=row[j*64+lane]; ss+=v[j]*v[j]; }
  ss = wsum(ss);
  float rstd = rsqrtf(ss/(float)H_+1e-6f);
  float a0=0,a1=0,a2=0,a3=0;
  #pragma unroll
  for(int j=0;j<16;j++){
    int idx=j*64+lane;
    float xv = v[j]*rstd*lw[idx];
    float4 g4 = ((const float4*)gate)[idx];
    a0 += xv*g4.x; a1 += xv*g4.y; a2 += xv*g4.z; a3 += xv*g4.w;
  }
  a0=wsum(a0); a1=wsum(a1); a2=wsum(a2); a3=wsum(a3);
  if(lane==0){
    float p[4]={a0,a1,a2,a3};
    float m = fmaxf(fmaxf(p[0],p[1]),fmaxf(p[2],p[3]));
    float s=0; for(int e=0;e<4;e++){ p[e]=__expf(p[e]-m); s+=p[e]; }
    for(int e=0;e<4;e++) p[e]/=s;
    int i1=0; for(int e=1;e<4;e++) if(p[e]>p[i1]) i1=e;
    int i2=-1; for(int e=0;e<4;e++){ if(e==i1) continue; if(i2<0||p[e]>p[i2]) i2=e; }
    float* c = comb + (long)t*4;
    for(int e=0;e<4;e++) c[e] = (e==i1||e==i2)? p[e] : 0.f;
    int p1 = atomicAdd(&cnt[i1],1); lists[i1*T_+p1]=t;
    int p2 = atomicAdd(&cnt[i2],1); lists[i2*T_+p2]=t;
    epos[t] = make_int2((p1<<2)|i1, (p2<<2)|i2);
  }
}

// ---------------- causal row softmax (in-place, fp32) ----------------
__global__ void k_softmax(float* __restrict__ sc){
  int wid=threadIdx.x>>6, lane=threadIdx.x&63;
  int r = blockIdx.x*4+wid;
  float* row = sc + (long)blockIdx.y*((long)S_*S_) + (long)r*S_;
  float e[16]; float mx=-3.4e38f;
  #pragma unroll
  for(int j=0;j<16;j++){ int idx=j*64+lane; float vv=row[idx]; vv = (idx<=r)? vv : -3.4e38f; e[j]=vv; mx=fmaxf(mx,vv); }
  mx = wmax(mx);
  float s=0.f;
  #pragma unroll
  for(int j=0;j<16;j++){ int idx=j*64+lane; float vv = (idx<=r)? __expf(e[j]-mx) : 0.f; e[j]=vv; s+=vv; }
  s = wsum(s);
  float inv = 1.f/s;
  #pragma unroll
  for(int j=0;j<16;j++) row[j*64+lane] = e[j]*inv;
}

// ---------------- transpose+split: fp32 [R][C] -> bf16 hi(+lo) [C][R] ----------------
__global__ void k_transpose(const float* __restrict__ in, u16* __restrict__ hi, u16* __restrict__ lo,
                            int R, int C, long zi, long zo){
  __shared__ float tile[32][33];
  in += (long)blockIdx.z*zi; hi += (long)blockIdx.z*zo; if(lo) lo += (long)blockIdx.z*zo;
  int c0 = blockIdx.x*32, r0 = blockIdx.y*32;
  int tx = threadIdx.x, ty = threadIdx.y;
  #pragma unroll
  for(int i=0;i<4;i++) tile[ty+8*i][tx] = in[(long)(r0+ty+8*i)*C + c0+tx];
  __syncthreads();
  #pragma unroll
  for(int i=0;i<4;i++){
    int cc=ty+8*i; float v = tile[tx][cc];
    u16 hv = f2b(v);
    long idx = (long)(c0+cc)*R + r0+tx;
    hi[idx] = hv;
    if(lo) lo[idx] = f2b(v - b2f(hv));
  }
}

// ---------------- elementwise split fp32 -> hi/lo bf16 planes ----------------
__global__ void k_split(const float* __restrict__ in, u16* __restrict__ hi, u16* __restrict__ lo){
  long i = ((long)blockIdx.x*blockDim.x + threadIdx.x)*4;
  float4 v = *(const float4*)(in+i);
  u16 h0=f2b(v.x),h1=f2b(v.y),h2=f2b(v.z),h3=f2b(v.w);
  ushort4 H; H.x=h0; H.y=h1; H.z=h2; H.w=h3;
  *(ushort4*)(hi+i)=H;
  ushort4 L; L.x=f2b(v.x-b2f(h0)); L.y=f2b(v.y-b2f(h1)); L.z=f2b(v.z-b2f(h2)); L.w=f2b(v.w-b2f(h3));
  *(ushort4*)(lo+i)=L;
}

// ---------------- MoE combine: h[t] += c1*eo[e1,p1] + c2*eo[e2,p2] ----------------
__global__ void k_combine(float* __restrict__ h, const float* __restrict__ eo,
                          const int2* __restrict__ epos, const float* __restrict__ comb){
  int t = blockIdx.x, c = threadIdx.x;
  int2 ep = epos[t];
  int e1 = ep.x&3, p1 = ep.x>>2, e2 = ep.y&3, p2 = ep.y>>2;
  float c1 = comb[t*4+e1], c2 = comb[t*4+e2];
  float4 a = ((const float4*)(eo + (long)(e1*T_+p1)*H_))[c];
  float4 b = ((const float4*)(eo + (long)(e2*T_+p2)*H_))[c];
  float4* hp = (float4*)(h + (long)t*H_) + c;
  float4 hv = *hp;
  hv.x += c1*a.x + c2*b.x; hv.y += c1*a.y + c2*b.y;
  hv.z += c1*a.z + c2*b.z; hv.w += c1*a.w + c2*b.w;
  *hp = hv;
}

// ---------------- fused MoE up+gate: silu(x@Wg)*(x@Wu) -> gu (compact per expert) ----------------
__global__ void k_moe_ug(const u16* __restrict__ xhi, const u16* __restrict__ xlo,
                         const u16* __restrict__ Wuh, const u16* __restrict__ Wul,
                         const u16* __restrict__ Wgh, const u16* __restrict__ Wgl,
                         float* __restrict__ gu,
                         const int* __restrict__ lists, const int* __restrict__ cntp)
{
  constexpr int BM=128, BN=64, BK=32, LK=BK+8, NT=256;
  const int e = blockIdx.x>>4, m0=(blockIdx.x&15)*BM;
  const int ce = cntp[e];
  if(m0>=ce) return;
  const int n0 = blockIdx.y*BN;
  const int* ridx = lists + e*T_;
  const u16* Buh_g = Wuh + (size_t)e*H_*I_;
  const u16* Bul_g = Wul + (size_t)e*H_*I_;
  const u16* Bgh_g = Wgh + (size_t)e*H_*I_;
  const u16* Bgl_g = Wgl + (size_t)e*H_*I_;
  __shared__ alignas(16) u16 Ah[BM*LK], Al[BM*LK];
  __shared__ alignas(16) u16 Buh[BN*LK], Bul[BN*LK], Bgh[BN*LK], Bgl[BN*LK];
  const int tid=threadIdx.x, lane=tid&63, w=tid>>6;
  const int wr=w>>1, wc=w&1;
  int ar[2];
  #pragma unroll
  for(int s=0;s<2;s++){ int idx=m0 + ((s*NT+tid)>>2); ar[s]=ridx[idx<ce?idx:ce-1]; }
  const int brow = tid>>2;
  const int kc = (tid&3)*8;
  f32x4 au[4][2], ag[4][2];
  #pragma unroll
  for(int i=0;i<4;i++)
    #pragma unroll
    for(int j=0;j<2;j++){ f32x4 zv={0.f,0.f,0.f,0.f}; au[i][j]=zv; ag[i][j]=zv; }

  for(int kt=0;kt<H_/BK;kt++){
    const int k0=kt*BK;
    uint4 a_h[2],a_l[2],bu0,bu1,bg0,bg1;
    #pragma unroll
    for(int s=0;s<2;s++){
      a_h[s]=*(const uint4*)(xhi + (long)ar[s]*H_ + k0+kc);
      a_l[s]=*(const uint4*)(xlo + (long)ar[s]*H_ + k0+kc);
    }
    bu0=*(const uint4*)(Buh_g + (long)(n0+brow)*H_ + k0+kc);
    bu1=*(const uint4*)(Bul_g + (long)(n0+brow)*H_ + k0+kc);
    bg0=*(const uint4*)(Bgh_g + (long)(n0+brow)*H_ + k0+kc);
    bg1=*(const uint4*)(Bgl_g + (long)(n0+brow)*H_ + k0+kc);
    __syncthreads();
    #pragma unroll
    for(int s=0;s<2;s++){
      int row=(s*NT+tid)>>2;
      *(uint4*)&Ah[row*LK+kc]=a_h[s];
      *(uint4*)&Al[row*LK+kc]=a_l[s];
    }
    *(uint4*)&Buh[brow*LK+kc]=bu0; *(uint4*)&Bul[brow*LK+kc]=bu1;
    *(uint4*)&Bgh[brow*LK+kc]=bg0; *(uint4*)&Bgl[brow*LK+kc]=bg1;
    __syncthreads();
    s16x8 fah[4],fal[4],fbuh[2],fbul[2],fbgh[2],fbgl[2];
    const int rA=lane&15, kg=(lane>>4)*8;
    #pragma unroll
    for(int i=0;i<4;i++){
      fah[i]=*(const s16x8*)&Ah[(wr*64+i*16+rA)*LK+kg];
      fal[i]=*(const s16x8*)&Al[(wr*64+i*16+rA)*LK+kg];
    }
    #pragma unroll
    for(int j=0;j<2;j++){
      fbuh[j]=*(const s16x8*)&Buh[(wc*32+j*16+rA)*LK+kg];
      fbul[j]=*(const s16x8*)&Bul[(wc*32+j*16+rA)*LK+kg];
      fbgh[j]=*(const s16x8*)&Bgh[(wc*32+j*16+rA)*LK+kg];
      fbgl[j]=*(const s16x8*)&Bgl[(wc*32+j*16+rA)*LK+kg];
    }
    #pragma unroll
    for(int i=0;i<4;i++)
      #pragma unroll
      for(int j=0;j<2;j++){
        au[i][j]=__builtin_amdgcn_mfma_f32_16x16x32_bf16(fah[i],fbuh[j],au[i][j],0,0,0);
        au[i][j]=__builtin_amdgcn_mfma_f32_16x16x32_bf16(fah[i],fbul[j],au[i][j],0,0,0);
        au[i][j]=__builtin_amdgcn_mfma_f32_16x16x32_bf16(fal[i],fbuh[j],au[i][j],0,0,0);
        ag[i][j]=__builtin_amdgcn_mfma_f32_16x16x32_bf16(fah[i],fbgh[j],ag[i][j],0,0,0);
        ag[i][j]=__builtin_amdgcn_mfma_f32_16x16x32_bf16(fah[i],fbgl[j],ag[i][j],0,0,0);
        ag[i][j]=__builtin_amdgcn_mfma_f32_16x16x32_bf16(fal[i],fbgh[j],ag[i][j],0,0,0);
      }
  }

  #pragma unroll
  for(int i=0;i<4;i++){
    #pragma unroll
    for(int j=0;j<2;j++){
      const int gm0 = m0 + wr*64 + i*16 + ((lane>>4)<<2);
      const int gn  = n0 + wc*32 + j*16 + (lane&15);
      #pragma unroll
      for(int r=0;r<4;r++){
        const int gm = gm0+r;
        if(gm<ce){
          float uu=au[i][j][r], gg=ag[i][j][r];
          float sg = gg/(1.f+__expf(-gg));
          gu[(long)(e*T_+gm)*I_ + gn] = sg*uu;
        }
      }
    }
  }
}

// ---------------- MFMA GEMM: C[M,N] = A[M,K] * B[N,K]^T ----------------
// ABT: 0 = A fp32 (sp2-split on the fly if SPL), 2 = A bf16 hi/lo planes (requires SPL)
// SPL: bf16x2 split precision (B hi/lo planes, 3 MFMAs)
// EPI: 1=store f32*scale, 2=f32 +=, 5=store f32 transposed [b][col][tok],
//      7=store f32 compact per expert slot: eo[(e*T+gm)*ldc+gn]
// CM : 0=none, 1=skip blocks strictly above diagonal, 2=K-limit at m0+BM (causal PV)
// GATH: 0=dense, 3=expert-slot mode (bid.x -> (e,mslot); A compact rows, clamp; B += e*zB)
template<int BM,int BN,int WM,int WN,int ABT,bool SPL,int EPI,int CM,int GATH>
__launch_bounds__(WM*WN*64)
__global__ void k_gemm(const void* __restrict__ Ap, const void* __restrict__ A2p,
                       const u16* __restrict__ Bhip, const u16* __restrict__ Blop,
                       void* __restrict__ Cp, const void* __restrict__ auxp,
                       const int* __restrict__ ridxp, const int* __restrict__ cntp,
                       int Kdim, int lda, int ldb, int ldc,
                       long zA, long zB, int zBdiv, long zC,
                       float scale, int eidx)
{
  static_assert(!(ABT==2 && !SPL), "plane-A requires split");
  constexpr int NT = WM*WN*64;
  constexpr int BK = 32;
  constexpr int LK = BK+8;
  constexpr int WMT = BM/WM, WNT = BN/WN;
  constexpr int MF = WMT/16, NF = WNT/16;
  constexpr int ACH = (BM*BK)/(NT*8);
  constexpr int BCH = (BN*BK)/(NT*8);
  constexpr int PL = SPL?2:1;
  static_assert(ACH>=1 && BCH>=1, "staging chunks");
  __shared__ alignas(16) u16 As[PL*BM*LK];
  __shared__ alignas(16) u16 Bs[PL*BN*LK];
  int m0, eid_ = eidx, cnt = 0;
  if constexpr (GATH==3){
    eid_ = blockIdx.x>>4; m0 = (blockIdx.x&15)*BM;
    cnt = cntp[eid_]; if(m0>=cnt) return;
  } else {
    m0 = blockIdx.x*BM;
  }
  const int n0 = blockIdx.y*BN;
  if (CM==1 && n0 > m0) return;
  const int z = blockIdx.z;
  const int tid = threadIdx.x, lane = tid&63, w = tid>>6;
  const int wr = w/WN, wc = w%WN;
  const float* Af = (const float*)Ap + (long)z*zA + (GATH==3 ? (long)eid_*T_*lda : 0);
  const u16*  Ahi = (const u16*)Ap + (long)z*zA;
  const u16*  Alo = (const u16*)A2p + (long)z*zA;
  const u16*  Bh  = Bhip + (long)(z/zBdiv)*zB + (GATH==3 ? (long)eid_*zB : 0);
  const u16*  Bl  = SPL ? (Blop + (long)(z/zBdiv)*zB + (GATH==3 ? (long)eid_*zB : 0)) : (const u16*)nullptr;

  f32x4 acc[MF][NF];
  #pragma unroll
  for(int i=0;i<MF;i++)
    #pragma unroll
    for(int j=0;j<NF;j++){ f32x4 zv={0.f,0.f,0.f,0.f}; acc[i][j]=zv; }

  int ktend = Kdim/BK;
  if (CM==2){ int lim=(m0+BM)/BK; if(lim<ktend) ktend=lim; }

  for(int kt=0;kt<ktend;kt++){
    const int k0 = kt*BK;
    uint4 avh[ACH], avl[ACH], bvh[BCH], bvl[BCH];
    #pragma unroll
    for(int s=0;s<ACH;s++){
      int c = s*NT+tid; int row=c>>2; int kc=(c&3)*8;
      int arow = m0+row;
      if constexpr (GATH==3){ arow = arow < cnt ? arow : cnt-1; }
      if constexpr (ABT==2){
        avh[s] = *(const uint4*)(Ahi + (long)arow*lda + k0+kc);
        avl[s] = *(const uint4*)(Alo + (long)arow*lda + k0+kc);
      } else {
        const float* pA = Af + (long)arow*lda + k0+kc;
        float4 X=*(const float4*)pA, Y=*(const float4*)(pA+4);
        if constexpr (SPL){
          sp2(X.x,X.y,avh[s].x,avl[s].x); sp2(X.z,X.w,avh[s].y,avl[s].y);
          sp2(Y.x,Y.y,avh[s].z,avl[s].z); sp2(Y.z,Y.w,avh[s].w,avl[s].w);
        } else {
          avh[s].x=pk2(X.x,X.y); avh[s].y=pk2(X.z,X.w); avh[s].z=pk2(Y.x,Y.y); avh[s].w=pk2(Y.z,Y.w);
        }
      }
    }
    #pragma unroll
    for(int s=0;s<BCH;s++){
      int c = s*NT+tid; int row=c>>2; int kc=(c&3)*8;
      bvh[s] = *(const uint4*)(Bh + (long)(n0+row)*ldb + k0+kc);
      if constexpr (SPL) bvl[s] = *(const uint4*)(Bl + (long)(n0+row)*ldb + k0+kc);
    }
    __syncthreads();
    #pragma unroll
    for(int s=0;s<ACH;s++){ int c=s*NT+tid; int row=c>>2; int kc=(c&3)*8;
      *(uint4*)&As[row*LK+kc] = avh[s];
      if constexpr (SPL) *(uint4*)&As[BM*LK + row*LK+kc] = avl[s]; }
    #pragma unroll
    for(int s=0;s<BCH;s++){ int c=s*NT+tid; int row=c>>2; int kc=(c&3)*8;
      *(uint4*)&Bs[row*LK+kc] = bvh[s];
      if constexpr (SPL) *(uint4*)&Bs[BN*LK + row*LK+kc] = bvl[s]; }
    __syncthreads();
    s16x8 ah[MF], bh[NF], al[MF], bl[NF];
    const int rA = lane&15, kg=(lane>>4)*8;
    #pragma unroll
    for(int i=0;i<MF;i++){
      ah[i]=*(const s16x8*)&As[(wr*WMT+i*16+rA)*LK+kg];
      if constexpr (SPL) al[i]=*(const s16x8*)&As[BM*LK+(wr*WMT+i*16+rA)*LK+kg];
    }
    #pragma unroll
    for(int j=0;j<NF;j++){
      bh[j]=*(const s16x8*)&Bs[(wc*WNT+j*16+rA)*LK+kg];
      if constexpr (SPL) bl[j]=*(const s16x8*)&Bs[BN*LK+(wc*WNT+j*16+rA)*LK+kg];
    }
    #pragma unroll
    for(int i=0;i<MF;i++)
      #pragma unroll
      for(int j=0;j<NF;j++){
        acc[i][j]=__builtin_amdgcn_mfma_f32_16x16x32_bf16(ah[i],bh[j],acc[i][j],0,0,0);
        if constexpr (SPL){
          acc[i][j]=__builtin_amdgcn_mfma_f32_16x16x32_bf16(ah[i],bl[j],acc[i][j],0,0,0);
          acc[i][j]=__builtin_amdgcn_mfma_f32_16x16x32_bf16(al[i],bh[j],acc[i][j],0,0,0);
        }
      }
  }

  #pragma unroll
  for(int i=0;i<MF;i++){
    #pragma unroll
    for(int j=0;j<NF;j++){
      const int gm0 = m0 + wr*WMT + i*16 + ((lane>>4)<<2);
      const int gn  = n0 + wc*WNT + j*16 + (lane&15);
      #pragma unroll
      for(int r=0;r<4;r++){
        const int gm = gm0+r;
        const float v = acc[i][j][r];
        const bool live = (GATH==0) || (gm < cnt);
        if constexpr (EPI==1){
          if(live) ((float*)Cp + (long)z*zC)[(long)gm*ldc+gn] = v*scale;
        } else if constexpr (EPI==2){
          float* C = (float*)Cp; C[(long)gm*ldc+gn] += v;
        } else if constexpr (EPI==5){
          ((float*)Cp)[((long)(gm>>10)<<19) + (long)gn*S_ + (gm&1023)] = v;
        } else if constexpr (EPI==7){
          if(live) ((float*)Cp)[(long)(eid_*T_+gm)*ldc+gn] = v*scale;
        }
      }
    }
  }
}

extern "C" void kernel_launch(void* const* d_in, const int* in_sizes, int n_in,
                              void* d_out, int out_size, void* d_ws, size_t ws_size,
                              hipStream_t stream)
{
  (void)in_sizes; (void)n_in; (void)out_size;
  const int*   ids   = (const int*)d_in[0];
  const float* emb   = (const float*)d_in[1];
  const float* Wq    = (const float*)d_in[2];
  const float* Wk    = (const float*)d_in[3];
  const float* Wv    = (const float*)d_in[4];
  const float* Wo    = (const float*)d_in[5];
  const float* ln1   = (const float*)d_in[6];
  const float* ln2   = (const float*)d_in[7];
  const float* gate  = (const float*)d_in[8];
  const float* Wg    = (const float*)d_in[9];
  const float* Wu    = (const float*)d_in[10];
  const float* Wd    = (const float*)d_in[11];
  const float* normw = (const float*)d_in[12];
  const float* lmh   = (const float*)d_in[13];

  char* p = (char*)d_ws;
  auto carve = [&](size_t bytes)->void*{ void* r=p; p += (bytes+255)&~(size_t)255; return r; };
  float* h    = (float*)carve((size_t)T_*H_*4);
  float* x    = (float*)carve((size_t)T_*H_*4);
  u16*   xhi  = (u16*)  carve((size_t)T_*H_*2);
  u16*   xlo  = (u16*)  carve((size_t)T_*H_*2);
  float* q    = (float*)carve((size_t)T_*NHD*4);
  float* kf   = (float*)carve((size_t)T_*KVD*4);
  u16*   khi  = (u16*)  carve((size_t)T_*KVD*2);
  u16*   klo  = (u16*)  carve((size_t)T_*KVD*2);
  float* vT   = (float*)carve((size_t)T_*KVD*4);
  u16*   vthi = (u16*)  carve((size_t)T_*KVD*2);
  u16*   vtlo = (u16*)  carve((size_t)T_*KVD*2);
  float* o    = (float*)carve((size_t)T_*NHD*4);
  float* sc   = (float*)carve((size_t)8*S_*S_*4);
  float* comb = (float*)carve((size_t)T_*4*4);
  int*   cnt  = (int*)  carve((size_t)4*4);
  int*   lists= (int*)  carve((size_t)4*T_*4);
  int2*  epos = (int2*) carve((size_t)T_*8);
  float* gu   = (float*)carve((size_t)4*T_*I_*4);
  u16*   wp   = (u16*)  carve((size_t)56623104*2);
  if ((size_t)(p - (char*)d_ws) > ws_size) return;

  float* eo = sc;   // reuse attention score buffer for MoE expert outputs (32 MB <= 33.5 MB)

  u16 *WqTh = wp,            *WqTl = wp+1048576;
  u16 *WkTh = wp+2097152,    *WkTl = wp+2621440;
  u16 *WvTh = wp+3145728,    *WvTl = wp+3670016;
  u16 *WoTh = wp+4194304,    *WoTl = wp+5242880;
  u16 *WgTh = wp+6291456,    *WgTl = wp+14680064;
  u16 *WuTh = wp+23068672,   *WuTl = wp+31457280;
  u16 *WdTh = wp+39845888,   *WdTl = wp+48234496;

  dim3 tb(32,8);

  k_embed<<<T_,256,0,stream>>>(ids, emb, h);

  for(int l=0;l<4;l++){
    k_transpose<<<dim3(32,32),tb,0,stream>>>(Wq+(size_t)l*H_*NHD, WqTh, WqTl, H_, NHD, 0,0);
    k_transpose<<<dim3(16,32),tb,0,stream>>>(Wk+(size_t)l*H_*KVD, WkTh, WkTl, H_, KVD, 0,0);
    k_transpose<<<dim3(16,32),tb,0,stream>>>(Wv+(size_t)l*H_*KVD, WvTh, WvTl, H_, KVD, 0,0);
    k_transpose<<<dim3(32,32),tb,0,stream>>>(Wo+(size_t)l*NHD*H_, WoTh, WoTl, NHD, H_, 0,0);
    k_transpose<<<dim3(64,32,4),tb,0,stream>>>(Wg+(size_t)l*4*H_*I_, WgTh, WgTl, H_, I_, (long)H_*I_, (long)I_*H_);
    k_transpose<<<dim3(64,32,4),tb,0,stream>>>(Wu+(size_t)l*4*H_*I_, WuTh, WuTl, H_, I_, (long)H_*I_, (long)I_*H_);
    k_transpose<<<dim3(32,64,4),tb,0,stream>>>(Wd+(size_t)l*4*I_*H_, WdTh, WdTl, I_, H_, (long)I_*H_, (long)H_*I_);

    k_rms_sp<<<T_/4,256,0,stream>>>(h, ln1+(size_t)l*H_, xhi, xlo);

    // QKV projections (A = pre-split planes), fp32 outputs
    k_gemm<128,128,2,2,2,true,1,0,0><<<dim3(16,8,1),256,0,stream>>>(xhi, xlo, WqTh, WqTl, q, nullptr, nullptr, nullptr, H_, H_,H_,NHD, 0,0,1,0, 1.f,0);
    k_gemm<128,128,2,2,2,true,1,0,0><<<dim3(16,4,1),256,0,stream>>>(xhi, xlo, WkTh, WkTl, kf, nullptr, nullptr, nullptr, H_, H_,H_,KVD, 0,0,1,0, 1.f,0);
    k_gemm<128,128,2,2,2,true,5,0,0><<<dim3(16,4,1),256,0,stream>>>(xhi, xlo, WvTh, WvTl, vT, nullptr, nullptr, nullptr, H_, H_,H_,KVD, 0,0,1,0, 0.f,0);
    k_split<<<1024,256,0,stream>>>(kf, khi, klo);
    k_split<<<1024,256,0,stream>>>(vT, vthi, vtlo);

    for(int c=0;c<4;c++){
      int b = c>>1, qb=(c&1)*8, kb=qb>>1;
      const float* Aq = q + (size_t)b*S_*NHD + (size_t)qb*64;
      const u16* Bkh = khi + (size_t)b*S_*KVD + (size_t)kb*64;
      const u16* Bkl = klo + (size_t)b*S_*KVD + (size_t)kb*64;
      k_gemm<128,128,2,2,0,true,1,1,0><<<dim3(8,8,8),256,0,stream>>>(Aq, nullptr, Bkh, Bkl, sc, nullptr, nullptr, nullptr, 64, NHD, KVD, S_, 64, 64, 2, (long)S_*S_, 0.125f, 0);
      k_softmax<<<dim3(256,8),256,0,stream>>>(sc);
      const u16* Bvh = vthi + (size_t)b*S_*KVD + (size_t)kb*64*S_;
      const u16* Bvl = vtlo + (size_t)b*S_*KVD + (size_t)kb*64*S_;
      float* Co = o + (size_t)b*S_*NHD + (size_t)qb*64;
      k_gemm<128,64,2,2,0,true,1,2,0><<<dim3(8,1,8),256,0,stream>>>(sc, nullptr, Bvh, Bvl, Co, nullptr, nullptr, nullptr, S_, S_, S_, NHD, (long)S_*S_, (long)64*S_, 2, 64, 1.f, 0);
    }

    // o @ Wo += h
    k_gemm<128,128,2,2,0,true,2,0,0><<<dim3(16,8,1),256,0,stream>>>(o, nullptr, WoTh, WoTl, h, nullptr, nullptr, nullptr, NHD, NHD,NHD,H_, 0,0,1,0, 0.f,0);

    k_zero<<<1,64,0,stream>>>(cnt);
    k_router<<<T_/4,256,0,stream>>>(h, ln2+(size_t)l*H_, gate+(size_t)l*H_*4, comb, lists, cnt, epos);
    k_rms_sp<<<T_/4,256,0,stream>>>(h, ln2+(size_t)l*H_, xhi, xlo);

    // fused sparse MoE: up+gate (all experts, slot-mapped), down-proj, combine
    k_moe_ug<<<dim3(64,32),256,0,stream>>>(xhi, xlo, WuTh, WuTl, WgTh, WgTl, gu, lists, cnt);
    k_gemm<128,128,2,2,0,true,7,0,3><<<dim3(64,8),256,0,stream>>>(gu, nullptr, WdTh, WdTl, eo, nullptr, lists, cnt, I_, I_,I_,H_, 0,(long)I_*H_,1,0, 1.f,0);
    k_combine<<<T_,256,0,stream>>>(h, eo, epos, comb);
  }

  k_rms<<<T_/4,256,0,stream>>>(h, normw, x);
  k_transpose<<<dim3(1000,32),tb,0,stream>>>(lmh, wp, nullptr, H_, V_, 0,0);
  k_gemm<128,128,2,2,0,false,1,0,0><<<dim3(16,250,1),256,0,stream>>>(x, nullptr, wp, nullptr, (float*)d_out, nullptr, nullptr, nullptr, H_, H_,H_,V_, 0,0,1,0, 1.f,0);
}

// Round 6
// 5120.281 us; speedup vs baseline: 1.5372x; 1.0791x over previous
//
#include <hip/hip_runtime.h>

#define T_ 2048
#define H_ 1024
#define S_ 1024
#define V_ 32000
#define I_ 2048
#define NHD 1024   // NH*HD
#define KVD 512    // NKV*HD

typedef unsigned short u16;
typedef unsigned int u32;
typedef __attribute__((ext_vector_type(8))) short s16x8;
typedef __attribute__((ext_vector_type(4))) float f32x4;

__device__ __forceinline__ u16 f2b(float f){ u32 x=__builtin_bit_cast(u32,f); return (u16)((x+0x7fffu+((x>>16)&1u))>>16); }
__device__ __forceinline__ float b2f(u16 u){ return __builtin_bit_cast(float,(u32)u<<16); }
__device__ __forceinline__ u32 pk2(float lo,float hi){ return (u32)f2b(lo)|((u32)f2b(hi)<<16); }
__device__ __forceinline__ void sp2(float a,float b,u32&h,u32&l){
  u16 ha=f2b(a), hb=f2b(b);
  float ra=a-b2f(ha), rb=b-b2f(hb);
  h=(u32)ha|((u32)hb<<16); l=(u32)f2b(ra)|((u32)f2b(rb)<<16);
}
__device__ __forceinline__ float wsum(float v){ for(int o=32;o;o>>=1) v+=__shfl_xor(v,o); return v; }
__device__ __forceinline__ float wmax(float v){ for(int o=32;o;o>>=1) v=fmaxf(v,__shfl_xor(v,o)); return v; }

// ---------------- embedding gather ----------------
__global__ void k_embed(const int* __restrict__ ids, const float* __restrict__ emb, float* __restrict__ h){
  int t = blockIdx.x;
  long src = (long)ids[t]*H_;
  ((float4*)(h + (long)t*H_))[threadIdx.x] = ((const float4*)(emb+src))[threadIdx.x];
}

__global__ void k_zero(int* c){ if(threadIdx.x<4) c[threadIdx.x]=0; }

// ---------------- rmsnorm: fp32 -> fp32 ----------------
__global__ void k_rms(const float* __restrict__ h, const float* __restrict__ w, float* __restrict__ out){
  int wid = threadIdx.x>>6, lane = threadIdx.x&63;
  int t = blockIdx.x*4 + wid;
  const float* row = h + (long)t*H_;
  float v[16]; float ss=0.f;
  #pragma unroll
  for(int j=0;j<16;j++){ v[j]=row[j*64+lane]; ss += v[j]*v[j]; }
  ss = wsum(ss);
  float rstd = rsqrtf(ss/(float)H_ + 1e-6f);
  float* orow = out + (long)t*H_;
  #pragma unroll
  for(int j=0;j<16;j++) orow[j*64+lane] = v[j]*rstd*w[j*64+lane];
}

// ---------------- rmsnorm: fp32 -> bf16 hi/lo planes ----------------
__global__ void k_rms_sp(const float* __restrict__ h, const float* __restrict__ w,
                         u16* __restrict__ xhi, u16* __restrict__ xlo){
  int wid = threadIdx.x>>6, lane = threadIdx.x&63;
  int t = blockIdx.x*4 + wid;
  const float* row = h + (long)t*H_;
  float v[16]; float ss=0.f;
  #pragma unroll
  for(int j=0;j<16;j++){ v[j]=row[j*64+lane]; ss += v[j]*v[j]; }
  ss = wsum(ss);
  float rstd = rsqrtf(ss/(float)H_ + 1e-6f);
  #pragma unroll
  for(int j=0;j<16;j++){
    int idx=j*64+lane;
    float y = v[j]*rstd*w[idx];
    u16 hv = f2b(y);
    xhi[(long)t*H_+idx] = hv;
    xlo[(long)t*H_+idx] = f2b(y - b2f(hv));
  }
}

// ---------------- router (fp32) + expert list build ----------------
__global__ void k_router(const float* __restrict__ h, const float* __restrict__ lw,
                         const float* __restrict__ gate, float* __restrict__ comb,
                         int* __restrict__ lists, int* __restrict__ cnt, int2* __restrict__ epos){
  int wid = threadIdx.x>>6, lane = threadIdx.x&63;
  int t = blockIdx.x*4+wid;
  const float* row = h + (long)t*H_;
  float v[16]; float ss=0.f;
  #pragma unroll
  for(int j=0;j<16;j++){ v[j]=row[j*64+lane]; ss+=v[j]*v[j]; }
  ss = wsum(ss);
  float rstd = rsqrtf(ss/(float)H_+1e-6f);
  float a0=0,a1=0,a2=0,a3=0;
  #pragma unroll
  for(int j=0;j<16;j++){
    int idx=j*64+lane;
    float xv = v[j]*rstd*lw[idx];
    float4 g4 = ((const float4*)gate)[idx];
    a0 += xv*g4.x; a1 += xv*g4.y; a2 += xv*g4.z; a3 += xv*g4.w;
  }
  a0=wsum(a0); a1=wsum(a1); a2=wsum(a2); a3=wsum(a3);
  if(lane==0){
    float p[4]={a0,a1,a2,a3};
    float m = fmaxf(fmaxf(p[0],p[1]),fmaxf(p[2],p[3]));
    float s=0; for(int e=0;e<4;e++){ p[e]=__expf(p[e]-m); s+=p[e]; }
    for(int e=0;e<4;e++) p[e]/=s;
    int i1=0; for(int e=1;e<4;e++) if(p[e]>p[i1]) i1=e;
    int i2=-1; for(int e=0;e<4;e++){ if(e==i1) continue; if(i2<0||p[e]>p[i2]) i2=e; }
    float* c = comb + (long)t*4;
    for(int e=0;e<4;e++) c[e] = (e==i1||e==i2)? p[e] : 0.f;
    int p1 = atomicAdd(&cnt[i1],1); lists[i1*T_+p1]=t;
    int p2 = atomicAdd(&cnt[i2],1); lists[i2*T_+p2]=t;
    epos[t] = make_int2((p1<<2)|i1, (p2<<2)|i2);
  }
}

// ---------------- causal row softmax (in-place, fp32) ----------------
__global__ void k_softmax(float* __restrict__ sc){
  int wid=threadIdx.x>>6, lane=threadIdx.x&63;
  int r = blockIdx.x*4+wid;
  float* row = sc + (long)blockIdx.y*((long)S_*S_) + (long)r*S_;
  float e[16]; float mx=-3.4e38f;
  #pragma unroll
  for(int j=0;j<16;j++){ int idx=j*64+lane; float vv=row[idx]; vv = (idx<=r)? vv : -3.4e38f; e[j]=vv; mx=fmaxf(mx,vv); }
  mx = wmax(mx);
  float s=0.f;
  #pragma unroll
  for(int j=0;j<16;j++){ int idx=j*64+lane; float vv = (idx<=r)? __expf(e[j]-mx) : 0.f; e[j]=vv; s+=vv; }
  s = wsum(s);
  float inv = 1.f/s;
  #pragma unroll
  for(int j=0;j<16;j++) row[j*64+lane] = e[j]*inv;
}

// ---------------- transpose+split: fp32 [R][C] -> bf16 hi(+lo) [C][R] ----------------
__global__ void k_transpose(const float* __restrict__ in, u16* __restrict__ hi, u16* __restrict__ lo,
                            int R, int C, long zi, long zo){
  __shared__ float tile[32][33];
  in += (long)blockIdx.z*zi; hi += (long)blockIdx.z*zo; if(lo) lo += (long)blockIdx.z*zo;
  int c0 = blockIdx.x*32, r0 = blockIdx.y*32;
  int tx = threadIdx.x, ty = threadIdx.y;
  #pragma unroll
  for(int i=0;i<4;i++) tile[ty+8*i][tx] = in[(long)(r0+ty+8*i)*C + c0+tx];
  __syncthreads();
  #pragma unroll
  for(int i=0;i<4;i++){
    int cc=ty+8*i; float v = tile[tx][cc];
    u16 hv = f2b(v);
    long idx = (long)(c0+cc)*R + r0+tx;
    hi[idx] = hv;
    if(lo) lo[idx] = f2b(v - b2f(hv));
  }
}

// ---------------- elementwise split fp32 -> hi/lo bf16 planes ----------------
__global__ void k_split(const float* __restrict__ in, u16* __restrict__ hi, u16* __restrict__ lo){
  long i = ((long)blockIdx.x*blockDim.x + threadIdx.x)*4;
  float4 v = *(const float4*)(in+i);
  u16 h0=f2b(v.x),h1=f2b(v.y),h2=f2b(v.z),h3=f2b(v.w);
  ushort4 H; H.x=h0; H.y=h1; H.z=h2; H.w=h3;
  *(ushort4*)(hi+i)=H;
  ushort4 L; L.x=f2b(v.x-b2f(h0)); L.y=f2b(v.y-b2f(h1)); L.z=f2b(v.z-b2f(h2)); L.w=f2b(v.w-b2f(h3));
  *(ushort4*)(lo+i)=L;
}

// ---------------- MoE combine: h[t] += c1*eo[e1,p1] + c2*eo[e2,p2] ----------------
__global__ void k_combine(float* __restrict__ h, const float* __restrict__ eo,
                          const int2* __restrict__ epos, const float* __restrict__ comb){
  int t = blockIdx.x, c = threadIdx.x;
  int2 ep = epos[t];
  int e1 = ep.x&3, p1 = ep.x>>2, e2 = ep.y&3, p2 = ep.y>>2;
  float c1 = comb[t*4+e1], c2 = comb[t*4+e2];
  float4 a = ((const float4*)(eo + (long)(e1*T_+p1)*H_))[c];
  float4 b = ((const float4*)(eo + (long)(e2*T_+p2)*H_))[c];
  float4* hp = (float4*)(h + (long)t*H_) + c;
  float4 hv = *hp;
  hv.x += c1*a.x + c2*b.x; hv.y += c1*a.y + c2*b.y;
  hv.z += c1*a.z + c2*b.z; hv.w += c1*a.w + c2*b.w;
  *hp = hv;
}

// ---------------- fused MoE up+gate: silu(x@Wg)*(x@Wu) -> gu (compact per expert) ----------------
__global__ void k_moe_ug(const u16* __restrict__ xhi, const u16* __restrict__ xlo,
                         const u16* __restrict__ Wuh, const u16* __restrict__ Wul,
                         const u16* __restrict__ Wgh, const u16* __restrict__ Wgl,
                         float* __restrict__ gu,
                         const int* __restrict__ lists, const int* __restrict__ cntp)
{
  constexpr int BM=128, BN=64, BK=32, LK=BK+8, NT=256;
  const int e = blockIdx.x>>4, m0=(blockIdx.x&15)*BM;
  const int ce = cntp[e];
  if(m0>=ce) return;
  const int n0 = blockIdx.y*BN;
  const int* ridx = lists + e*T_;
  const u16* Buh_g = Wuh + (size_t)e*H_*I_;
  const u16* Bul_g = Wul + (size_t)e*H_*I_;
  const u16* Bgh_g = Wgh + (size_t)e*H_*I_;
  const u16* Bgl_g = Wgl + (size_t)e*H_*I_;
  __shared__ alignas(16) u16 Ah[BM*LK], Al[BM*LK];
  __shared__ alignas(16) u16 Buh[BN*LK], Bul[BN*LK], Bgh[BN*LK], Bgl[BN*LK];
  const int tid=threadIdx.x, lane=tid&63, w=tid>>6;
  const int wr=w>>1, wc=w&1;
  int ar[2];
  #pragma unroll
  for(int s=0;s<2;s++){ int idx=m0 + ((s*NT+tid)>>2); ar[s]=ridx[idx<ce?idx:ce-1]; }
  const int brow = tid>>2;
  const int kc = (tid&3)*8;
  f32x4 au[4][2], ag[4][2];
  #pragma unroll
  for(int i=0;i<4;i++)
    #pragma unroll
    for(int j=0;j<2;j++){ f32x4 zv={0.f,0.f,0.f,0.f}; au[i][j]=zv; ag[i][j]=zv; }

  for(int kt=0;kt<H_/BK;kt++){
    const int k0=kt*BK;
    uint4 a_h[2],a_l[2],bu0,bu1,bg0,bg1;
    #pragma unroll
    for(int s=0;s<2;s++){
      a_h[s]=*(const uint4*)(xhi + (long)ar[s]*H_ + k0+kc);
      a_l[s]=*(const uint4*)(xlo + (long)ar[s]*H_ + k0+kc);
    }
    bu0=*(const uint4*)(Buh_g + (long)(n0+brow)*H_ + k0+kc);
    bu1=*(const uint4*)(Bul_g + (long)(n0+brow)*H_ + k0+kc);
    bg0=*(const uint4*)(Bgh_g + (long)(n0+brow)*H_ + k0+kc);
    bg1=*(const uint4*)(Bgl_g + (long)(n0+brow)*H_ + k0+kc);
    __syncthreads();
    #pragma unroll
    for(int s=0;s<2;s++){
      int row=(s*NT+tid)>>2;
      *(uint4*)&Ah[row*LK+kc]=a_h[s];
      *(uint4*)&Al[row*LK+kc]=a_l[s];
    }
    *(uint4*)&Buh[brow*LK+kc]=bu0; *(uint4*)&Bul[brow*LK+kc]=bu1;
    *(uint4*)&Bgh[brow*LK+kc]=bg0; *(uint4*)&Bgl[brow*LK+kc]=bg1;
    __syncthreads();
    s16x8 fah[4],fal[4],fbuh[2],fbul[2],fbgh[2],fbgl[2];
    const int rA=lane&15, kg=(lane>>4)*8;
    #pragma unroll
    for(int i=0;i<4;i++){
      fah[i]=*(const s16x8*)&Ah[(wr*64+i*16+rA)*LK+kg];
      fal[i]=*(const s16x8*)&Al[(wr*64+i*16+rA)*LK+kg];
    }
    #pragma unroll
    for(int j=0;j<2;j++){
      fbuh[j]=*(const s16x8*)&Buh[(wc*32+j*16+rA)*LK+kg];
      fbul[j]=*(const s16x8*)&Bul[(wc*32+j*16+rA)*LK+kg];
      fbgh[j]=*(const s16x8*)&Bgh[(wc*32+j*16+rA)*LK+kg];
      fbgl[j]=*(const s16x8*)&Bgl[(wc*32+j*16+rA)*LK+kg];
    }
    #pragma unroll
    for(int i=0;i<4;i++)
      #pragma unroll
      for(int j=0;j<2;j++){
        au[i][j]=__builtin_amdgcn_mfma_f32_16x16x32_bf16(fah[i],fbuh[j],au[i][j],0,0,0);
        au[i][j]=__builtin_amdgcn_mfma_f32_16x16x32_bf16(fah[i],fbul[j],au[i][j],0,0,0);
        au[i][j]=__builtin_amdgcn_mfma_f32_16x16x32_bf16(fal[i],fbuh[j],au[i][j],0,0,0);
        ag[i][j]=__builtin_amdgcn_mfma_f32_16x16x32_bf16(fah[i],fbgh[j],ag[i][j],0,0,0);
        ag[i][j]=__builtin_amdgcn_mfma_f32_16x16x32_bf16(fah[i],fbgl[j],ag[i][j],0,0,0);
        ag[i][j]=__builtin_amdgcn_mfma_f32_16x16x32_bf16(fal[i],fbgh[j],ag[i][j],0,0,0);
      }
  }

  #pragma unroll
  for(int i=0;i<4;i++){
    #pragma unroll
    for(int j=0;j<2;j++){
      const int gm0 = m0 + wr*64 + i*16 + ((lane>>4)<<2);
      const int gn  = n0 + wc*32 + j*16 + (lane&15);
      #pragma unroll
      for(int r=0;r<4;r++){
        const int gm = gm0+r;
        if(gm<ce){
          float uu=au[i][j][r], gg=ag[i][j][r];
          float sg = gg/(1.f+__expf(-gg));
          gu[(long)(e*T_+gm)*I_ + gn] = sg*uu;
        }
      }
    }
  }
}

// ---------------- MFMA GEMM: C[M,N] = A[M,K] * B[N,K]^T ----------------
// ABT: 0 = A fp32 (sp2-split on the fly if SPL), 2 = A bf16 hi/lo planes (requires SPL)
// SPL: bf16x2 split precision (B hi/lo planes, 3 MFMAs)
// EPI: 1=store f32*scale, 2=f32 +=, 5=store f32 transposed [b][col][tok],
//      7=store f32 compact per expert slot, 8=store f32*scale via LDS (coalesced rows)
// CM : 0=none, 1=skip blocks strictly above diagonal, 2=K-limit at m0+BM (causal PV)
// GATH: 0=dense, 3=expert-slot mode (bid.x -> (e,mslot); A compact rows, clamp; B += e*zB)
template<int BM,int BN,int WM,int WN,int ABT,bool SPL,int EPI,int CM,int GATH>
__launch_bounds__(WM*WN*64)
__global__ void k_gemm(const void* __restrict__ Ap, const void* __restrict__ A2p,
                       const u16* __restrict__ Bhip, const u16* __restrict__ Blop,
                       void* __restrict__ Cp, const void* __restrict__ auxp,
                       const int* __restrict__ ridxp, const int* __restrict__ cntp,
                       int Kdim, int lda, int ldb, int ldc,
                       long zA, long zB, int zBdiv, long zC,
                       float scale, int eidx)
{
  static_assert(!(ABT==2 && !SPL), "plane-A requires split");
  constexpr int NT = WM*WN*64;
  constexpr int BK = 32;
  constexpr int LK = BK+8;
  constexpr int WMT = BM/WM, WNT = BN/WN;
  constexpr int MF = WMT/16, NF = WNT/16;
  constexpr int ACH = (BM*BK)/(NT*8);
  constexpr int BCH = (BN*BK)/(NT*8);
  constexpr int PL = SPL?2:1;
  static_assert(ACH>=1 && BCH>=1, "staging chunks");
  __shared__ alignas(16) u16 As[PL*BM*LK];
  __shared__ alignas(16) u16 Bs[PL*BN*LK];
  __shared__ float Cs[EPI==8?WM:1][EPI==8?16:1][EPI==8?(BN+4):1];
  int m0, eid_ = eidx, cnt = 0;
  if constexpr (GATH==3){
    eid_ = blockIdx.x>>4; m0 = (blockIdx.x&15)*BM;
    cnt = cntp[eid_]; if(m0>=cnt) return;
  } else {
    m0 = blockIdx.x*BM;
  }
  const int n0 = blockIdx.y*BN;
  if (CM==1 && n0 > m0) return;
  const int z = blockIdx.z;
  const int tid = threadIdx.x, lane = tid&63, w = tid>>6;
  const int wr = w/WN, wc = w%WN;
  const float* Af = (const float*)Ap + (long)z*zA + (GATH==3 ? (long)eid_*T_*lda : 0);
  const u16*  Ahi = (const u16*)Ap + (long)z*zA;
  const u16*  Alo = (const u16*)A2p + (long)z*zA;
  const u16*  Bh  = Bhip + (long)(z/zBdiv)*zB + (GATH==3 ? (long)eid_*zB : 0);
  const u16*  Bl  = SPL ? (Blop + (long)(z/zBdiv)*zB + (GATH==3 ? (long)eid_*zB : 0)) : (const u16*)nullptr;

  f32x4 acc[MF][NF];
  #pragma unroll
  for(int i=0;i<MF;i++)
    #pragma unroll
    for(int j=0;j<NF;j++){ f32x4 zv={0.f,0.f,0.f,0.f}; acc[i][j]=zv; }

  int ktend = Kdim/BK;
  if (CM==2){ int lim=(m0+BM)/BK; if(lim<ktend) ktend=lim; }

  for(int kt=0;kt<ktend;kt++){
    const int k0 = kt*BK;
    uint4 avh[ACH], avl[ACH], bvh[BCH], bvl[BCH];
    #pragma unroll
    for(int s=0;s<ACH;s++){
      int c = s*NT+tid; int row=c>>2; int kc=(c&3)*8;
      int arow = m0+row;
      if constexpr (GATH==3){ arow = arow < cnt ? arow : cnt-1; }
      if constexpr (ABT==2){
        avh[s] = *(const uint4*)(Ahi + (long)arow*lda + k0+kc);
        avl[s] = *(const uint4*)(Alo + (long)arow*lda + k0+kc);
      } else {
        const float* pA = Af + (long)arow*lda + k0+kc;
        float4 X=*(const float4*)pA, Y=*(const float4*)(pA+4);
        if constexpr (SPL){
          sp2(X.x,X.y,avh[s].x,avl[s].x); sp2(X.z,X.w,avh[s].y,avl[s].y);
          sp2(Y.x,Y.y,avh[s].z,avl[s].z); sp2(Y.z,Y.w,avh[s].w,avl[s].w);
        } else {
          avh[s].x=pk2(X.x,X.y); avh[s].y=pk2(X.z,X.w); avh[s].z=pk2(Y.x,Y.y); avh[s].w=pk2(Y.z,Y.w);
        }
      }
    }
    #pragma unroll
    for(int s=0;s<BCH;s++){
      int c = s*NT+tid; int row=c>>2; int kc=(c&3)*8;
      bvh[s] = *(const uint4*)(Bh + (long)(n0+row)*ldb + k0+kc);
      if constexpr (SPL) bvl[s] = *(const uint4*)(Bl + (long)(n0+row)*ldb + k0+kc);
    }
    __syncthreads();
    #pragma unroll
    for(int s=0;s<ACH;s++){ int c=s*NT+tid; int row=c>>2; int kc=(c&3)*8;
      *(uint4*)&As[row*LK+kc] = avh[s];
      if constexpr (SPL) *(uint4*)&As[BM*LK + row*LK+kc] = avl[s]; }
    #pragma unroll
    for(int s=0;s<BCH;s++){ int c=s*NT+tid; int row=c>>2; int kc=(c&3)*8;
      *(uint4*)&Bs[row*LK+kc] = bvh[s];
      if constexpr (SPL) *(uint4*)&Bs[BN*LK + row*LK+kc] = bvl[s]; }
    __syncthreads();
    s16x8 ah[MF], bh[NF], al[MF], bl[NF];
    const int rA = lane&15, kg=(lane>>4)*8;
    #pragma unroll
    for(int i=0;i<MF;i++){
      ah[i]=*(const s16x8*)&As[(wr*WMT+i*16+rA)*LK+kg];
      if constexpr (SPL) al[i]=*(const s16x8*)&As[BM*LK+(wr*WMT+i*16+rA)*LK+kg];
    }
    #pragma unroll
    for(int j=0;j<NF;j++){
      bh[j]=*(const s16x8*)&Bs[(wc*WNT+j*16+rA)*LK+kg];
      if constexpr (SPL) bl[j]=*(const s16x8*)&Bs[BN*LK+(wc*WNT+j*16+rA)*LK+kg];
    }
    #pragma unroll
    for(int i=0;i<MF;i++)
      #pragma unroll
      for(int j=0;j<NF;j++){
        acc[i][j]=__builtin_amdgcn_mfma_f32_16x16x32_bf16(ah[i],bh[j],acc[i][j],0,0,0);
        if constexpr (SPL){
          acc[i][j]=__builtin_amdgcn_mfma_f32_16x16x32_bf16(ah[i],bl[j],acc[i][j],0,0,0);
          acc[i][j]=__builtin_amdgcn_mfma_f32_16x16x32_bf16(al[i],bh[j],acc[i][j],0,0,0);
        }
      }
  }

  if constexpr (EPI==8){
    // LDS-staged coalesced store: full 128B-line writes per row
    float* C = (float*)Cp + (long)z*zC;
    #pragma unroll
    for(int i=0;i<MF;i++){
      __syncthreads();
      #pragma unroll
      for(int j=0;j<NF;j++)
        #pragma unroll
        for(int r=0;r<4;r++)
          Cs[wr][((lane>>4)<<2)+r][wc*WNT + j*16 + (lane&15)] = acc[i][j][r]*scale;
      __syncthreads();
      const int rrow = tid>>3;            // 0..31
      const int wri = rrow>>4, r16 = rrow&15;
      const long gm = m0 + wri*WMT + i*16 + r16;
      #pragma unroll
      for(int s=0;s<BN/32;s++){
        int c0 = ((tid&7) + s*8)*4;
        float4 vv = { Cs[wri][r16][c0], Cs[wri][r16][c0+1], Cs[wri][r16][c0+2], Cs[wri][r16][c0+3] };
        *(float4*)(C + gm*ldc + n0 + c0) = vv;
      }
    }
    return;
  }

  #pragma unroll
  for(int i=0;i<MF;i++){
    #pragma unroll
    for(int j=0;j<NF;j++){
      const int gm0 = m0 + wr*WMT + i*16 + ((lane>>4)<<2);
      const int gn  = n0 + wc*WNT + j*16 + (lane&15);
      #pragma unroll
      for(int r=0;r<4;r++){
        const int gm = gm0+r;
        const float v = acc[i][j][r];
        const bool live = (GATH==0) || (gm < cnt);
        if constexpr (EPI==1){
          if(live) ((float*)Cp + (long)z*zC)[(long)gm*ldc+gn] = v*scale;
        } else if constexpr (EPI==2){
          float* C = (float*)Cp; C[(long)gm*ldc+gn] += v;
        } else if constexpr (EPI==5){
          ((float*)Cp)[((long)(gm>>10)<<19) + (long)gn*S_ + (gm&1023)] = v;
        } else if constexpr (EPI==7){
          if(live) ((float*)Cp)[(long)(eid_*T_+gm)*ldc+gn] = v*scale;
        }
      }
    }
  }
}

extern "C" void kernel_launch(void* const* d_in, const int* in_sizes, int n_in,
                              void* d_out, int out_size, void* d_ws, size_t ws_size,
                              hipStream_t stream)
{
  (void)in_sizes; (void)n_in; (void)out_size;
  const int*   ids   = (const int*)d_in[0];
  const float* emb   = (const float*)d_in[1];
  const float* Wq    = (const float*)d_in[2];
  const float* Wk    = (const float*)d_in[3];
  const float* Wv    = (const float*)d_in[4];
  const float* Wo    = (const float*)d_in[5];
  const float* ln1   = (const float*)d_in[6];
  const float* ln2   = (const float*)d_in[7];
  const float* gate  = (const float*)d_in[8];
  const float* Wg    = (const float*)d_in[9];
  const float* Wu    = (const float*)d_in[10];
  const float* Wd    = (const float*)d_in[11];
  const float* normw = (const float*)d_in[12];
  const float* lmh   = (const float*)d_in[13];

  char* p = (char*)d_ws;
  auto carve = [&](size_t bytes)->void*{ void* r=p; p += (bytes+255)&~(size_t)255; return r; };
  float* h    = (float*)carve((size_t)T_*H_*4);
  float* x    = (float*)carve((size_t)T_*H_*4);
  u16*   xhi  = (u16*)  carve((size_t)T_*H_*2);
  u16*   xlo  = (u16*)  carve((size_t)T_*H_*2);
  float* q    = (float*)carve((size_t)T_*NHD*4);
  float* kf   = (float*)carve((size_t)T_*KVD*4);
  u16*   khi  = (u16*)  carve((size_t)T_*KVD*2);
  u16*   klo  = (u16*)  carve((size_t)T_*KVD*2);
  float* vT   = (float*)carve((size_t)T_*KVD*4);
  u16*   vthi = (u16*)  carve((size_t)T_*KVD*2);
  u16*   vtlo = (u16*)  carve((size_t)T_*KVD*2);
  float* o    = (float*)carve((size_t)T_*NHD*4);
  float* comb = (float*)carve((size_t)T_*4*4);
  int*   cnt  = (int*)  carve((size_t)4*4);
  int*   lists= (int*)  carve((size_t)4*T_*4);
  int2*  epos = (int2*) carve((size_t)T_*8);
  float* U    = (float*)carve((size_t)96*1024*1024);   // union: sc16(67MB) | gu(64MB)+eo(32MB)
  u16*   wp   = (u16*)  carve((size_t)56623104*2);
  if ((size_t)(p - (char*)d_ws) > ws_size) return;

  float* sc = U;
  float* gu = U;
  float* eo = U + (size_t)16*1024*1024;   // 64MB offset in floats

  u16 *WqTh = wp,            *WqTl = wp+1048576;
  u16 *WkTh = wp+2097152,    *WkTl = wp+2621440;
  u16 *WvTh = wp+3145728,    *WvTl = wp+3670016;
  u16 *WoTh = wp+4194304,    *WoTl = wp+5242880;
  u16 *WgTh = wp+6291456,    *WgTl = wp+14680064;
  u16 *WuTh = wp+23068672,   *WuTl = wp+31457280;
  u16 *WdTh = wp+39845888,   *WdTl = wp+48234496;

  dim3 tb(32,8);

  k_embed<<<T_,256,0,stream>>>(ids, emb, h);

  for(int l=0;l<4;l++){
    k_transpose<<<dim3(32,32),tb,0,stream>>>(Wq+(size_t)l*H_*NHD, WqTh, WqTl, H_, NHD, 0,0);
    k_transpose<<<dim3(16,32),tb,0,stream>>>(Wk+(size_t)l*H_*KVD, WkTh, WkTl, H_, KVD, 0,0);
    k_transpose<<<dim3(16,32),tb,0,stream>>>(Wv+(size_t)l*H_*KVD, WvTh, WvTl, H_, KVD, 0,0);
    k_transpose<<<dim3(32,32),tb,0,stream>>>(Wo+(size_t)l*NHD*H_, WoTh, WoTl, NHD, H_, 0,0);
    k_transpose<<<dim3(64,32,4),tb,0,stream>>>(Wg+(size_t)l*4*H_*I_, WgTh, WgTl, H_, I_, (long)H_*I_, (long)I_*H_);
    k_transpose<<<dim3(64,32,4),tb,0,stream>>>(Wu+(size_t)l*4*H_*I_, WuTh, WuTl, H_, I_, (long)H_*I_, (long)I_*H_);
    k_transpose<<<dim3(32,64,4),tb,0,stream>>>(Wd+(size_t)l*4*I_*H_, WdTh, WdTl, I_, H_, (long)I_*H_, (long)H_*I_);

    k_rms_sp<<<T_/4,256,0,stream>>>(h, ln1+(size_t)l*H_, xhi, xlo);

    k_gemm<128,128,2,2,2,true,1,0,0><<<dim3(16,8,1),256,0,stream>>>(xhi, xlo, WqTh, WqTl, q, nullptr, nullptr, nullptr, H_, H_,H_,NHD, 0,0,1,0, 1.f,0);
    k_gemm<128,128,2,2,2,true,1,0,0><<<dim3(16,4,1),256,0,stream>>>(xhi, xlo, WkTh, WkTl, kf, nullptr, nullptr, nullptr, H_, H_,H_,KVD, 0,0,1,0, 1.f,0);
    k_gemm<128,128,2,2,2,true,5,0,0><<<dim3(16,4,1),256,0,stream>>>(xhi, xlo, WvTh, WvTl, vT, nullptr, nullptr, nullptr, H_, H_,H_,KVD, 0,0,1,0, 0.f,0);
    k_split<<<1024,256,0,stream>>>(kf, khi, klo);
    k_split<<<1024,256,0,stream>>>(vT, vthi, vtlo);

    // attention, batched over 16 heads per b (z = head)
    for(int b=0;b<2;b++){
      const float* Aq = q + (size_t)b*S_*NHD;
      const u16* Bkh = khi + (size_t)b*S_*KVD;
      const u16* Bkl = klo + (size_t)b*S_*KVD;
      k_gemm<128,128,2,2,0,true,1,1,0><<<dim3(8,8,16),256,0,stream>>>(Aq, nullptr, Bkh, Bkl, sc, nullptr, nullptr, nullptr, 64, NHD, KVD, S_, 64, 64, 2, (long)S_*S_, 0.125f, 0);
      k_softmax<<<dim3(256,16),256,0,stream>>>(sc);
      const u16* Bvh = vthi + (size_t)b*S_*KVD;
      const u16* Bvl = vtlo + (size_t)b*S_*KVD;
      float* Co = o + (size_t)b*S_*NHD;
      k_gemm<64,64,2,2,0,true,1,2,0><<<dim3(16,1,16),256,0,stream>>>(sc, nullptr, Bvh, Bvl, Co, nullptr, nullptr, nullptr, S_, S_, S_, NHD, (long)S_*S_, (long)64*S_, 2, 64, 1.f, 0);
    }

    // o @ Wo += h
    k_gemm<128,128,2,2,0,true,2,0,0><<<dim3(16,8,1),256,0,stream>>>(o, nullptr, WoTh, WoTl, h, nullptr, nullptr, nullptr, NHD, NHD,NHD,H_, 0,0,1,0, 0.f,0);

    k_zero<<<1,64,0,stream>>>(cnt);
    k_router<<<T_/4,256,0,stream>>>(h, ln2+(size_t)l*H_, gate+(size_t)l*H_*4, comb, lists, cnt, epos);
    k_rms_sp<<<T_/4,256,0,stream>>>(h, ln2+(size_t)l*H_, xhi, xlo);

    k_moe_ug<<<dim3(64,32),256,0,stream>>>(xhi, xlo, WuTh, WuTl, WgTh, WgTl, gu, lists, cnt);
    k_gemm<128,128,2,2,0,true,7,0,3><<<dim3(64,8),256,0,stream>>>(gu, nullptr, WdTh, WdTl, eo, nullptr, lists, cnt, I_, I_,I_,H_, 0,(long)I_*H_,1,0, 1.f,0);
    k_combine<<<T_,256,0,stream>>>(h, eo, epos, comb);
  }

  k_rms<<<T_/4,256,0,stream>>>(h, normw, x);
  k_transpose<<<dim3(1000,32),tb,0,stream>>>(lmh, wp, nullptr, H_, V_, 0,0);
  k_gemm<128,128,2,2,0,false,8,0,0><<<dim3(16,250,1),256,0,stream>>>(x, nullptr, wp, nullptr, (float*)d_out, nullptr, nullptr, nullptr, H_, H_,H_,V_, 0,0,1,0, 1.f,0);
}

// Round 7
// 4435.671 us; speedup vs baseline: 1.7745x; 1.1543x over previous
//
#include <hip/hip_runtime.h>

#define T_ 2048
#define H_ 1024
#define S_ 1024
#define V_ 32000
#define I_ 2048
#define NHD 1024   // NH*HD
#define KVD 512    // NKV*HD

typedef unsigned short u16;
typedef unsigned int u32;
typedef __attribute__((ext_vector_type(8))) short s16x8;
typedef __attribute__((ext_vector_type(4))) float f32x4;

__device__ __forceinline__ u16 f2b(float f){ u32 x=__builtin_bit_cast(u32,f); return (u16)((x+0x7fffu+((x>>16)&1u))>>16); }
__device__ __forceinline__ float b2f(u16 u){ return __builtin_bit_cast(float,(u32)u<<16); }
__device__ __forceinline__ u32 pk2(float lo,float hi){ return (u32)f2b(lo)|((u32)f2b(hi)<<16); }
__device__ __forceinline__ void sp2(float a,float b,u32&h,u32&l){
  u16 ha=f2b(a), hb=f2b(b);
  float ra=a-b2f(ha), rb=b-b2f(hb);
  h=(u32)ha|((u32)hb<<16); l=(u32)f2b(ra)|((u32)f2b(rb)<<16);
}
__device__ __forceinline__ float wsum(float v){ for(int o=32;o;o>>=1) v+=__shfl_xor(v,o); return v; }
__device__ __forceinline__ float wmax(float v){ for(int o=32;o;o>>=1) v=fmaxf(v,__shfl_xor(v,o)); return v; }

// ---------------- embedding gather ----------------
__global__ void k_embed(const int* __restrict__ ids, const float* __restrict__ emb, float* __restrict__ h){
  int t = blockIdx.x;
  long src = (long)ids[t]*H_;
  ((float4*)(h + (long)t*H_))[threadIdx.x] = ((const float4*)(emb+src))[threadIdx.x];
}

__global__ void k_zero(int* c){ if(threadIdx.x<16) c[threadIdx.x]=0; }

// ---------------- rmsnorm: fp32 -> fp32 ----------------
__global__ void k_rms(const float* __restrict__ h, const float* __restrict__ w, float* __restrict__ out){
  int wid = threadIdx.x>>6, lane = threadIdx.x&63;
  int t = blockIdx.x*4 + wid;
  const float* row = h + (long)t*H_;
  float v[16]; float ss=0.f;
  #pragma unroll
  for(int j=0;j<16;j++){ v[j]=row[j*64+lane]; ss += v[j]*v[j]; }
  ss = wsum(ss);
  float rstd = rsqrtf(ss/(float)H_ + 1e-6f);
  float* orow = out + (long)t*H_;
  #pragma unroll
  for(int j=0;j<16;j++) orow[j*64+lane] = v[j]*rstd*w[j*64+lane];
}

// ---------------- rmsnorm: fp32 -> bf16 hi/lo planes ----------------
__global__ void k_rms_sp(const float* __restrict__ h, const float* __restrict__ w,
                         u16* __restrict__ xhi, u16* __restrict__ xlo){
  int wid = threadIdx.x>>6, lane = threadIdx.x&63;
  int t = blockIdx.x*4 + wid;
  const float* row = h + (long)t*H_;
  float v[16]; float ss=0.f;
  #pragma unroll
  for(int j=0;j<16;j++){ v[j]=row[j*64+lane]; ss += v[j]*v[j]; }
  ss = wsum(ss);
  float rstd = rsqrtf(ss/(float)H_ + 1e-6f);
  #pragma unroll
  for(int j=0;j<16;j++){
    int idx=j*64+lane;
    float y = v[j]*rstd*w[idx];
    u16 hv = f2b(y);
    xhi[(long)t*H_+idx] = hv;
    xlo[(long)t*H_+idx] = f2b(y - b2f(hv));
  }
}

// ---------------- router (fp32) + expert list build ----------------
__global__ void k_router(const float* __restrict__ h, const float* __restrict__ lw,
                         const float* __restrict__ gate, float* __restrict__ comb,
                         int* __restrict__ lists, int* __restrict__ cnt, int2* __restrict__ epos){
  int wid = threadIdx.x>>6, lane = threadIdx.x&63;
  int t = blockIdx.x*4+wid;
  const float* row = h + (long)t*H_;
  float v[16]; float ss=0.f;
  #pragma unroll
  for(int j=0;j<16;j++){ v[j]=row[j*64+lane]; ss+=v[j]*v[j]; }
  ss = wsum(ss);
  float rstd = rsqrtf(ss/(float)H_+1e-6f);
  float a0=0,a1=0,a2=0,a3=0;
  #pragma unroll
  for(int j=0;j<16;j++){
    int idx=j*64+lane;
    float xv = v[j]*rstd*lw[idx];
    float4 g4 = ((const float4*)gate)[idx];
    a0 += xv*g4.x; a1 += xv*g4.y; a2 += xv*g4.z; a3 += xv*g4.w;
  }
  a0=wsum(a0); a1=wsum(a1); a2=wsum(a2); a3=wsum(a3);
  if(lane==0){
    float p[4]={a0,a1,a2,a3};
    float m = fmaxf(fmaxf(p[0],p[1]),fmaxf(p[2],p[3]));
    float s=0; for(int e=0;e<4;e++){ p[e]=__expf(p[e]-m); s+=p[e]; }
    for(int e=0;e<4;e++) p[e]/=s;
    int i1=0; for(int e=1;e<4;e++) if(p[e]>p[i1]) i1=e;
    int i2=-1; for(int e=0;e<4;e++){ if(e==i1) continue; if(i2<0||p[e]>p[i2]) i2=e; }
    float* c = comb + (long)t*4;
    for(int e=0;e<4;e++) c[e] = (e==i1||e==i2)? p[e] : 0.f;
    int p1 = atomicAdd(&cnt[i1],1); lists[i1*T_+p1]=t;
    int p2 = atomicAdd(&cnt[i2],1); lists[i2*T_+p2]=t;
    epos[t] = make_int2((p1<<2)|i1, (p2<<2)|i2);
  }
}

// ---------------- causal row softmax (in-place, fp32) ----------------
__global__ void k_softmax(float* __restrict__ sc){
  int wid=threadIdx.x>>6, lane=threadIdx.x&63;
  int r = blockIdx.x*4+wid;
  float* row = sc + (long)blockIdx.y*((long)S_*S_) + (long)r*S_;
  float e[16]; float mx=-3.4e38f;
  #pragma unroll
  for(int j=0;j<16;j++){ int idx=j*64+lane; float vv=row[idx]; vv = (idx<=r)? vv : -3.4e38f; e[j]=vv; mx=fmaxf(mx,vv); }
  mx = wmax(mx);
  float s=0.f;
  #pragma unroll
  for(int j=0;j<16;j++){ int idx=j*64+lane; float vv = (idx<=r)? __expf(e[j]-mx) : 0.f; e[j]=vv; s+=vv; }
  s = wsum(s);
  float inv = 1.f/s;
  #pragma unroll
  for(int j=0;j<16;j++) row[j*64+lane] = e[j]*inv;
}

// ---------------- transpose+split: fp32 [R][C] -> bf16 hi(+lo) [C][R] ----------------
__global__ void k_transpose(const float* __restrict__ in, u16* __restrict__ hi, u16* __restrict__ lo,
                            int R, int C, long zi, long zo){
  __shared__ float tile[32][33];
  in += (long)blockIdx.z*zi; hi += (long)blockIdx.z*zo; if(lo) lo += (long)blockIdx.z*zo;
  int c0 = blockIdx.x*32, r0 = blockIdx.y*32;
  int tx = threadIdx.x, ty = threadIdx.y;
  #pragma unroll
  for(int i=0;i<4;i++) tile[ty+8*i][tx] = in[(long)(r0+ty+8*i)*C + c0+tx];
  __syncthreads();
  #pragma unroll
  for(int i=0;i<4;i++){
    int cc=ty+8*i; float v = tile[tx][cc];
    u16 hv = f2b(v);
    long idx = (long)(c0+cc)*R + r0+tx;
    hi[idx] = hv;
    if(lo) lo[idx] = f2b(v - b2f(hv));
  }
}

// ---------------- MoE combine: h[t] += c1*eo[e1,p1] + c2*eo[e2,p2] ----------------
__global__ void k_combine(float* __restrict__ h, const float* __restrict__ eo,
                          const int2* __restrict__ epos, const float* __restrict__ comb){
  int t = blockIdx.x, c = threadIdx.x;
  int2 ep = epos[t];
  int e1 = ep.x&3, p1 = ep.x>>2, e2 = ep.y&3, p2 = ep.y>>2;
  float c1 = comb[t*4+e1], c2 = comb[t*4+e2];
  float4 a = ((const float4*)(eo + (long)(e1*T_+p1)*H_))[c];
  float4 b = ((const float4*)(eo + (long)(e2*T_+p2)*H_))[c];
  float4* hp = (float4*)(h + (long)t*H_) + c;
  float4 hv = *hp;
  hv.x += c1*a.x + c2*b.x; hv.y += c1*a.y + c2*b.y;
  hv.z += c1*a.z + c2*b.z; hv.w += c1*a.w + c2*b.w;
  *hp = hv;
}

// ---------------- fused QKV GEMM: x @ [Wq|Wk|Wv], split epilogue to planes ----------------
__global__ __launch_bounds__(256) void k_qkv(
  const u16* __restrict__ xhi, const u16* __restrict__ xlo,
  const u16* __restrict__ Bh, const u16* __restrict__ Bl,
  u16* __restrict__ qhi, u16* __restrict__ qlo,
  u16* __restrict__ khi, u16* __restrict__ klo,
  u16* __restrict__ vthi, u16* __restrict__ vtlo)
{
  constexpr int BM=128,BN=128,BK=32,LK=BK+8,NT=256;
  __shared__ alignas(16) u16 As[2*BM*LK], Bs[2*BN*LK];
  const int m0=blockIdx.x*BM, n0=blockIdx.y*BN;
  const int tid=threadIdx.x, lane=tid&63, w=tid>>6, wr=w>>1, wc=w&1;
  f32x4 acc[4][4];
  #pragma unroll
  for(int i=0;i<4;i++)
    #pragma unroll
    for(int j=0;j<4;j++){ f32x4 zv={0.f,0.f,0.f,0.f}; acc[i][j]=zv; }

  for(int kt=0;kt<H_/BK;kt++){
    const int k0=kt*BK;
    uint4 avh[2],avl[2],bvh[2],bvl[2];
    #pragma unroll
    for(int s=0;s<2;s++){
      int c=s*NT+tid; int row=c>>2; int kc=(c&3)*8;
      avh[s]=*(const uint4*)(xhi + (long)(m0+row)*H_ + k0+kc);
      avl[s]=*(const uint4*)(xlo + (long)(m0+row)*H_ + k0+kc);
      bvh[s]=*(const uint4*)(Bh + (long)(n0+row)*H_ + k0+kc);
      bvl[s]=*(const uint4*)(Bl + (long)(n0+row)*H_ + k0+kc);
    }
    __syncthreads();
    #pragma unroll
    for(int s=0;s<2;s++){
      int c=s*NT+tid; int row=c>>2; int kc=(c&3)*8;
      *(uint4*)&As[row*LK+kc]=avh[s];
      *(uint4*)&As[BM*LK+row*LK+kc]=avl[s];
      *(uint4*)&Bs[row*LK+kc]=bvh[s];
      *(uint4*)&Bs[BN*LK+row*LK+kc]=bvl[s];
    }
    __syncthreads();
    s16x8 ah[4],al[4],bh[4],bl[4];
    const int rA=lane&15, kg=(lane>>4)*8;
    #pragma unroll
    for(int i=0;i<4;i++){
      ah[i]=*(const s16x8*)&As[(wr*64+i*16+rA)*LK+kg];
      al[i]=*(const s16x8*)&As[BM*LK+(wr*64+i*16+rA)*LK+kg];
    }
    #pragma unroll
    for(int j=0;j<4;j++){
      bh[j]=*(const s16x8*)&Bs[(wc*64+j*16+rA)*LK+kg];
      bl[j]=*(const s16x8*)&Bs[BN*LK+(wc*64+j*16+rA)*LK+kg];
    }
    #pragma unroll
    for(int i=0;i<4;i++)
      #pragma unroll
      for(int j=0;j<4;j++){
        acc[i][j]=__builtin_amdgcn_mfma_f32_16x16x32_bf16(ah[i],bh[j],acc[i][j],0,0,0);
        acc[i][j]=__builtin_amdgcn_mfma_f32_16x16x32_bf16(ah[i],bl[j],acc[i][j],0,0,0);
        acc[i][j]=__builtin_amdgcn_mfma_f32_16x16x32_bf16(al[i],bh[j],acc[i][j],0,0,0);
      }
  }

  #pragma unroll
  for(int i=0;i<4;i++){
    #pragma unroll
    for(int j=0;j<4;j++){
      const int gm0 = m0 + wr*64 + i*16 + ((lane>>4)<<2);
      const int gn  = n0 + wc*64 + j*16 + (lane&15);
      #pragma unroll
      for(int r=0;r<4;r++){
        const int gm = gm0+r;
        float v = acc[i][j][r];
        u16 hv = f2b(v);
        u16 lv = f2b(v - b2f(hv));
        if(gn < 1024){
          long idx=(long)gm*NHD+gn; qhi[idx]=hv; qlo[idx]=lv;
        } else if(gn < 1536){
          long idx=(long)gm*KVD+(gn-1024); khi[idx]=hv; klo[idx]=lv;
        } else {
          long idx=((long)(gm>>10)<<19) + (long)(gn-1536)*S_ + (gm&1023);
          vthi[idx]=hv; vtlo[idx]=lv;
        }
      }
    }
  }
}

// ---------------- fused MoE up+gate: silu(x@Wg)*(x@Wu) -> gu (compact per expert) ----------------
__global__ void k_moe_ug(const u16* __restrict__ xhi, const u16* __restrict__ xlo,
                         const u16* __restrict__ Wuh, const u16* __restrict__ Wul,
                         const u16* __restrict__ Wgh, const u16* __restrict__ Wgl,
                         float* __restrict__ gu,
                         const int* __restrict__ lists, const int* __restrict__ cntp)
{
  constexpr int BM=128, BN=64, BK=32, LK=BK+8, NT=256;
  const int e = blockIdx.x>>4, m0=(blockIdx.x&15)*BM;
  const int ce = cntp[e];
  if(m0>=ce) return;
  const int n0 = blockIdx.y*BN;
  const int* ridx = lists + e*T_;
  const u16* Buh_g = Wuh + (size_t)e*H_*I_;
  const u16* Bul_g = Wul + (size_t)e*H_*I_;
  const u16* Bgh_g = Wgh + (size_t)e*H_*I_;
  const u16* Bgl_g = Wgl + (size_t)e*H_*I_;
  __shared__ alignas(16) u16 Ah[BM*LK], Al[BM*LK];
  __shared__ alignas(16) u16 Buh[BN*LK], Bul[BN*LK], Bgh[BN*LK], Bgl[BN*LK];
  const int tid=threadIdx.x, lane=tid&63, w=tid>>6;
  const int wr=w>>1, wc=w&1;
  int ar[2];
  #pragma unroll
  for(int s=0;s<2;s++){ int idx=m0 + ((s*NT+tid)>>2); ar[s]=ridx[idx<ce?idx:ce-1]; }
  const int brow = tid>>2;
  const int kc = (tid&3)*8;
  f32x4 au[4][2], ag[4][2];
  #pragma unroll
  for(int i=0;i<4;i++)
    #pragma unroll
    for(int j=0;j<2;j++){ f32x4 zv={0.f,0.f,0.f,0.f}; au[i][j]=zv; ag[i][j]=zv; }

  for(int kt=0;kt<H_/BK;kt++){
    const int k0=kt*BK;
    uint4 a_h[2],a_l[2],bu0,bu1,bg0,bg1;
    #pragma unroll
    for(int s=0;s<2;s++){
      a_h[s]=*(const uint4*)(xhi + (long)ar[s]*H_ + k0+kc);
      a_l[s]=*(const uint4*)(xlo + (long)ar[s]*H_ + k0+kc);
    }
    bu0=*(const uint4*)(Buh_g + (long)(n0+brow)*H_ + k0+kc);
    bu1=*(const uint4*)(Bul_g + (long)(n0+brow)*H_ + k0+kc);
    bg0=*(const uint4*)(Bgh_g + (long)(n0+brow)*H_ + k0+kc);
    bg1=*(const uint4*)(Bgl_g + (long)(n0+brow)*H_ + k0+kc);
    __syncthreads();
    #pragma unroll
    for(int s=0;s<2;s++){
      int row=(s*NT+tid)>>2;
      *(uint4*)&Ah[row*LK+kc]=a_h[s];
      *(uint4*)&Al[row*LK+kc]=a_l[s];
    }
    *(uint4*)&Buh[brow*LK+kc]=bu0; *(uint4*)&Bul[brow*LK+kc]=bu1;
    *(uint4*)&Bgh[brow*LK+kc]=bg0; *(uint4*)&Bgl[brow*LK+kc]=bg1;
    __syncthreads();
    s16x8 fah[4],fal[4],fbuh[2],fbul[2],fbgh[2],fbgl[2];
    const int rA=lane&15, kg=(lane>>4)*8;
    #pragma unroll
    for(int i=0;i<4;i++){
      fah[i]=*(const s16x8*)&Ah[(wr*64+i*16+rA)*LK+kg];
      fal[i]=*(const s16x8*)&Al[(wr*64+i*16+rA)*LK+kg];
    }
    #pragma unroll
    for(int j=0;j<2;j++){
      fbuh[j]=*(const s16x8*)&Buh[(wc*32+j*16+rA)*LK+kg];
      fbul[j]=*(const s16x8*)&Bul[(wc*32+j*16+rA)*LK+kg];
      fbgh[j]=*(const s16x8*)&Bgh[(wc*32+j*16+rA)*LK+kg];
      fbgl[j]=*(const s16x8*)&Bgl[(wc*32+j*16+rA)*LK+kg];
    }
    #pragma unroll
    for(int i=0;i<4;i++)
      #pragma unroll
      for(int j=0;j<2;j++){
        au[i][j]=__builtin_amdgcn_mfma_f32_16x16x32_bf16(fah[i],fbuh[j],au[i][j],0,0,0);
        au[i][j]=__builtin_amdgcn_mfma_f32_16x16x32_bf16(fah[i],fbul[j],au[i][j],0,0,0);
        au[i][j]=__builtin_amdgcn_mfma_f32_16x16x32_bf16(fal[i],fbuh[j],au[i][j],0,0,0);
        ag[i][j]=__builtin_amdgcn_mfma_f32_16x16x32_bf16(fah[i],fbgh[j],ag[i][j],0,0,0);
        ag[i][j]=__builtin_amdgcn_mfma_f32_16x16x32_bf16(fah[i],fbgl[j],ag[i][j],0,0,0);
        ag[i][j]=__builtin_amdgcn_mfma_f32_16x16x32_bf16(fal[i],fbgh[j],ag[i][j],0,0,0);
      }
  }

  #pragma unroll
  for(int i=0;i<4;i++){
    #pragma unroll
    for(int j=0;j<2;j++){
      const int gm0 = m0 + wr*64 + i*16 + ((lane>>4)<<2);
      const int gn  = n0 + wc*32 + j*16 + (lane&15);
      #pragma unroll
      for(int r=0;r<4;r++){
        const int gm = gm0+r;
        if(gm<ce){
          float uu=au[i][j][r], gg=ag[i][j][r];
          float sg = gg/(1.f+__expf(-gg));
          gu[(long)(e*T_+gm)*I_ + gn] = sg*uu;
        }
      }
    }
  }
}

// ---------------- MFMA GEMM: C[M,N] = A[M,K] * B[N,K]^T ----------------
// ABT: 0 = A fp32 (sp2-split on the fly if SPL), 2 = A bf16 hi/lo planes (requires SPL)
// SPL: bf16x2 split precision (B hi/lo planes, 3 MFMAs)
// EPI: 1=store f32*scale, 2=f32 +=, 7=store f32 compact per expert slot,
//      8=store f32*scale via LDS (coalesced rows)
// CM : 0=none, 1=skip blocks strictly above diagonal, 2=K-limit at m0+BM (causal PV)
// GATH: 0=dense, 3=expert-slot mode (bid.x -> (e,mslot); A compact rows, clamp; B += e*zB)
template<int BM,int BN,int WM,int WN,int ABT,bool SPL,int EPI,int CM,int GATH>
__launch_bounds__(WM*WN*64)
__global__ void k_gemm(const void* __restrict__ Ap, const void* __restrict__ A2p,
                       const u16* __restrict__ Bhip, const u16* __restrict__ Blop,
                       void* __restrict__ Cp, const void* __restrict__ auxp,
                       const int* __restrict__ ridxp, const int* __restrict__ cntp,
                       int Kdim, int lda, int ldb, int ldc,
                       long zA, long zB, int zBdiv, long zC,
                       float scale, int eidx)
{
  static_assert(!(ABT==2 && !SPL), "plane-A requires split");
  constexpr int NT = WM*WN*64;
  constexpr int BK = 32;
  constexpr int LK = BK+8;
  constexpr int WMT = BM/WM, WNT = BN/WN;
  constexpr int MF = WMT/16, NF = WNT/16;
  constexpr int ACH = (BM*BK)/(NT*8);
  constexpr int BCH = (BN*BK)/(NT*8);
  constexpr int PL = SPL?2:1;
  static_assert(ACH>=1 && BCH>=1, "staging chunks");
  __shared__ alignas(16) u16 As[PL*BM*LK];
  __shared__ alignas(16) u16 Bs[PL*BN*LK];
  __shared__ float Cs[EPI==8?WM:1][EPI==8?16:1][EPI==8?(BN+4):1];
  int m0, eid_ = eidx, cnt = 0;
  if constexpr (GATH==3){
    eid_ = blockIdx.x>>4; m0 = (blockIdx.x&15)*BM;
    cnt = cntp[eid_]; if(m0>=cnt) return;
  } else {
    m0 = blockIdx.x*BM;
  }
  const int n0 = blockIdx.y*BN;
  if (CM==1 && n0 > m0) return;
  const int z = blockIdx.z;
  const int tid = threadIdx.x, lane = tid&63, w = tid>>6;
  const int wr = w/WN, wc = w%WN;
  const float* Af = (const float*)Ap + (long)z*zA + (GATH==3 ? (long)eid_*T_*lda : 0);
  const u16*  Ahi = (const u16*)Ap + (long)z*zA;
  const u16*  Alo = (const u16*)A2p + (long)z*zA;
  const u16*  Bh  = Bhip + (long)(z/zBdiv)*zB + (GATH==3 ? (long)eid_*zB : 0);
  const u16*  Bl  = SPL ? (Blop + (long)(z/zBdiv)*zB + (GATH==3 ? (long)eid_*zB : 0)) : (const u16*)nullptr;

  f32x4 acc[MF][NF];
  #pragma unroll
  for(int i=0;i<MF;i++)
    #pragma unroll
    for(int j=0;j<NF;j++){ f32x4 zv={0.f,0.f,0.f,0.f}; acc[i][j]=zv; }

  int ktend = Kdim/BK;
  if (CM==2){ int lim=(m0+BM)/BK; if(lim<ktend) ktend=lim; }

  for(int kt=0;kt<ktend;kt++){
    const int k0 = kt*BK;
    uint4 avh[ACH], avl[ACH], bvh[BCH], bvl[BCH];
    #pragma unroll
    for(int s=0;s<ACH;s++){
      int c = s*NT+tid; int row=c>>2; int kc=(c&3)*8;
      int arow = m0+row;
      if constexpr (GATH==3){ arow = arow < cnt ? arow : cnt-1; }
      if constexpr (ABT==2){
        avh[s] = *(const uint4*)(Ahi + (long)arow*lda + k0+kc);
        avl[s] = *(const uint4*)(Alo + (long)arow*lda + k0+kc);
      } else {
        const float* pA = Af + (long)arow*lda + k0+kc;
        float4 X=*(const float4*)pA, Y=*(const float4*)(pA+4);
        if constexpr (SPL){
          sp2(X.x,X.y,avh[s].x,avl[s].x); sp2(X.z,X.w,avh[s].y,avl[s].y);
          sp2(Y.x,Y.y,avh[s].z,avl[s].z); sp2(Y.z,Y.w,avh[s].w,avl[s].w);
        } else {
          avh[s].x=pk2(X.x,X.y); avh[s].y=pk2(X.z,X.w); avh[s].z=pk2(Y.x,Y.y); avh[s].w=pk2(Y.z,Y.w);
        }
      }
    }
    #pragma unroll
    for(int s=0;s<BCH;s++){
      int c = s*NT+tid; int row=c>>2; int kc=(c&3)*8;
      bvh[s] = *(const uint4*)(Bh + (long)(n0+row)*ldb + k0+kc);
      if constexpr (SPL) bvl[s] = *(const uint4*)(Bl + (long)(n0+row)*ldb + k0+kc);
    }
    __syncthreads();
    #pragma unroll
    for(int s=0;s<ACH;s++){ int c=s*NT+tid; int row=c>>2; int kc=(c&3)*8;
      *(uint4*)&As[row*LK+kc] = avh[s];
      if constexpr (SPL) *(uint4*)&As[BM*LK + row*LK+kc] = avl[s]; }
    #pragma unroll
    for(int s=0;s<BCH;s++){ int c=s*NT+tid; int row=c>>2; int kc=(c&3)*8;
      *(uint4*)&Bs[row*LK+kc] = bvh[s];
      if constexpr (SPL) *(uint4*)&Bs[BN*LK + row*LK+kc] = bvl[s]; }
    __syncthreads();
    s16x8 ah[MF], bh[NF], al[MF], bl[NF];
    const int rA = lane&15, kg=(lane>>4)*8;
    #pragma unroll
    for(int i=0;i<MF;i++){
      ah[i]=*(const s16x8*)&As[(wr*WMT+i*16+rA)*LK+kg];
      if constexpr (SPL) al[i]=*(const s16x8*)&As[BM*LK+(wr*WMT+i*16+rA)*LK+kg];
    }
    #pragma unroll
    for(int j=0;j<NF;j++){
      bh[j]=*(const s16x8*)&Bs[(wc*WNT+j*16+rA)*LK+kg];
      if constexpr (SPL) bl[j]=*(const s16x8*)&Bs[BN*LK+(wc*WNT+j*16+rA)*LK+kg];
    }
    #pragma unroll
    for(int i=0;i<MF;i++)
      #pragma unroll
      for(int j=0;j<NF;j++){
        acc[i][j]=__builtin_amdgcn_mfma_f32_16x16x32_bf16(ah[i],bh[j],acc[i][j],0,0,0);
        if constexpr (SPL){
          acc[i][j]=__builtin_amdgcn_mfma_f32_16x16x32_bf16(ah[i],bl[j],acc[i][j],0,0,0);
          acc[i][j]=__builtin_amdgcn_mfma_f32_16x16x32_bf16(al[i],bh[j],acc[i][j],0,0,0);
        }
      }
  }

  if constexpr (EPI==8){
    float* C = (float*)Cp + (long)z*zC;
    #pragma unroll
    for(int i=0;i<MF;i++){
      __syncthreads();
      #pragma unroll
      for(int j=0;j<NF;j++)
        #pragma unroll
        for(int r=0;r<4;r++)
          Cs[wr][((lane>>4)<<2)+r][wc*WNT + j*16 + (lane&15)] = acc[i][j][r]*scale;
      __syncthreads();
      const int rrow = tid>>3;
      const int wri = rrow>>4, r16 = rrow&15;
      const long gm = m0 + wri*WMT + i*16 + r16;
      #pragma unroll
      for(int s=0;s<BN/32;s++){
        int c0 = ((tid&7) + s*8)*4;
        float4 vv = { Cs[wri][r16][c0], Cs[wri][r16][c0+1], Cs[wri][r16][c0+2], Cs[wri][r16][c0+3] };
        *(float4*)(C + gm*ldc + n0 + c0) = vv;
      }
    }
    return;
  }

  #pragma unroll
  for(int i=0;i<MF;i++){
    #pragma unroll
    for(int j=0;j<NF;j++){
      const int gm0 = m0 + wr*WMT + i*16 + ((lane>>4)<<2);
      const int gn  = n0 + wc*WNT + j*16 + (lane&15);
      #pragma unroll
      for(int r=0;r<4;r++){
        const int gm = gm0+r;
        const float v = acc[i][j][r];
        const bool live = (GATH==0) || (gm < cnt);
        if constexpr (EPI==1){
          if(live) ((float*)Cp + (long)z*zC)[(long)gm*ldc+gn] = v*scale;
        } else if constexpr (EPI==2){
          float* C = (float*)Cp; C[(long)gm*ldc+gn] += v;
        } else if constexpr (EPI==7){
          if(live) ((float*)Cp)[(long)(eid_*T_+gm)*ldc+gn] = v*scale;
        }
      }
    }
  }
}

extern "C" void kernel_launch(void* const* d_in, const int* in_sizes, int n_in,
                              void* d_out, int out_size, void* d_ws, size_t ws_size,
                              hipStream_t stream)
{
  (void)in_sizes; (void)n_in; (void)out_size;
  const int*   ids   = (const int*)d_in[0];
  const float* emb   = (const float*)d_in[1];
  const float* Wq    = (const float*)d_in[2];
  const float* Wk    = (const float*)d_in[3];
  const float* Wv    = (const float*)d_in[4];
  const float* Wo    = (const float*)d_in[5];
  const float* ln1   = (const float*)d_in[6];
  const float* ln2   = (const float*)d_in[7];
  const float* gate  = (const float*)d_in[8];
  const float* Wg    = (const float*)d_in[9];
  const float* Wu    = (const float*)d_in[10];
  const float* Wd    = (const float*)d_in[11];
  const float* normw = (const float*)d_in[12];
  const float* lmh   = (const float*)d_in[13];

  char* p = (char*)d_ws;
  auto carve = [&](size_t bytes)->void*{ void* r=p; p += (bytes+255)&~(size_t)255; return r; };
  float* h    = (float*)carve((size_t)T_*H_*4);
  float* x    = (float*)carve((size_t)T_*H_*4);
  u16*   xhi  = (u16*)  carve((size_t)T_*H_*2);
  u16*   xlo  = (u16*)  carve((size_t)T_*H_*2);
  u16*   qhi  = (u16*)  carve((size_t)T_*NHD*2);
  u16*   qlo  = (u16*)  carve((size_t)T_*NHD*2);
  u16*   khi  = (u16*)  carve((size_t)T_*KVD*2);
  u16*   klo  = (u16*)  carve((size_t)T_*KVD*2);
  u16*   vthi = (u16*)  carve((size_t)T_*KVD*2);
  u16*   vtlo = (u16*)  carve((size_t)T_*KVD*2);
  float* o    = (float*)carve((size_t)T_*NHD*4);
  float* comb = (float*)carve((size_t)T_*4*4);
  int*   cnt  = (int*)  carve((size_t)16*4);
  int*   lists= (int*)  carve((size_t)4*T_*4);
  int2*  epos = (int2*) carve((size_t)T_*8);
  float* U    = (float*)carve((size_t)96*1024*1024);   // union: sc16(67MB) | gu(64MB)+eo(32MB)
  u16*   wp   = (u16*)  carve((size_t)56623104*2);
  if ((size_t)(p - (char*)d_ws) > ws_size) return;

  float* sc = U;
  float* gu = U;
  float* eo = U + (size_t)16*1024*1024;

  u16 *WqkvTh = wp,          *WqkvTl = wp+2097152;     // [2048][1024]: rows 0-1023 q, 1024-1535 k, 1536-2047 v
  u16 *WoTh = wp+4194304,    *WoTl = wp+5242880;
  u16 *WgTh = wp+6291456,    *WgTl = wp+14680064;
  u16 *WuTh = wp+23068672,   *WuTl = wp+31457280;
  u16 *WdTh = wp+39845888,   *WdTl = wp+48234496;

  dim3 tb(32,8);

  k_embed<<<T_,256,0,stream>>>(ids, emb, h);
  k_zero<<<1,64,0,stream>>>(cnt);

  for(int l=0;l<4;l++){
    k_transpose<<<dim3(32,32),tb,0,stream>>>(Wq+(size_t)l*H_*NHD, WqkvTh, WqkvTl, H_, NHD, 0,0);
    k_transpose<<<dim3(16,32),tb,0,stream>>>(Wk+(size_t)l*H_*KVD, WqkvTh+1048576, WqkvTl+1048576, H_, KVD, 0,0);
    k_transpose<<<dim3(16,32),tb,0,stream>>>(Wv+(size_t)l*H_*KVD, WqkvTh+1572864, WqkvTl+1572864, H_, KVD, 0,0);
    k_transpose<<<dim3(32,32),tb,0,stream>>>(Wo+(size_t)l*NHD*H_, WoTh, WoTl, NHD, H_, 0,0);
    k_transpose<<<dim3(64,32,4),tb,0,stream>>>(Wg+(size_t)l*4*H_*I_, WgTh, WgTl, H_, I_, (long)H_*I_, (long)I_*H_);
    k_transpose<<<dim3(64,32,4),tb,0,stream>>>(Wu+(size_t)l*4*H_*I_, WuTh, WuTl, H_, I_, (long)H_*I_, (long)I_*H_);
    k_transpose<<<dim3(32,64,4),tb,0,stream>>>(Wd+(size_t)l*4*I_*H_, WdTh, WdTl, I_, H_, (long)I_*H_, (long)H_*I_);

    k_rms_sp<<<T_/4,256,0,stream>>>(h, ln1+(size_t)l*H_, xhi, xlo);

    // fused QKV: one full-occupancy GEMM, split epilogue to planes
    k_qkv<<<dim3(16,16),256,0,stream>>>(xhi, xlo, WqkvTh, WqkvTl, qhi, qlo, khi, klo, vthi, vtlo);

    // attention, batched over 16 heads per b (z = head)
    for(int b=0;b<2;b++){
      const u16* Aqh = qhi + (size_t)b*S_*NHD;
      const u16* Aql = qlo + (size_t)b*S_*NHD;
      const u16* Bkh = khi + (size_t)b*S_*KVD;
      const u16* Bkl = klo + (size_t)b*S_*KVD;
      k_gemm<128,128,2,2,2,true,1,1,0><<<dim3(8,8,16),256,0,stream>>>(Aqh, Aql, Bkh, Bkl, sc, nullptr, nullptr, nullptr, 64, NHD, KVD, S_, 64, 64, 2, (long)S_*S_, 0.125f, 0);
      k_softmax<<<dim3(256,16),256,0,stream>>>(sc);
      const u16* Bvh = vthi + (size_t)b*S_*KVD;
      const u16* Bvl = vtlo + (size_t)b*S_*KVD;
      float* Co = o + (size_t)b*S_*NHD;
      k_gemm<64,64,2,2,0,true,1,2,0><<<dim3(16,1,16),256,0,stream>>>(sc, nullptr, Bvh, Bvl, Co, nullptr, nullptr, nullptr, S_, S_, S_, NHD, (long)S_*S_, (long)64*S_, 2, 64, 1.f, 0);
    }

    // o @ Wo += h (BM=64 for full occupancy: 32x8=256 blocks)
    k_gemm<64,128,2,2,0,true,2,0,0><<<dim3(32,8,1),256,0,stream>>>(o, nullptr, WoTh, WoTl, h, nullptr, nullptr, nullptr, NHD, NHD,NHD,H_, 0,0,1,0, 0.f,0);

    k_router<<<T_/4,256,0,stream>>>(h, ln2+(size_t)l*H_, gate+(size_t)l*H_*4, comb, lists, cnt+l*4, epos);
    k_rms_sp<<<T_/4,256,0,stream>>>(h, ln2+(size_t)l*H_, xhi, xlo);

    k_moe_ug<<<dim3(64,32),256,0,stream>>>(xhi, xlo, WuTh, WuTl, WgTh, WgTl, gu, lists, cnt+l*4);
    k_gemm<128,128,2,2,0,true,7,0,3><<<dim3(64,8),256,0,stream>>>(gu, nullptr, WdTh, WdTl, eo, nullptr, lists, cnt+l*4, I_, I_,I_,H_, 0,(long)I_*H_,1,0, 1.f,0);
    k_combine<<<T_,256,0,stream>>>(h, eo, epos, comb);
  }

  k_rms<<<T_/4,256,0,stream>>>(h, normw, x);
  k_transpose<<<dim3(1000,32),tb,0,stream>>>(lmh, wp, nullptr, H_, V_, 0,0);
  k_gemm<128,128,2,2,0,false,8,0,0><<<dim3(16,250,1),256,0,stream>>>(x, nullptr, wp, nullptr, (float*)d_out, nullptr, nullptr, nullptr, H_, H_,H_,V_, 0,0,1,0, 1.f,0);
}

// Round 8
// 2798.296 us; speedup vs baseline: 2.8128x; 1.5851x over previous
//
#include <hip/hip_runtime.h>

#define T_ 2048
#define H_ 1024
#define S_ 1024
#define V_ 32000
#define I_ 2048
#define NHD 1024   // NH*HD
#define KVD 512    // NKV*HD

typedef unsigned short u16;
typedef unsigned int u32;
typedef __attribute__((ext_vector_type(8))) short s16x8;
typedef __attribute__((ext_vector_type(4))) float f32x4;

__device__ __forceinline__ u16 f2b(float f){ u32 x=__builtin_bit_cast(u32,f); return (u16)((x+0x7fffu+((x>>16)&1u))>>16); }
__device__ __forceinline__ float b2f(u16 u){ return __builtin_bit_cast(float,(u32)u<<16); }
__device__ __forceinline__ float wsum(float v){ for(int o=32;o;o>>=1) v+=__shfl_xor(v,o); return v; }
__device__ __forceinline__ float wmax(float v){ for(int o=32;o;o>>=1) v=fmaxf(v,__shfl_xor(v,o)); return v; }

// async global->LDS, 16B per lane; LDS dest = wave-uniform base + lane*16
__device__ __forceinline__ void gl16(const void* g, void* l){
  __builtin_amdgcn_global_load_lds(
      (const __attribute__((address_space(1))) unsigned int*)g,
      (__attribute__((address_space(3))) unsigned int*)l, 16, 0, 0);
}

// ---------------- embedding gather ----------------
__global__ void k_embed(const int* __restrict__ ids, const float* __restrict__ emb, float* __restrict__ h){
  int t = blockIdx.x;
  long src = (long)ids[t]*H_;
  ((float4*)(h + (long)t*H_))[threadIdx.x] = ((const float4*)(emb+src))[threadIdx.x];
}

__global__ void k_zero(int* c){ if(threadIdx.x<16) c[threadIdx.x]=0; }

// ---------------- rmsnorm: fp32 -> bf16 hi/lo planes ----------------
__global__ void k_rms_sp(const float* __restrict__ h, const float* __restrict__ w,
                         u16* __restrict__ xhi, u16* __restrict__ xlo){
  int wid = threadIdx.x>>6, lane = threadIdx.x&63;
  int t = blockIdx.x*4 + wid;
  const float* row = h + (long)t*H_;
  float v[16]; float ss=0.f;
  #pragma unroll
  for(int j=0;j<16;j++){ v[j]=row[j*64+lane]; ss += v[j]*v[j]; }
  ss = wsum(ss);
  float rstd = rsqrtf(ss/(float)H_ + 1e-6f);
  #pragma unroll
  for(int j=0;j<16;j++){
    int idx=j*64+lane;
    float y = v[j]*rstd*w[idx];
    u16 hv = f2b(y);
    xhi[(long)t*H_+idx] = hv;
    xlo[(long)t*H_+idx] = f2b(y - b2f(hv));
  }
}

// ---------------- router (fp32) + expert list build ----------------
__global__ void k_router(const float* __restrict__ h, const float* __restrict__ lw,
                         const float* __restrict__ gate, float* __restrict__ comb,
                         int* __restrict__ lists, int* __restrict__ cnt, int2* __restrict__ epos){
  int wid = threadIdx.x>>6, lane = threadIdx.x&63;
  int t = blockIdx.x*4+wid;
  const float* row = h + (long)t*H_;
  float v[16]; float ss=0.f;
  #pragma unroll
  for(int j=0;j<16;j++){ v[j]=row[j*64+lane]; ss+=v[j]*v[j]; }
  ss = wsum(ss);
  float rstd = rsqrtf(ss/(float)H_+1e-6f);
  float a0=0,a1=0,a2=0,a3=0;
  #pragma unroll
  for(int j=0;j<16;j++){
    int idx=j*64+lane;
    float xv = v[j]*rstd*lw[idx];
    float4 g4 = ((const float4*)gate)[idx];
    a0 += xv*g4.x; a1 += xv*g4.y; a2 += xv*g4.z; a3 += xv*g4.w;
  }
  a0=wsum(a0); a1=wsum(a1); a2=wsum(a2); a3=wsum(a3);
  if(lane==0){
    float p[4]={a0,a1,a2,a3};
    float m = fmaxf(fmaxf(p[0],p[1]),fmaxf(p[2],p[3]));
    float s=0; for(int e=0;e<4;e++){ p[e]=__expf(p[e]-m); s+=p[e]; }
    for(int e=0;e<4;e++) p[e]/=s;
    int i1=0; for(int e=1;e<4;e++) if(p[e]>p[i1]) i1=e;
    int i2=-1; for(int e=0;e<4;e++){ if(e==i1) continue; if(i2<0||p[e]>p[i2]) i2=e; }
    float* c = comb + (long)t*4;
    for(int e=0;e<4;e++) c[e] = (e==i1||e==i2)? p[e] : 0.f;
    int p1 = atomicAdd(&cnt[i1],1); lists[i1*T_+p1]=t;
    int p2 = atomicAdd(&cnt[i2],1); lists[i2*T_+p2]=t;
    epos[t] = make_int2((p1<<2)|i1, (p2<<2)|i2);
  }
}

// ---------------- causal row softmax: fp32 in -> bf16 hi/lo planes out ----------------
__global__ void k_softmax(const float* __restrict__ sc, u16* __restrict__ ph, u16* __restrict__ pl){
  int wid=threadIdx.x>>6, lane=threadIdx.x&63;
  int r = blockIdx.x*4+wid;
  long base = (long)blockIdx.y*((long)S_*S_) + (long)r*S_;
  const float* row = sc + base;
  float e[16]; float mx=-3.4e38f;
  #pragma unroll
  for(int j=0;j<16;j++){ int idx=j*64+lane; float vv=row[idx]; vv = (idx<=r)? vv : -3.4e38f; e[j]=vv; mx=fmaxf(mx,vv); }
  mx = wmax(mx);
  float s=0.f;
  #pragma unroll
  for(int j=0;j<16;j++){ int idx=j*64+lane; float vv = (idx<=r)? __expf(e[j]-mx) : 0.f; e[j]=vv; s+=vv; }
  s = wsum(s);
  float inv = 1.f/s;
  #pragma unroll
  for(int j=0;j<16;j++){
    float y = e[j]*inv;
    u16 hv = f2b(y);
    ph[base + j*64+lane] = hv;
    pl[base + j*64+lane] = f2b(y - b2f(hv));
  }
}

// ---------------- transpose+split: fp32 [R][C] -> bf16 hi(+lo) [C][R] ----------------
__global__ void k_transpose(const float* __restrict__ in, u16* __restrict__ hi, u16* __restrict__ lo,
                            int R, int C, long zi, long zo){
  __shared__ float tile[32][33];
  in += (long)blockIdx.z*zi; hi += (long)blockIdx.z*zo; if(lo) lo += (long)blockIdx.z*zo;
  int c0 = blockIdx.x*32, r0 = blockIdx.y*32;
  int tx = threadIdx.x, ty = threadIdx.y;
  #pragma unroll
  for(int i=0;i<4;i++) tile[ty+8*i][tx] = in[(long)(r0+ty+8*i)*C + c0+tx];
  __syncthreads();
  #pragma unroll
  for(int i=0;i<4;i++){
    int cc=ty+8*i; float v = tile[tx][cc];
    u16 hv = f2b(v);
    long idx = (long)(c0+cc)*R + r0+tx;
    hi[idx] = hv;
    if(lo) lo[idx] = f2b(v - b2f(hv));
  }
}

// ---------------- MoE combine: h[t] += c1*eo[e1,p1] + c2*eo[e2,p2] ----------------
__global__ void k_combine(float* __restrict__ h, const float* __restrict__ eo,
                          const int2* __restrict__ epos, const float* __restrict__ comb){
  int t = blockIdx.x, c = threadIdx.x;
  int2 ep = epos[t];
  int e1 = ep.x&3, p1 = ep.x>>2, e2 = ep.y&3, p2 = ep.y>>2;
  float c1 = comb[t*4+e1], c2 = comb[t*4+e2];
  float4 a = ((const float4*)(eo + (long)(e1*T_+p1)*H_))[c];
  float4 b = ((const float4*)(eo + (long)(e2*T_+p2)*H_))[c];
  float4* hp = (float4*)(h + (long)t*H_) + c;
  float4 hv = *hp;
  hv.x += c1*a.x + c2*b.x; hv.y += c1*a.y + c2*b.y;
  hv.z += c1*a.z + c2*b.z; hv.w += c1*a.w + c2*b.w;
  *hp = hv;
}

// ---------------- fused QKV GEMM (gload staging): x @ [Wq|Wk|Wv] -> split planes ----------------
__global__ __launch_bounds__(256) void k_qkv(
  const u16* __restrict__ xhi, const u16* __restrict__ xlo,
  const u16* __restrict__ Bh, const u16* __restrict__ Bl,
  u16* __restrict__ qhi, u16* __restrict__ qlo,
  u16* __restrict__ khi, u16* __restrict__ klo,
  u16* __restrict__ vthi, u16* __restrict__ vtlo)
{
  constexpr int BK=32;
  __shared__ alignas(16) u16 As[2*128*32], Bs[2*128*32];
  const int m0=blockIdx.x*128, n0=blockIdx.y*128;
  const int tid=threadIdx.x, lane=tid&63, w=tid>>6, wr=w>>1, wc=w&1;
  const int col8 = (lane&3)*8, rsub = lane>>2;
  f32x4 acc[4][4];
  #pragma unroll
  for(int i=0;i<4;i++)
    #pragma unroll
    for(int j=0;j<4;j++){ f32x4 zv={0.f,0.f,0.f,0.f}; acc[i][j]=zv; }

  for(int kt=0;kt<H_/BK;kt++){
    const int k0=kt*BK;
    __syncthreads();
    #pragma unroll
    for(int s=0;s<2;s++){
      int ch = s*4+w; int row = ch*16 + rsub;
      gl16(xhi + (long)(m0+row)*H_ + k0+col8, &As[ch*512]);
      gl16(xlo + (long)(m0+row)*H_ + k0+col8, &As[4096+ch*512]);
      gl16(Bh  + (long)(n0+row)*H_ + k0+col8, &Bs[ch*512]);
      gl16(Bl  + (long)(n0+row)*H_ + k0+col8, &Bs[4096+ch*512]);
    }
    __syncthreads();
    s16x8 ah[4],al[4],bh[4],bl[4];
    const int rA=lane&15, kg=(lane>>4)*8;
    #pragma unroll
    for(int i=0;i<4;i++){
      ah[i]=*(const s16x8*)&As[(wr*64+i*16+rA)*32+kg];
      al[i]=*(const s16x8*)&As[4096+(wr*64+i*16+rA)*32+kg];
    }
    #pragma unroll
    for(int j=0;j<4;j++){
      bh[j]=*(const s16x8*)&Bs[(wc*64+j*16+rA)*32+kg];
      bl[j]=*(const s16x8*)&Bs[4096+(wc*64+j*16+rA)*32+kg];
    }
    #pragma unroll
    for(int i=0;i<4;i++)
      #pragma unroll
      for(int j=0;j<4;j++){
        acc[i][j]=__builtin_amdgcn_mfma_f32_16x16x32_bf16(ah[i],bh[j],acc[i][j],0,0,0);
        acc[i][j]=__builtin_amdgcn_mfma_f32_16x16x32_bf16(ah[i],bl[j],acc[i][j],0,0,0);
        acc[i][j]=__builtin_amdgcn_mfma_f32_16x16x32_bf16(al[i],bh[j],acc[i][j],0,0,0);
      }
  }

  #pragma unroll
  for(int i=0;i<4;i++){
    #pragma unroll
    for(int j=0;j<4;j++){
      const int gm0 = m0 + wr*64 + i*16 + ((lane>>4)<<2);
      const int gn  = n0 + wc*64 + j*16 + (lane&15);
      #pragma unroll
      for(int r=0;r<4;r++){
        const int gm = gm0+r;
        float v = acc[i][j][r];
        u16 hv = f2b(v);
        u16 lv = f2b(v - b2f(hv));
        if(gn < 1024){
          long idx=(long)gm*NHD+gn; qhi[idx]=hv; qlo[idx]=lv;
        } else if(gn < 1536){
          long idx=(long)gm*KVD+(gn-1024); khi[idx]=hv; klo[idx]=lv;
        } else {
          long idx=((long)(gm>>10)<<19) + (long)(gn-1536)*S_ + (gm&1023);
          vthi[idx]=hv; vtlo[idx]=lv;
        }
      }
    }
  }
}

// ---------------- fused MoE up+gate (gload): silu(x@Wg)*(x@Wu) -> gu planes ----------------
__global__ __launch_bounds__(256) void k_moe_ug(
  const u16* __restrict__ xhi, const u16* __restrict__ xlo,
  const u16* __restrict__ Wuh, const u16* __restrict__ Wul,
  const u16* __restrict__ Wgh, const u16* __restrict__ Wgl,
  u16* __restrict__ guh, u16* __restrict__ gul,
  const int* __restrict__ lists, const int* __restrict__ cntp)
{
  constexpr int BK=32;
  const int e = blockIdx.x>>4, m0=(blockIdx.x&15)*128;
  const int ce = cntp[e];
  if(m0>=ce) return;
  const int n0 = blockIdx.y*64;
  const int* ridx = lists + e*T_;
  const u16* Buh_g = Wuh + (size_t)e*H_*I_;
  const u16* Bul_g = Wul + (size_t)e*H_*I_;
  const u16* Bgh_g = Wgh + (size_t)e*H_*I_;
  const u16* Bgl_g = Wgl + (size_t)e*H_*I_;
  __shared__ alignas(16) u16 Ah[128*32], Al[128*32];
  __shared__ alignas(16) u16 Buh[64*32], Bul[64*32], Bgh[64*32], Bgl[64*32];
  const int tid=threadIdx.x, lane=tid&63, w=tid>>6;
  const int wr=w>>1, wc=w&1;
  const int col8=(lane&3)*8, rsub=lane>>2;
  int arA[2];
  #pragma unroll
  for(int s=0;s<2;s++){ int idx=m0 + (s*4+w)*16 + rsub; arA[s]=ridx[idx<ce?idx:ce-1]; }
  const int brow = n0 + w*16 + rsub;
  f32x4 au[4][2], ag[4][2];
  #pragma unroll
  for(int i=0;i<4;i++)
    #pragma unroll
    for(int j=0;j<2;j++){ f32x4 zv={0.f,0.f,0.f,0.f}; au[i][j]=zv; ag[i][j]=zv; }

  for(int kt=0;kt<H_/BK;kt++){
    const int k0=kt*BK;
    __syncthreads();
    #pragma unroll
    for(int s=0;s<2;s++){
      int ch=s*4+w;
      gl16(xhi + (long)arA[s]*H_ + k0+col8, &Ah[ch*512]);
      gl16(xlo + (long)arA[s]*H_ + k0+col8, &Al[ch*512]);
    }
    gl16(Buh_g + (long)brow*H_ + k0+col8, &Buh[w*512]);
    gl16(Bul_g + (long)brow*H_ + k0+col8, &Bul[w*512]);
    gl16(Bgh_g + (long)brow*H_ + k0+col8, &Bgh[w*512]);
    gl16(Bgl_g + (long)brow*H_ + k0+col8, &Bgl[w*512]);
    __syncthreads();
    s16x8 fah[4],fal[4],fbuh[2],fbul[2],fbgh[2],fbgl[2];
    const int rA=lane&15, kg=(lane>>4)*8;
    #pragma unroll
    for(int i=0;i<4;i++){
      fah[i]=*(const s16x8*)&Ah[(wr*64+i*16+rA)*32+kg];
      fal[i]=*(const s16x8*)&Al[(wr*64+i*16+rA)*32+kg];
    }
    #pragma unroll
    for(int j=0;j<2;j++){
      fbuh[j]=*(const s16x8*)&Buh[(wc*32+j*16+rA)*32+kg];
      fbul[j]=*(const s16x8*)&Bul[(wc*32+j*16+rA)*32+kg];
      fbgh[j]=*(const s16x8*)&Bgh[(wc*32+j*16+rA)*32+kg];
      fbgl[j]=*(const s16x8*)&Bgl[(wc*32+j*16+rA)*32+kg];
    }
    #pragma unroll
    for(int i=0;i<4;i++)
      #pragma unroll
      for(int j=0;j<2;j++){
        au[i][j]=__builtin_amdgcn_mfma_f32_16x16x32_bf16(fah[i],fbuh[j],au[i][j],0,0,0);
        au[i][j]=__builtin_amdgcn_mfma_f32_16x16x32_bf16(fah[i],fbul[j],au[i][j],0,0,0);
        au[i][j]=__builtin_amdgcn_mfma_f32_16x16x32_bf16(fal[i],fbuh[j],au[i][j],0,0,0);
        ag[i][j]=__builtin_amdgcn_mfma_f32_16x16x32_bf16(fah[i],fbgh[j],ag[i][j],0,0,0);
        ag[i][j]=__builtin_amdgcn_mfma_f32_16x16x32_bf16(fah[i],fbgl[j],ag[i][j],0,0,0);
        ag[i][j]=__builtin_amdgcn_mfma_f32_16x16x32_bf16(fal[i],fbgh[j],ag[i][j],0,0,0);
      }
  }

  #pragma unroll
  for(int i=0;i<4;i++){
    #pragma unroll
    for(int j=0;j<2;j++){
      const int gm0 = m0 + wr*64 + i*16 + ((lane>>4)<<2);
      const int gn  = n0 + wc*32 + j*16 + (lane&15);
      #pragma unroll
      for(int r=0;r<4;r++){
        const int gm = gm0+r;
        if(gm<ce){
          float uu=au[i][j][r], gg=ag[i][j][r];
          float val = (gg/(1.f+__expf(-gg)))*uu;
          long idx = (long)(e*T_+gm)*I_ + gn;
          u16 hv=f2b(val);
          guh[idx]=hv; gul[idx]=f2b(val-b2f(hv));
        }
      }
    }
  }
}

// ---------------- generic MFMA GEMM (A,B = bf16 planes, gload staging) ----------------
// SPL: bf16x2 split (hi/lo planes, 3 MFMAs); EPI: 1=f32*scale, 2=f32 +=,
//      7=f32 compact expert slot, 8=f32 via LDS coalesced, 9=split planes (Cp=hi,auxp=lo)
// CM : 0=none, 1=skip blocks above diagonal, 2=K-limit at m0+BM
// GATH: 0=dense, 3=expert-slot mode (bid.x->(e,mslot); clamp A rows; A,B += e offsets)
template<int BM,int BN,int WM,int WN,bool SPL,int EPI,int CM,int GATH>
__launch_bounds__(WM*WN*64)
__global__ void k_gemm(const u16* __restrict__ Ahip, const u16* __restrict__ Alop,
                       const u16* __restrict__ Bhip, const u16* __restrict__ Blop,
                       void* __restrict__ Cp, void* __restrict__ auxp,
                       const int* __restrict__ cntp,
                       int Kdim, int lda, int ldb, int ldc,
                       long zA, long zB, int zBdiv, long zC,
                       float scale)
{
  constexpr int NT = WM*WN*64;
  constexpr int Wv = NT/64;
  constexpr int BK = 32;
  constexpr int WMT = BM/WM, WNT = BN/WN;
  constexpr int MF = WMT/16, NF = WNT/16;
  constexpr int ACn = BM/(16*Wv);
  constexpr int BCn = BN/(16*Wv);
  static_assert(ACn>=1 && BCn>=1, "chunks");
  __shared__ alignas(16) u16 As[(SPL?2:1)*BM*32];
  __shared__ alignas(16) u16 Bs[(SPL?2:1)*BN*32];
  __shared__ float Cs[EPI==8?WM:1][EPI==8?16:1][EPI==8?(BN+4):1];
  int m0, eid_ = 0, cnt = 0;
  if constexpr (GATH==3){
    eid_ = blockIdx.x>>4; m0 = (blockIdx.x&15)*BM;
    cnt = cntp[eid_]; if(m0>=cnt) return;
  } else {
    m0 = blockIdx.x*BM;
  }
  const int n0 = blockIdx.y*BN;
  if (CM==1 && n0 > m0) return;
  const int z = blockIdx.z;
  const int tid = threadIdx.x, lane = tid&63, w = tid>>6;
  const int wr = w/WN, wc = w%WN;
  const int col8 = (lane&3)*8, rsub = lane>>2;
  const u16* Ahi = Ahip + (long)z*zA + (GATH==3 ? (long)eid_*T_*lda : 0);
  const u16* Alo = SPL ? (Alop + (long)z*zA + (GATH==3 ? (long)eid_*T_*lda : 0)) : (const u16*)nullptr;
  const u16* Bh  = Bhip + (long)(z/zBdiv)*zB + (GATH==3 ? (long)eid_*zB : 0);
  const u16* Bl  = SPL ? (Blop + (long)(z/zBdiv)*zB + (GATH==3 ? (long)eid_*zB : 0)) : (const u16*)nullptr;

  f32x4 acc[MF][NF];
  #pragma unroll
  for(int i=0;i<MF;i++)
    #pragma unroll
    for(int j=0;j<NF;j++){ f32x4 zv={0.f,0.f,0.f,0.f}; acc[i][j]=zv; }

  int ktend = Kdim/BK;
  if (CM==2){ int lim=(m0+BM)/BK; if(lim<ktend) ktend=lim; }

  for(int kt=0;kt<ktend;kt++){
    const int k0 = kt*BK;
    __syncthreads();
    #pragma unroll
    for(int s=0;s<ACn;s++){
      int ch = s*Wv + w;
      int arow = m0 + ch*16 + rsub;
      if constexpr (GATH==3){ arow = arow < cnt ? arow : cnt-1; }
      gl16(Ahi + (long)arow*lda + k0+col8, &As[ch*512]);
      if constexpr (SPL) gl16(Alo + (long)arow*lda + k0+col8, &As[BM*32 + ch*512]);
    }
    #pragma unroll
    for(int s=0;s<BCn;s++){
      int ch = s*Wv + w;
      int brow = n0 + ch*16 + rsub;
      gl16(Bh + (long)brow*ldb + k0+col8, &Bs[ch*512]);
      if constexpr (SPL) gl16(Bl + (long)brow*ldb + k0+col8, &Bs[BN*32 + ch*512]);
    }
    __syncthreads();
    s16x8 ah[MF], al[MF], bh[NF], bl[NF];
    const int rA = lane&15, kg=(lane>>4)*8;
    #pragma unroll
    for(int i=0;i<MF;i++){
      ah[i]=*(const s16x8*)&As[(wr*WMT+i*16+rA)*32+kg];
      if constexpr (SPL) al[i]=*(const s16x8*)&As[BM*32+(wr*WMT+i*16+rA)*32+kg];
    }
    #pragma unroll
    for(int j=0;j<NF;j++){
      bh[j]=*(const s16x8*)&Bs[(wc*WNT+j*16+rA)*32+kg];
      if constexpr (SPL) bl[j]=*(const s16x8*)&Bs[BN*32+(wc*WNT+j*16+rA)*32+kg];
    }
    #pragma unroll
    for(int i=0;i<MF;i++)
      #pragma unroll
      for(int j=0;j<NF;j++){
        acc[i][j]=__builtin_amdgcn_mfma_f32_16x16x32_bf16(ah[i],bh[j],acc[i][j],0,0,0);
        if constexpr (SPL){
          acc[i][j]=__builtin_amdgcn_mfma_f32_16x16x32_bf16(ah[i],bl[j],acc[i][j],0,0,0);
          acc[i][j]=__builtin_amdgcn_mfma_f32_16x16x32_bf16(al[i],bh[j],acc[i][j],0,0,0);
        }
      }
  }

  if constexpr (EPI==8){
    float* C = (float*)Cp + (long)z*zC;
    #pragma unroll
    for(int i=0;i<MF;i++){
      __syncthreads();
      #pragma unroll
      for(int j=0;j<NF;j++)
        #pragma unroll
        for(int r=0;r<4;r++)
          Cs[wr][((lane>>4)<<2)+r][wc*WNT + j*16 + (lane&15)] = acc[i][j][r]*scale;
      __syncthreads();
      const int rrow = tid>>3;
      const int wri = rrow>>4, r16 = rrow&15;
      const long gm = m0 + wri*WMT + i*16 + r16;
      #pragma unroll
      for(int s=0;s<BN/32;s++){
        int c0 = ((tid&7) + s*8)*4;
        float4 vv = { Cs[wri][r16][c0], Cs[wri][r16][c0+1], Cs[wri][r16][c0+2], Cs[wri][r16][c0+3] };
        *(float4*)(C + gm*ldc + n0 + c0) = vv;
      }
    }
    return;
  }

  #pragma unroll
  for(int i=0;i<MF;i++){
    #pragma unroll
    for(int j=0;j<NF;j++){
      const int gm0 = m0 + wr*WMT + i*16 + ((lane>>4)<<2);
      const int gn  = n0 + wc*WNT + j*16 + (lane&15);
      #pragma unroll
      for(int r=0;r<4;r++){
        const int gm = gm0+r;
        const float v = acc[i][j][r];
        const bool live = (GATH==0) || (gm < cnt);
        if constexpr (EPI==1){
          if(live) ((float*)Cp + (long)z*zC)[(long)gm*ldc+gn] = v*scale;
        } else if constexpr (EPI==2){
          float* C = (float*)Cp; C[(long)gm*ldc+gn] += v;
        } else if constexpr (EPI==7){
          if(live) ((float*)Cp)[(long)(eid_*T_+gm)*ldc+gn] = v*scale;
        } else if constexpr (EPI==9){
          u16* Ch = (u16*)Cp + (long)z*zC;
          u16* Cl = (u16*)auxp + (long)z*zC;
          long idx = (long)gm*ldc+gn;
          u16 hv = f2b(v);
          Ch[idx]=hv; Cl[idx]=f2b(v-b2f(hv));
        }
      }
    }
  }
}

extern "C" void kernel_launch(void* const* d_in, const int* in_sizes, int n_in,
                              void* d_out, int out_size, void* d_ws, size_t ws_size,
                              hipStream_t stream)
{
  (void)in_sizes; (void)n_in; (void)out_size;
  const int*   ids   = (const int*)d_in[0];
  const float* emb   = (const float*)d_in[1];
  const float* Wq    = (const float*)d_in[2];
  const float* Wk    = (const float*)d_in[3];
  const float* Wv    = (const float*)d_in[4];
  const float* Wo    = (const float*)d_in[5];
  const float* ln1   = (const float*)d_in[6];
  const float* ln2   = (const float*)d_in[7];
  const float* gate  = (const float*)d_in[8];
  const float* Wg    = (const float*)d_in[9];
  const float* Wu    = (const float*)d_in[10];
  const float* Wd    = (const float*)d_in[11];
  const float* normw = (const float*)d_in[12];
  const float* lmh   = (const float*)d_in[13];

  char* p = (char*)d_ws;
  auto carve = [&](size_t bytes)->void*{ void* r=p; p += (bytes+255)&~(size_t)255; return r; };
  float* h    = (float*)carve((size_t)T_*H_*4);
  u16*   xhi  = (u16*)  carve((size_t)T_*H_*2);
  u16*   xlo  = (u16*)  carve((size_t)T_*H_*2);
  u16*   qhi  = (u16*)  carve((size_t)T_*NHD*2);
  u16*   qlo  = (u16*)  carve((size_t)T_*NHD*2);
  u16*   khi  = (u16*)  carve((size_t)T_*KVD*2);
  u16*   klo  = (u16*)  carve((size_t)T_*KVD*2);
  u16*   vthi = (u16*)  carve((size_t)T_*KVD*2);
  u16*   vtlo = (u16*)  carve((size_t)T_*KVD*2);
  u16*   ohi  = (u16*)  carve((size_t)T_*NHD*2);
  u16*   olo  = (u16*)  carve((size_t)T_*NHD*2);
  float* comb = (float*)carve((size_t)T_*4*4);
  int*   cnt  = (int*)  carve((size_t)16*4);
  int*   lists= (int*)  carve((size_t)4*T_*4);
  int2*  epos = (int2*) carve((size_t)T_*8);
  char*  U    = (char*) carve((size_t)136*1024*1024);
  u16*   wp   = (u16*)  carve((size_t)56623104*2);
  if ((size_t)(p - (char*)d_ws) > ws_size) return;

  // attention phase: sc fp32 (67MB) + p-planes (33.5MB each)
  float* sc   = (float*)U;
  u16*   schi = (u16*)(U + 67108864);
  u16*   sclo = (u16*)(U + 100663296);
  // MoE phase (sc region dead): gu planes + eo
  u16*   guh  = (u16*)U;
  u16*   gul  = (u16*)(U + 33554432);
  float* eo   = (float*)(U + 67108864);

  u16 *WqkvTh = wp,          *WqkvTl = wp+2097152;   // [2048][1024]: q rows 0-1023, k 1024-1535, v 1536-2047
  u16 *WoTh = wp+4194304,    *WoTl = wp+5242880;
  u16 *WgTh = wp+6291456,    *WgTl = wp+14680064;
  u16 *WuTh = wp+23068672,   *WuTl = wp+31457280;
  u16 *WdTh = wp+39845888,   *WdTl = wp+48234496;

  dim3 tb(32,8);

  k_embed<<<T_,256,0,stream>>>(ids, emb, h);
  k_zero<<<1,64,0,stream>>>(cnt);

  for(int l=0;l<4;l++){
    k_transpose<<<dim3(32,32),tb,0,stream>>>(Wq+(size_t)l*H_*NHD, WqkvTh, WqkvTl, H_, NHD, 0,0);
    k_transpose<<<dim3(16,32),tb,0,stream>>>(Wk+(size_t)l*H_*KVD, WqkvTh+1048576, WqkvTl+1048576, H_, KVD, 0,0);
    k_transpose<<<dim3(16,32),tb,0,stream>>>(Wv+(size_t)l*H_*KVD, WqkvTh+1572864, WqkvTl+1572864, H_, KVD, 0,0);
    k_transpose<<<dim3(32,32),tb,0,stream>>>(Wo+(size_t)l*NHD*H_, WoTh, WoTl, NHD, H_, 0,0);
    k_transpose<<<dim3(64,32,4),tb,0,stream>>>(Wg+(size_t)l*4*H_*I_, WgTh, WgTl, H_, I_, (long)H_*I_, (long)I_*H_);
    k_transpose<<<dim3(64,32,4),tb,0,stream>>>(Wu+(size_t)l*4*H_*I_, WuTh, WuTl, H_, I_, (long)H_*I_, (long)I_*H_);
    k_transpose<<<dim3(32,64,4),tb,0,stream>>>(Wd+(size_t)l*4*I_*H_, WdTh, WdTl, I_, H_, (long)I_*H_, (long)H_*I_);

    k_rms_sp<<<T_/4,256,0,stream>>>(h, ln1+(size_t)l*H_, xhi, xlo);

    k_qkv<<<dim3(16,16),256,0,stream>>>(xhi, xlo, WqkvTh, WqkvTl, qhi, qlo, khi, klo, vthi, vtlo);

    for(int b=0;b<2;b++){
      // QK^T (causal block-skip), z = head
      k_gemm<128,128,2,2,true,1,1,0><<<dim3(8,8,16),256,0,stream>>>(
        qhi+(size_t)b*S_*NHD, qlo+(size_t)b*S_*NHD, khi+(size_t)b*S_*KVD, klo+(size_t)b*S_*KVD,
        sc, nullptr, nullptr, 64, NHD, KVD, S_, 64, 64, 2, (long)S_*S_, 0.125f);
      k_softmax<<<dim3(256,16),256,0,stream>>>(sc, schi, sclo);
      // PV (K-limited causal), writes o planes
      k_gemm<64,64,2,2,true,9,2,0><<<dim3(16,1,16),256,0,stream>>>(
        schi, sclo, vthi+(size_t)b*S_*KVD, vtlo+(size_t)b*S_*KVD,
        ohi+(size_t)b*S_*NHD, olo+(size_t)b*S_*NHD, nullptr,
        S_, S_, S_, NHD, (long)S_*S_, (long)64*S_, 2, 64, 1.f);
    }

    // o @ Wo += h
    k_gemm<64,128,2,2,true,2,0,0><<<dim3(32,8,1),256,0,stream>>>(
      ohi, olo, WoTh, WoTl, h, nullptr, nullptr, NHD, NHD, NHD, H_, 0,0,1,0, 0.f);

    k_router<<<T_/4,256,0,stream>>>(h, ln2+(size_t)l*H_, gate+(size_t)l*H_*4, comb, lists, cnt+l*4, epos);
    k_rms_sp<<<T_/4,256,0,stream>>>(h, ln2+(size_t)l*H_, xhi, xlo);

    k_moe_ug<<<dim3(64,32),256,0,stream>>>(xhi, xlo, WuTh, WuTl, WgTh, WgTl, guh, gul, lists, cnt+l*4);
    k_gemm<128,128,2,2,true,7,0,3><<<dim3(64,8),256,0,stream>>>(
      guh, gul, WdTh, WdTl, eo, nullptr, cnt+l*4, I_, I_, I_, H_, 0, (long)I_*H_, 1, 0, 1.f);
    k_combine<<<T_,256,0,stream>>>(h, eo, epos, comb);
  }

  k_rms_sp<<<T_/4,256,0,stream>>>(h, normw, xhi, xlo);
  k_transpose<<<dim3(1000,32),tb,0,stream>>>(lmh, wp, nullptr, H_, V_, 0,0);
  // lm_head: single-plane A, non-split (1 MFMA), LDS-coalesced f32 store
  k_gemm<128,128,2,2,false,8,0,0><<<dim3(16,250,1),256,0,stream>>>(
    xhi, nullptr, wp, nullptr, (float*)d_out, nullptr, nullptr, H_, H_, H_, V_, 0,0,1,0, 1.f);
}

// Round 10
// 2473.372 us; speedup vs baseline: 3.1823x; 1.1314x over previous
//
#include <hip/hip_runtime.h>

#define T_ 2048
#define H_ 1024
#define S_ 1024
#define V_ 32000
#define I_ 2048
#define NHD 1024   // NH*HD
#define KVD 512    // NKV*HD

typedef unsigned short u16;
typedef unsigned int u32;
typedef __attribute__((ext_vector_type(8))) short s16x8;
typedef __attribute__((ext_vector_type(4))) float f32x4;

__device__ __forceinline__ u16 f2b(float f){ u32 x=__builtin_bit_cast(u32,f); return (u16)((x+0x7fffu+((x>>16)&1u))>>16); }
__device__ __forceinline__ float b2f(u16 u){ return __builtin_bit_cast(float,(u32)u<<16); }
__device__ __forceinline__ float wsum(float v){ for(int o=32;o;o>>=1) v+=__shfl_xor(v,o); return v; }
__device__ __forceinline__ float wmax(float v){ for(int o=32;o;o>>=1) v=fmaxf(v,__shfl_xor(v,o)); return v; }

// async global->LDS, 16B per lane; LDS dest = wave-uniform base + lane*16
__device__ __forceinline__ void gl16(const void* g, void* l){
  __builtin_amdgcn_global_load_lds(
      (const __attribute__((address_space(1))) unsigned int*)g,
      (__attribute__((address_space(3))) unsigned int*)l, 16, 0, 0);
}

// ---------------- embedding gather ----------------
__global__ void k_embed(const int* __restrict__ ids, const float* __restrict__ emb, float* __restrict__ h){
  int t = blockIdx.x;
  long src = (long)ids[t]*H_;
  ((float4*)(h + (long)t*H_))[threadIdx.x] = ((const float4*)(emb+src))[threadIdx.x];
}

__global__ void k_zero(int* c){ if(threadIdx.x<16) c[threadIdx.x]=0; }

// ---------------- rmsnorm: fp32 -> bf16 hi/lo planes ----------------
__global__ void k_rms_sp(const float* __restrict__ h, const float* __restrict__ w,
                         u16* __restrict__ xhi, u16* __restrict__ xlo){
  int wid = threadIdx.x>>6, lane = threadIdx.x&63;
  int t = blockIdx.x*4 + wid;
  const float* row = h + (long)t*H_;
  float v[16]; float ss=0.f;
  #pragma unroll
  for(int j=0;j<16;j++){ v[j]=row[j*64+lane]; ss += v[j]*v[j]; }
  ss = wsum(ss);
  float rstd = rsqrtf(ss/(float)H_ + 1e-6f);
  #pragma unroll
  for(int j=0;j<16;j++){
    int idx=j*64+lane;
    float y = v[j]*rstd*w[idx];
    u16 hv = f2b(y);
    xhi[(long)t*H_+idx] = hv;
    xlo[(long)t*H_+idx] = f2b(y - b2f(hv));
  }
}

// ---------------- router (fp32) + expert list build ----------------
__global__ void k_router(const float* __restrict__ h, const float* __restrict__ lw,
                         const float* __restrict__ gate, float* __restrict__ comb,
                         int* __restrict__ lists, int* __restrict__ cnt, int2* __restrict__ epos){
  int wid = threadIdx.x>>6, lane = threadIdx.x&63;
  int t = blockIdx.x*4+wid;
  const float* row = h + (long)t*H_;
  float v[16]; float ss=0.f;
  #pragma unroll
  for(int j=0;j<16;j++){ v[j]=row[j*64+lane]; ss+=v[j]*v[j]; }
  ss = wsum(ss);
  float rstd = rsqrtf(ss/(float)H_+1e-6f);
  float a0=0,a1=0,a2=0,a3=0;
  #pragma unroll
  for(int j=0;j<16;j++){
    int idx=j*64+lane;
    float xv = v[j]*rstd*lw[idx];
    float4 g4 = ((const float4*)gate)[idx];
    a0 += xv*g4.x; a1 += xv*g4.y; a2 += xv*g4.z; a3 += xv*g4.w;
  }
  a0=wsum(a0); a1=wsum(a1); a2=wsum(a2); a3=wsum(a3);
  if(lane==0){
    float p[4]={a0,a1,a2,a3};
    float m = fmaxf(fmaxf(p[0],p[1]),fmaxf(p[2],p[3]));
    float s=0; for(int e=0;e<4;e++){ p[e]=__expf(p[e]-m); s+=p[e]; }
    for(int e=0;e<4;e++) p[e]/=s;
    int i1=0; for(int e=1;e<4;e++) if(p[e]>p[i1]) i1=e;
    int i2=-1; for(int e=0;e<4;e++){ if(e==i1) continue; if(i2<0||p[e]>p[i2]) i2=e; }
    float* c = comb + (long)t*4;
    for(int e=0;e<4;e++) c[e] = (e==i1||e==i2)? p[e] : 0.f;
    int p1 = atomicAdd(&cnt[i1],1); lists[i1*T_+p1]=t;
    int p2 = atomicAdd(&cnt[i2],1); lists[i2*T_+p2]=t;
    epos[t] = make_int2((p1<<2)|i1, (p2<<2)|i2);
  }
}

// ---------------- transpose+split: fp32 [R][C] -> bf16 hi(+lo) [C][R] ----------------
__global__ void k_transpose(const float* __restrict__ in, u16* __restrict__ hi, u16* __restrict__ lo,
                            int R, int C, long zi, long zo){
  __shared__ float tile[32][33];
  in += (long)blockIdx.z*zi; hi += (long)blockIdx.z*zo; if(lo) lo += (long)blockIdx.z*zo;
  int c0 = blockIdx.x*32, r0 = blockIdx.y*32;
  int tx = threadIdx.x, ty = threadIdx.y;
  #pragma unroll
  for(int i=0;i<4;i++) tile[ty+8*i][tx] = in[(long)(r0+ty+8*i)*C + c0+tx];
  __syncthreads();
  #pragma unroll
  for(int i=0;i<4;i++){
    int cc=ty+8*i; float v = tile[tx][cc];
    u16 hv = f2b(v);
    long idx = (long)(c0+cc)*R + r0+tx;
    hi[idx] = hv;
    if(lo) lo[idx] = f2b(v - b2f(hv));
  }
}

// ---------------- MoE combine: h[t] += c1*eo[e1,p1] + c2*eo[e2,p2] ----------------
__global__ void k_combine(float* __restrict__ h, const float* __restrict__ eo,
                          const int2* __restrict__ epos, const float* __restrict__ comb){
  int t = blockIdx.x, c = threadIdx.x;
  int2 ep = epos[t];
  int e1 = ep.x&3, p1 = ep.x>>2, e2 = ep.y&3, p2 = ep.y>>2;
  float c1 = comb[t*4+e1], c2 = comb[t*4+e2];
  float4 a = ((const float4*)(eo + (long)(e1*T_+p1)*H_))[c];
  float4 b = ((const float4*)(eo + (long)(e2*T_+p2)*H_))[c];
  float4* hp = (float4*)(h + (long)t*H_) + c;
  float4 hv = *hp;
  hv.x += c1*a.x + c2*b.x; hv.y += c1*a.y + c2*b.y;
  hv.z += c1*a.z + c2*b.z; hv.w += c1*a.w + c2*b.w;
  *hp = hv;
}

// ---------------- fused flash attention (split precision, online softmax) ----------------
// grid (qt=8, h=16, b=2), 256 threads = 4 waves; wave w owns q rows w*32..w*32+31, ALL 128 keys.
__global__ __launch_bounds__(256) void k_flash(
  const u16* __restrict__ qh_g, const u16* __restrict__ ql_g,
  const u16* __restrict__ kh_g, const u16* __restrict__ kl_g,
  const u16* __restrict__ vth_g, const u16* __restrict__ vtl_g,
  u16* __restrict__ oh_g, u16* __restrict__ ol_g)
{
  __shared__ alignas(16) u16 Qh[8192], Ql[8192];     // [2 hf][128 q][32]
  __shared__ alignas(16) u16 KVh[8192], KVl[8192];   // K: [2 hf][128 key][32] | V: [4 ks][64 d][32]
  __shared__ alignas(16) u16 Ph[16384], Pl[16384];   // [4 ks][128 q][32]
  const int qt = blockIdx.x, hh = blockIdx.y, b = blockIdx.z;
  const int hk = hh>>1;
  const int tid = threadIdx.x, lane = tid&63, w = tid>>6;
  const int rA = lane&15, kg = (lane>>4)*8;

  // load Q tile once: rows b*1024+qt*128+row, cols hh*64..+64
  {
    const u16* qp = qh_g + ((long)(b*1024+qt*128))*NHD + hh*64;
    const u16* qp2= ql_g + ((long)(b*1024+qt*128))*NHD + hh*64;
    #pragma unroll
    for(int s=0;s<4;s++){
      int idx=s*4+w, hf=idx>>3, g=idx&7;
      int row = g*16 + (lane>>2);
      int c8  = hf*32 + (lane&3)*8;
      gl16(qp  + (long)row*NHD + c8, &Qh[hf*4096 + g*16*32]);
      gl16(qp2 + (long)row*NHD + c8, &Ql[hf*4096 + g*16*32]);
    }
  }

  f32x4 Oa[2][4];
  float mrun[2][4], lrun[2][4];
  #pragma unroll
  for(int i=0;i<2;i++){
    #pragma unroll
    for(int jn=0;jn<4;jn++){ f32x4 zv={0.f,0.f,0.f,0.f}; Oa[i][jn]=zv; }
    #pragma unroll
    for(int r=0;r<4;r++){ mrun[i][r]=-3.0e38f; lrun[i][r]=0.f; }
  }

  for(int kt=0; kt<=qt; kt++){
    __syncthreads();   // prev PV reads of KV done
    // stage K planes [hf][key][32]
    {
      const u16* kp = kh_g + ((long)(b*1024+kt*128))*KVD + hk*64;
      const u16* kp2= kl_g + ((long)(b*1024+kt*128))*KVD + hk*64;
      #pragma unroll
      for(int s=0;s<4;s++){
        int idx=s*4+w, hf=idx>>3, g=idx&7;
        int row = g*16 + (lane>>2);
        int c8  = hf*32 + (lane&3)*8;
        gl16(kp  + (long)row*KVD + c8, &KVh[hf*4096 + g*16*32]);
        gl16(kp2 + (long)row*KVD + c8, &KVl[hf*4096 + g*16*32]);
      }
    }
    __syncthreads();   // K ready

    // S = Q K^T (split, 3 MFMA): 2 q-frags x 8 key-frags per wave
    f32x4 Sf[2][8];
    #pragma unroll
    for(int i=0;i<2;i++)
      #pragma unroll
      for(int j=0;j<8;j++){ f32x4 zv={0.f,0.f,0.f,0.f}; Sf[i][j]=zv; }
    #pragma unroll
    for(int k2=0;k2<2;k2++){
      s16x8 ah[2],al[2],bh[8],bl[8];
      #pragma unroll
      for(int i=0;i<2;i++){
        int q = w*32+i*16+rA;
        ah[i]=*(const s16x8*)&Qh[k2*4096 + q*32 + kg];
        al[i]=*(const s16x8*)&Ql[k2*4096 + q*32 + kg];
      }
      #pragma unroll
      for(int j=0;j<8;j++){
        int ky = j*16+rA;
        bh[j]=*(const s16x8*)&KVh[k2*4096 + ky*32 + kg];
        bl[j]=*(const s16x8*)&KVl[k2*4096 + ky*32 + kg];
      }
      #pragma unroll
      for(int i=0;i<2;i++)
        #pragma unroll
        for(int j=0;j<8;j++){
          Sf[i][j]=__builtin_amdgcn_mfma_f32_16x16x32_bf16(ah[i],bh[j],Sf[i][j],0,0,0);
          Sf[i][j]=__builtin_amdgcn_mfma_f32_16x16x32_bf16(ah[i],bl[j],Sf[i][j],0,0,0);
          Sf[i][j]=__builtin_amdgcn_mfma_f32_16x16x32_bf16(al[i],bh[j],Sf[i][j],0,0,0);
        }
    }

    // scale + causal mask (diagonal tile)
    #pragma unroll
    for(int i=0;i<2;i++)
      #pragma unroll
      for(int j=0;j<8;j++)
        #pragma unroll
        for(int r=0;r<4;r++){
          float sv = Sf[i][j][r]*0.125f;
          if(kt==qt){
            int qr = w*32+i*16+((lane>>4)<<2)+r;
            int ky = j*16+(lane&15);
            if(ky>qr) sv = -3.0e38f;
          }
          Sf[i][j][r]=sv;
        }

    // full-row max: 8 frags cover all 128 keys; 16-lane group covers cols
    float mt[2][4];
    #pragma unroll
    for(int i=0;i<2;i++)
      #pragma unroll
      for(int r=0;r<4;r++){
        float v = Sf[i][0][r];
        #pragma unroll
        for(int j=1;j<8;j++) v = fmaxf(v, Sf[i][j][r]);
        v=fmaxf(v,__shfl_xor(v,1)); v=fmaxf(v,__shfl_xor(v,2));
        v=fmaxf(v,__shfl_xor(v,4)); v=fmaxf(v,__shfl_xor(v,8));
        mt[i][r]=v;
      }

    // online update: rescale O, l
    #pragma unroll
    for(int i=0;i<2;i++)
      #pragma unroll
      for(int r=0;r<4;r++){
        float mo=mrun[i][r];
        float mn=fmaxf(mo,mt[i][r]);
        float al_=__expf(mo-mn);
        mrun[i][r]=mn;
        lrun[i][r]*=al_;
        #pragma unroll
        for(int jn=0;jn<4;jn++) Oa[i][jn][r]*=al_;
      }

    // P = exp(S-m): accumulate l, write split planes to LDS [ks][q][32]
    float ls[2][4];
    #pragma unroll
    for(int i=0;i<2;i++)
      #pragma unroll
      for(int r=0;r<4;r++) ls[i][r]=0.f;
    #pragma unroll
    for(int i=0;i<2;i++)
      #pragma unroll
      for(int j=0;j<8;j++)
        #pragma unroll
        for(int r=0;r<4;r++){
          int q  = w*32+i*16+((lane>>4)<<2)+r;
          int ky = j*16+(lane&15);
          float pv=__expf(Sf[i][j][r]-mrun[i][r]);
          ls[i][r]+=pv;
          u16 hv=f2b(pv);
          int a=(ky>>5)*4096 + q*32 + (ky&31);
          Ph[a]=hv; Pl[a]=f2b(pv-b2f(hv));
        }
    #pragma unroll
    for(int i=0;i<2;i++)
      #pragma unroll
      for(int r=0;r<4;r++){
        float v=ls[i][r];
        v+=__shfl_xor(v,1); v+=__shfl_xor(v,2); v+=__shfl_xor(v,4); v+=__shfl_xor(v,8);
        lrun[i][r]+=v;
      }
    __syncthreads();   // P visible; K reads done -> KV reusable

    // stage V planes [ks][d][32] (reuse KV buffers)
    {
      const u16* vp = vth_g + (long)b*((long)KVD*S_) + (long)(hk*64)*S_ + kt*128;
      const u16* vp2= vtl_g + (long)b*((long)KVD*S_) + (long)(hk*64)*S_ + kt*128;
      #pragma unroll
      for(int s=0;s<4;s++){
        int idx=s*4+w, ks=idx>>2, g=idx&3;
        int dr = g*16 + (lane>>2);
        int k8 = (lane&3)*8;
        gl16(vp  + (long)dr*S_ + ks*32 + k8, &KVh[ks*2048 + g*16*32]);
        gl16(vp2 + (long)dr*S_ + ks*32 + k8, &KVl[ks*2048 + g*16*32]);
      }
    }
    __syncthreads();   // V ready

    // O += P·V (split, 3 MFMA): wave reads its own q rows' P, all 4 key-subtiles
    #pragma unroll
    for(int ks=0;ks<4;ks++){
      s16x8 pah[2],pal[2],vbh[4],vbl[4];
      #pragma unroll
      for(int i=0;i<2;i++){
        int q = w*32+i*16+rA;
        pah[i]=*(const s16x8*)&Ph[ks*4096 + q*32 + kg];
        pal[i]=*(const s16x8*)&Pl[ks*4096 + q*32 + kg];
      }
      #pragma unroll
      for(int jn=0;jn<4;jn++){
        int d = jn*16+rA;
        vbh[jn]=*(const s16x8*)&KVh[ks*2048 + d*32 + kg];
        vbl[jn]=*(const s16x8*)&KVl[ks*2048 + d*32 + kg];
      }
      #pragma unroll
      for(int i=0;i<2;i++)
        #pragma unroll
        for(int jn=0;jn<4;jn++){
          Oa[i][jn]=__builtin_amdgcn_mfma_f32_16x16x32_bf16(pah[i],vbh[jn],Oa[i][jn],0,0,0);
          Oa[i][jn]=__builtin_amdgcn_mfma_f32_16x16x32_bf16(pah[i],vbl[jn],Oa[i][jn],0,0,0);
          Oa[i][jn]=__builtin_amdgcn_mfma_f32_16x16x32_bf16(pal[i],vbh[jn],Oa[i][jn],0,0,0);
        }
    }
  }

  // epilogue: O /= l, split-store to o planes
  #pragma unroll
  for(int i=0;i<2;i++)
    #pragma unroll
    for(int jn=0;jn<4;jn++)
      #pragma unroll
      for(int r=0;r<4;r++){
        long t = (long)b*1024 + qt*128 + w*32+i*16+((lane>>4)<<2)+r;
        int col = hh*64 + jn*16 + (lane&15);
        float ov = Oa[i][jn][r] / lrun[i][r];
        u16 hv=f2b(ov);
        oh_g[t*NHD+col]=hv;
        ol_g[t*NHD+col]=f2b(ov-b2f(hv));
      }
}

// ---------------- fused QKV GEMM (gload staging): x @ [Wq|Wk|Wv] -> split planes ----------------
__global__ __launch_bounds__(256) void k_qkv(
  const u16* __restrict__ xhi, const u16* __restrict__ xlo,
  const u16* __restrict__ Bh, const u16* __restrict__ Bl,
  u16* __restrict__ qhi, u16* __restrict__ qlo,
  u16* __restrict__ khi, u16* __restrict__ klo,
  u16* __restrict__ vthi, u16* __restrict__ vtlo)
{
  constexpr int BK=32;
  __shared__ alignas(16) u16 As[2*128*32], Bs[2*128*32];
  const int m0=blockIdx.x*128, n0=blockIdx.y*128;
  const int tid=threadIdx.x, lane=tid&63, w=tid>>6, wr=w>>1, wc=w&1;
  const int col8 = (lane&3)*8, rsub = lane>>2;
  f32x4 acc[4][4];
  #pragma unroll
  for(int i=0;i<4;i++)
    #pragma unroll
    for(int j=0;j<4;j++){ f32x4 zv={0.f,0.f,0.f,0.f}; acc[i][j]=zv; }

  for(int kt=0;kt<H_/BK;kt++){
    const int k0=kt*BK;
    __syncthreads();
    #pragma unroll
    for(int s=0;s<2;s++){
      int ch = s*4+w; int row = ch*16 + rsub;
      gl16(xhi + (long)(m0+row)*H_ + k0+col8, &As[ch*512]);
      gl16(xlo + (long)(m0+row)*H_ + k0+col8, &As[4096+ch*512]);
      gl16(Bh  + (long)(n0+row)*H_ + k0+col8, &Bs[ch*512]);
      gl16(Bl  + (long)(n0+row)*H_ + k0+col8, &Bs[4096+ch*512]);
    }
    __syncthreads();
    s16x8 ah[4],al[4],bh[4],bl[4];
    const int rA=lane&15, kg=(lane>>4)*8;
    #pragma unroll
    for(int i=0;i<4;i++){
      ah[i]=*(const s16x8*)&As[(wr*64+i*16+rA)*32+kg];
      al[i]=*(const s16x8*)&As[4096+(wr*64+i*16+rA)*32+kg];
    }
    #pragma unroll
    for(int j=0;j<4;j++){
      bh[j]=*(const s16x8*)&Bs[(wc*64+j*16+rA)*32+kg];
      bl[j]=*(const s16x8*)&Bs[4096+(wc*64+j*16+rA)*32+kg];
    }
    #pragma unroll
    for(int i=0;i<4;i++)
      #pragma unroll
      for(int j=0;j<4;j++){
        acc[i][j]=__builtin_amdgcn_mfma_f32_16x16x32_bf16(ah[i],bh[j],acc[i][j],0,0,0);
        acc[i][j]=__builtin_amdgcn_mfma_f32_16x16x32_bf16(ah[i],bl[j],acc[i][j],0,0,0);
        acc[i][j]=__builtin_amdgcn_mfma_f32_16x16x32_bf16(al[i],bh[j],acc[i][j],0,0,0);
      }
  }

  #pragma unroll
  for(int i=0;i<4;i++){
    #pragma unroll
    for(int j=0;j<4;j++){
      const int gm0 = m0 + wr*64 + i*16 + ((lane>>4)<<2);
      const int gn  = n0 + wc*64 + j*16 + (lane&15);
      #pragma unroll
      for(int r=0;r<4;r++){
        const int gm = gm0+r;
        float v = acc[i][j][r];
        u16 hv = f2b(v);
        u16 lv = f2b(v - b2f(hv));
        if(gn < 1024){
          long idx=(long)gm*NHD+gn; qhi[idx]=hv; qlo[idx]=lv;
        } else if(gn < 1536){
          long idx=(long)gm*KVD+(gn-1024); khi[idx]=hv; klo[idx]=lv;
        } else {
          long idx=((long)(gm>>10)<<19) + (long)(gn-1536)*S_ + (gm&1023);
          vthi[idx]=hv; vtlo[idx]=lv;
        }
      }
    }
  }
}

// ---------------- fused MoE up+gate (gload): silu(x@Wg)*(x@Wu) -> gu planes ----------------
__global__ __launch_bounds__(256) void k_moe_ug(
  const u16* __restrict__ xhi, const u16* __restrict__ xlo,
  const u16* __restrict__ Wuh, const u16* __restrict__ Wul,
  const u16* __restrict__ Wgh, const u16* __restrict__ Wgl,
  u16* __restrict__ guh, u16* __restrict__ gul,
  const int* __restrict__ lists, const int* __restrict__ cntp)
{
  constexpr int BK=32;
  const int e = blockIdx.x>>4, m0=(blockIdx.x&15)*128;
  const int ce = cntp[e];
  if(m0>=ce) return;
  const int n0 = blockIdx.y*64;
  const int* ridx = lists + e*T_;
  const u16* Buh_g = Wuh + (size_t)e*H_*I_;
  const u16* Bul_g = Wul + (size_t)e*H_*I_;
  const u16* Bgh_g = Wgh + (size_t)e*H_*I_;
  const u16* Bgl_g = Wgl + (size_t)e*H_*I_;
  __shared__ alignas(16) u16 Ah[128*32], Al[128*32];
  __shared__ alignas(16) u16 Buh[64*32], Bul[64*32], Bgh[64*32], Bgl[64*32];
  const int tid=threadIdx.x, lane=tid&63, w=tid>>6;
  const int wr=w>>1, wc=w&1;
  const int col8=(lane&3)*8, rsub=lane>>2;
  int arA[2];
  #pragma unroll
  for(int s=0;s<2;s++){ int idx=m0 + (s*4+w)*16 + rsub; arA[s]=ridx[idx<ce?idx:ce-1]; }
  const int brow = n0 + w*16 + rsub;
  f32x4 au[4][2], ag[4][2];
  #pragma unroll
  for(int i=0;i<4;i++)
    #pragma unroll
    for(int j=0;j<2;j++){ f32x4 zv={0.f,0.f,0.f,0.f}; au[i][j]=zv; ag[i][j]=zv; }

  for(int kt=0;kt<H_/BK;kt++){
    const int k0=kt*BK;
    __syncthreads();
    #pragma unroll
    for(int s=0;s<2;s++){
      int ch=s*4+w;
      gl16(xhi + (long)arA[s]*H_ + k0+col8, &Ah[ch*512]);
      gl16(xlo + (long)arA[s]*H_ + k0+col8, &Al[ch*512]);
    }
    gl16(Buh_g + (long)brow*H_ + k0+col8, &Buh[w*512]);
    gl16(Bul_g + (long)brow*H_ + k0+col8, &Bul[w*512]);
    gl16(Bgh_g + (long)brow*H_ + k0+col8, &Bgh[w*512]);
    gl16(Bgl_g + (long)brow*H_ + k0+col8, &Bgl[w*512]);
    __syncthreads();
    s16x8 fah[4],fal[4],fbuh[2],fbul[2],fbgh[2],fbgl[2];
    const int rA=lane&15, kg=(lane>>4)*8;
    #pragma unroll
    for(int i=0;i<4;i++){
      fah[i]=*(const s16x8*)&Ah[(wr*64+i*16+rA)*32+kg];
      fal[i]=*(const s16x8*)&Al[(wr*64+i*16+rA)*32+kg];
    }
    #pragma unroll
    for(int j=0;j<2;j++){
      fbuh[j]=*(const s16x8*)&Buh[(wc*32+j*16+rA)*32+kg];
      fbul[j]=*(const s16x8*)&Bul[(wc*32+j*16+rA)*32+kg];
      fbgh[j]=*(const s16x8*)&Bgh[(wc*32+j*16+rA)*32+kg];
      fbgl[j]=*(const s16x8*)&Bgl[(wc*32+j*16+rA)*32+kg];
    }
    #pragma unroll
    for(int i=0;i<4;i++)
      #pragma unroll
      for(int j=0;j<2;j++){
        au[i][j]=__builtin_amdgcn_mfma_f32_16x16x32_bf16(fah[i],fbuh[j],au[i][j],0,0,0);
        au[i][j]=__builtin_amdgcn_mfma_f32_16x16x32_bf16(fah[i],fbul[j],au[i][j],0,0,0);
        au[i][j]=__builtin_amdgcn_mfma_f32_16x16x32_bf16(fal[i],fbuh[j],au[i][j],0,0,0);
        ag[i][j]=__builtin_amdgcn_mfma_f32_16x16x32_bf16(fah[i],fbgh[j],ag[i][j],0,0,0);
        ag[i][j]=__builtin_amdgcn_mfma_f32_16x16x32_bf16(fah[i],fbgl[j],ag[i][j],0,0,0);
        ag[i][j]=__builtin_amdgcn_mfma_f32_16x16x32_bf16(fal[i],fbgh[j],ag[i][j],0,0,0);
      }
  }

  #pragma unroll
  for(int i=0;i<4;i++){
    #pragma unroll
    for(int j=0;j<2;j++){
      const int gm0 = m0 + wr*64 + i*16 + ((lane>>4)<<2);
      const int gn  = n0 + wc*32 + j*16 + (lane&15);
      #pragma unroll
      for(int r=0;r<4;r++){
        const int gm = gm0+r;
        if(gm<ce){
          float uu=au[i][j][r], gg=ag[i][j][r];
          float val = (gg/(1.f+__expf(-gg)))*uu;
          long idx = (long)(e*T_+gm)*I_ + gn;
          u16 hv=f2b(val);
          guh[idx]=hv; gul[idx]=f2b(val-b2f(hv));
        }
      }
    }
  }
}

// ---------------- generic MFMA GEMM (A,B = bf16 planes, gload staging) ----------------
// SPL: bf16x2 split (hi/lo planes, 3 MFMAs); EPI: 1=f32*scale, 2=f32 +=,
//      7=f32 compact expert slot, 8=f32 via LDS coalesced, 9=split planes (Cp=hi,auxp=lo)
// CM : 0=none, 1=skip blocks above diagonal, 2=K-limit at m0+BM
// GATH: 0=dense, 3=expert-slot mode
template<int BM,int BN,int WM,int WN,bool SPL,int EPI,int CM,int GATH>
__launch_bounds__(WM*WN*64)
__global__ void k_gemm(const u16* __restrict__ Ahip, const u16* __restrict__ Alop,
                       const u16* __restrict__ Bhip, const u16* __restrict__ Blop,
                       void* __restrict__ Cp, void* __restrict__ auxp,
                       const int* __restrict__ cntp,
                       int Kdim, int lda, int ldb, int ldc,
                       long zA, long zB, int zBdiv, long zC,
                       float scale)
{
  constexpr int NT = WM*WN*64;
  constexpr int Wv = NT/64;
  constexpr int BK = 32;
  constexpr int WMT = BM/WM, WNT = BN/WN;
  constexpr int MF = WMT/16, NF = WNT/16;
  constexpr int ACn = BM/(16*Wv);
  constexpr int BCn = BN/(16*Wv);
  static_assert(ACn>=1 && BCn>=1, "chunks");
  __shared__ alignas(16) u16 As[(SPL?2:1)*BM*32];
  __shared__ alignas(16) u16 Bs[(SPL?2:1)*BN*32];
  __shared__ float Cs[EPI==8?WM:1][EPI==8?16:1][EPI==8?(BN+4):1];
  int m0, eid_ = 0, cnt = 0;
  if constexpr (GATH==3){
    eid_ = blockIdx.x>>4; m0 = (blockIdx.x&15)*BM;
    cnt = cntp[eid_]; if(m0>=cnt) return;
  } else {
    m0 = blockIdx.x*BM;
  }
  const int n0 = blockIdx.y*BN;
  if (CM==1 && n0 > m0) return;
  const int z = blockIdx.z;
  const int tid = threadIdx.x, lane = tid&63, w = tid>>6;
  const int wr = w/WN, wc = w%WN;
  const int col8 = (lane&3)*8, rsub = lane>>2;
  const u16* Ahi = Ahip + (long)z*zA + (GATH==3 ? (long)eid_*T_*lda : 0);
  const u16* Alo = SPL ? (Alop + (long)z*zA + (GATH==3 ? (long)eid_*T_*lda : 0)) : (const u16*)nullptr;
  const u16* Bh  = Bhip + (long)(z/zBdiv)*zB + (GATH==3 ? (long)eid_*zB : 0);
  const u16* Bl  = SPL ? (Blop + (long)(z/zBdiv)*zB + (GATH==3 ? (long)eid_*zB : 0)) : (const u16*)nullptr;

  f32x4 acc[MF][NF];
  #pragma unroll
  for(int i=0;i<MF;i++)
    #pragma unroll
    for(int j=0;j<NF;j++){ f32x4 zv={0.f,0.f,0.f,0.f}; acc[i][j]=zv; }

  int ktend = Kdim/BK;
  if (CM==2){ int lim=(m0+BM)/BK; if(lim<ktend) ktend=lim; }

  for(int kt=0;kt<ktend;kt++){
    const int k0 = kt*BK;
    __syncthreads();
    #pragma unroll
    for(int s=0;s<ACn;s++){
      int ch = s*Wv + w;
      int arow = m0 + ch*16 + rsub;
      if constexpr (GATH==3){ arow = arow < cnt ? arow : cnt-1; }
      gl16(Ahi + (long)arow*lda + k0+col8, &As[ch*512]);
      if constexpr (SPL) gl16(Alo + (long)arow*lda + k0+col8, &As[BM*32 + ch*512]);
    }
    #pragma unroll
    for(int s=0;s<BCn;s++){
      int ch = s*Wv + w;
      int brow = n0 + ch*16 + rsub;
      gl16(Bh + (long)brow*ldb + k0+col8, &Bs[ch*512]);
      if constexpr (SPL) gl16(Bl + (long)brow*ldb + k0+col8, &Bs[BN*32 + ch*512]);
    }
    __syncthreads();
    s16x8 ah[MF], al[MF], bh[NF], bl[NF];
    const int rA = lane&15, kg=(lane>>4)*8;
    #pragma unroll
    for(int i=0;i<MF;i++){
      ah[i]=*(const s16x8*)&As[(wr*WMT+i*16+rA)*32+kg];
      if constexpr (SPL) al[i]=*(const s16x8*)&As[BM*32+(wr*WMT+i*16+rA)*32+kg];
    }
    #pragma unroll
    for(int j=0;j<NF;j++){
      bh[j]=*(const s16x8*)&Bs[(wc*WNT+j*16+rA)*32+kg];
      if constexpr (SPL) bl[j]=*(const s16x8*)&Bs[BN*32+(wc*WNT+j*16+rA)*32+kg];
    }
    #pragma unroll
    for(int i=0;i<MF;i++)
      #pragma unroll
      for(int j=0;j<NF;j++){
        acc[i][j]=__builtin_amdgcn_mfma_f32_16x16x32_bf16(ah[i],bh[j],acc[i][j],0,0,0);
        if constexpr (SPL){
          acc[i][j]=__builtin_amdgcn_mfma_f32_16x16x32_bf16(ah[i],bl[j],acc[i][j],0,0,0);
          acc[i][j]=__builtin_amdgcn_mfma_f32_16x16x32_bf16(al[i],bh[j],acc[i][j],0,0,0);
        }
      }
  }

  if constexpr (EPI==8){
    float* C = (float*)Cp + (long)z*zC;
    #pragma unroll
    for(int i=0;i<MF;i++){
      __syncthreads();
      #pragma unroll
      for(int j=0;j<NF;j++)
        #pragma unroll
        for(int r=0;r<4;r++)
          Cs[wr][((lane>>4)<<2)+r][wc*WNT + j*16 + (lane&15)] = acc[i][j][r]*scale;
      __syncthreads();
      const int rrow = tid>>3;
      const int wri = rrow>>4, r16 = rrow&15;
      const long gm = m0 + wri*WMT + i*16 + r16;
      #pragma unroll
      for(int s=0;s<BN/32;s++){
        int c0 = ((tid&7) + s*8)*4;
        float4 vv = { Cs[wri][r16][c0], Cs[wri][r16][c0+1], Cs[wri][r16][c0+2], Cs[wri][r16][c0+3] };
        *(float4*)(C + gm*ldc + n0 + c0) = vv;
      }
    }
    return;
  }

  #pragma unroll
  for(int i=0;i<MF;i++){
    #pragma unroll
    for(int j=0;j<NF;j++){
      const int gm0 = m0 + wr*WMT + i*16 + ((lane>>4)<<2);
      const int gn  = n0 + wc*WNT + j*16 + (lane&15);
      #pragma unroll
      for(int r=0;r<4;r++){
        const int gm = gm0+r;
        const float v = acc[i][j][r];
        const bool live = (GATH==0) || (gm < cnt);
        if constexpr (EPI==1){
          if(live) ((float*)Cp + (long)z*zC)[(long)gm*ldc+gn] = v*scale;
        } else if constexpr (EPI==2){
          float* C = (float*)Cp; C[(long)gm*ldc+gn] += v;
        } else if constexpr (EPI==7){
          if(live) ((float*)Cp)[(long)(eid_*T_+gm)*ldc+gn] = v*scale;
        } else if constexpr (EPI==9){
          u16* Ch = (u16*)Cp + (long)z*zC;
          u16* Cl = (u16*)auxp + (long)z*zC;
          long idx = (long)gm*ldc+gn;
          u16 hv = f2b(v);
          Ch[idx]=hv; Cl[idx]=f2b(v-b2f(hv));
        }
      }
    }
  }
}

extern "C" void kernel_launch(void* const* d_in, const int* in_sizes, int n_in,
                              void* d_out, int out_size, void* d_ws, size_t ws_size,
                              hipStream_t stream)
{
  (void)in_sizes; (void)n_in; (void)out_size;
  const int*   ids   = (const int*)d_in[0];
  const float* emb   = (const float*)d_in[1];
  const float* Wq    = (const float*)d_in[2];
  const float* Wk    = (const float*)d_in[3];
  const float* Wv    = (const float*)d_in[4];
  const float* Wo    = (const float*)d_in[5];
  const float* ln1   = (const float*)d_in[6];
  const float* ln2   = (const float*)d_in[7];
  const float* gate  = (const float*)d_in[8];
  const float* Wg    = (const float*)d_in[9];
  const float* Wu    = (const float*)d_in[10];
  const float* Wd    = (const float*)d_in[11];
  const float* normw = (const float*)d_in[12];
  const float* lmh   = (const float*)d_in[13];

  char* p = (char*)d_ws;
  auto carve = [&](size_t bytes)->void*{ void* r=p; p += (bytes+255)&~(size_t)255; return r; };
  float* h    = (float*)carve((size_t)T_*H_*4);
  u16*   xhi  = (u16*)  carve((size_t)T_*H_*2);
  u16*   xlo  = (u16*)  carve((size_t)T_*H_*2);
  u16*   qhi  = (u16*)  carve((size_t)T_*NHD*2);
  u16*   qlo  = (u16*)  carve((size_t)T_*NHD*2);
  u16*   khi  = (u16*)  carve((size_t)T_*KVD*2);
  u16*   klo  = (u16*)  carve((size_t)T_*KVD*2);
  u16*   vthi = (u16*)  carve((size_t)T_*KVD*2);
  u16*   vtlo = (u16*)  carve((size_t)T_*KVD*2);
  u16*   ohi  = (u16*)  carve((size_t)T_*NHD*2);
  u16*   olo  = (u16*)  carve((size_t)T_*NHD*2);
  float* comb = (float*)carve((size_t)T_*4*4);
  int*   cnt  = (int*)  carve((size_t)16*4);
  int*   lists= (int*)  carve((size_t)4*T_*4);
  int2*  epos = (int2*) carve((size_t)T_*8);
  char*  U    = (char*) carve((size_t)112*1024*1024);
  u16*   wp   = (u16*)  carve((size_t)56623104*2);
  if ((size_t)(p - (char*)d_ws) > ws_size) return;

  u16*   guh  = (u16*)U;
  u16*   gul  = (u16*)(U + 33554432);
  float* eo   = (float*)(U + 67108864);

  u16 *WqkvTh = wp,          *WqkvTl = wp+2097152;   // [2048][1024]: q rows 0-1023, k 1024-1535, v 1536-2047
  u16 *WoTh = wp+4194304,    *WoTl = wp+5242880;
  u16 *WgTh = wp+6291456,    *WgTl = wp+14680064;
  u16 *WuTh = wp+23068672,   *WuTl = wp+31457280;
  u16 *WdTh = wp+39845888,   *WdTl = wp+48234496;

  dim3 tb(32,8);

  k_embed<<<T_,256,0,stream>>>(ids, emb, h);
  k_zero<<<1,64,0,stream>>>(cnt);

  for(int l=0;l<4;l++){
    k_transpose<<<dim3(32,32),tb,0,stream>>>(Wq+(size_t)l*H_*NHD, WqkvTh, WqkvTl, H_, NHD, 0,0);
    k_transpose<<<dim3(16,32),tb,0,stream>>>(Wk+(size_t)l*H_*KVD, WqkvTh+1048576, WqkvTl+1048576, H_, KVD, 0,0);
    k_transpose<<<dim3(16,32),tb,0,stream>>>(Wv+(size_t)l*H_*KVD, WqkvTh+1572864, WqkvTl+1572864, H_, KVD, 0,0);
    k_transpose<<<dim3(32,32),tb,0,stream>>>(Wo+(size_t)l*NHD*H_, WoTh, WoTl, NHD, H_, 0,0);
    k_transpose<<<dim3(64,32,4),tb,0,stream>>>(Wg+(size_t)l*4*H_*I_, WgTh, WgTl, H_, I_, (long)H_*I_, (long)I_*H_);
    k_transpose<<<dim3(64,32,4),tb,0,stream>>>(Wu+(size_t)l*4*H_*I_, WuTh, WuTl, H_, I_, (long)H_*I_, (long)I_*H_);
    k_transpose<<<dim3(32,64,4),tb,0,stream>>>(Wd+(size_t)l*4*I_*H_, WdTh, WdTl, I_, H_, (long)I_*H_, (long)H_*I_);

    k_rms_sp<<<T_/4,256,0,stream>>>(h, ln1+(size_t)l*H_, xhi, xlo);

    k_qkv<<<dim3(16,16),256,0,stream>>>(xhi, xlo, WqkvTh, WqkvTl, qhi, qlo, khi, klo, vthi, vtlo);

    // fused flash attention (replaces QK + softmax + PV)
    k_flash<<<dim3(8,16,2),256,0,stream>>>(qhi, qlo, khi, klo, vthi, vtlo, ohi, olo);

    // o @ Wo += h
    k_gemm<64,128,2,2,true,2,0,0><<<dim3(32,8,1),256,0,stream>>>(
      ohi, olo, WoTh, WoTl, h, nullptr, nullptr, NHD, NHD, NHD, H_, 0,0,1,0, 0.f);

    k_router<<<T_/4,256,0,stream>>>(h, ln2+(size_t)l*H_, gate+(size_t)l*H_*4, comb, lists, cnt+l*4, epos);
    k_rms_sp<<<T_/4,256,0,stream>>>(h, ln2+(size_t)l*H_, xhi, xlo);

    k_moe_ug<<<dim3(64,32),256,0,stream>>>(xhi, xlo, WuTh, WuTl, WgTh, WgTl, guh, gul, lists, cnt+l*4);
    k_gemm<128,128,2,2,true,7,0,3><<<dim3(64,8),256,0,stream>>>(
      guh, gul, WdTh, WdTl, eo, nullptr, cnt+l*4, I_, I_, I_, H_, 0, (long)I_*H_, 1, 0, 1.f);
    k_combine<<<T_,256,0,stream>>>(h, eo, epos, comb);
  }

  k_rms_sp<<<T_/4,256,0,stream>>>(h, normw, xhi, xlo);
  k_transpose<<<dim3(1000,32),tb,0,stream>>>(lmh, wp, nullptr, H_, V_, 0,0);
  k_gemm<128,128,2,2,false,8,0,0><<<dim3(16,250,1),256,0,stream>>>(
    xhi, nullptr, wp, nullptr, (float*)d_out, nullptr, nullptr, H_, H_, H_, V_, 0,0,1,0, 1.f);
}

// Round 11
// 2389.263 us; speedup vs baseline: 3.2943x; 1.0352x over previous
//
#include <hip/hip_runtime.h>

#define T_ 2048
#define H_ 1024
#define S_ 1024
#define V_ 32000
#define I_ 2048
#define NHD 1024   // NH*HD
#define KVD 512    // NKV*HD

typedef unsigned short u16;
typedef unsigned int u32;
typedef __attribute__((ext_vector_type(8))) short s16x8;
typedef __attribute__((ext_vector_type(4))) float f32x4;

__device__ __forceinline__ u16 f2b(float f){ u32 x=__builtin_bit_cast(u32,f); return (u16)((x+0x7fffu+((x>>16)&1u))>>16); }
__device__ __forceinline__ float b2f(u16 u){ return __builtin_bit_cast(float,(u32)u<<16); }
__device__ __forceinline__ float wsum(float v){ for(int o=32;o;o>>=1) v+=__shfl_xor(v,o); return v; }
__device__ __forceinline__ float wmax(float v){ for(int o=32;o;o>>=1) v=fmaxf(v,__shfl_xor(v,o)); return v; }

// async global->LDS, 16B per lane; LDS dest = wave-uniform base + lane*16
__device__ __forceinline__ void gl16(const void* g, void* l){
  __builtin_amdgcn_global_load_lds(
      (const __attribute__((address_space(1))) unsigned int*)g,
      (__attribute__((address_space(3))) unsigned int*)l, 16, 0, 0);
}

// ---------------- embedding gather ----------------
__global__ void k_embed(const int* __restrict__ ids, const float* __restrict__ emb, float* __restrict__ h){
  int t = blockIdx.x;
  long src = (long)ids[t]*H_;
  ((float4*)(h + (long)t*H_))[threadIdx.x] = ((const float4*)(emb+src))[threadIdx.x];
}

__global__ void k_zero(int* c){ if(threadIdx.x<16) c[threadIdx.x]=0; }

// ---------------- rmsnorm: fp32 -> bf16 hi/lo planes ----------------
__global__ void k_rms_sp(const float* __restrict__ h, const float* __restrict__ w,
                         u16* __restrict__ xhi, u16* __restrict__ xlo){
  int wid = threadIdx.x>>6, lane = threadIdx.x&63;
  int t = blockIdx.x*4 + wid;
  const float* row = h + (long)t*H_;
  float v[16]; float ss=0.f;
  #pragma unroll
  for(int j=0;j<16;j++){ v[j]=row[j*64+lane]; ss += v[j]*v[j]; }
  ss = wsum(ss);
  float rstd = rsqrtf(ss/(float)H_ + 1e-6f);
  #pragma unroll
  for(int j=0;j<16;j++){
    int idx=j*64+lane;
    float y = v[j]*rstd*w[idx];
    u16 hv = f2b(y);
    xhi[(long)t*H_+idx] = hv;
    xlo[(long)t*H_+idx] = f2b(y - b2f(hv));
  }
}

// ---------------- router (fp32) + expert list build ----------------
__global__ void k_router(const float* __restrict__ h, const float* __restrict__ lw,
                         const float* __restrict__ gate, float* __restrict__ comb,
                         int* __restrict__ lists, int* __restrict__ cnt, int2* __restrict__ epos){
  int wid = threadIdx.x>>6, lane = threadIdx.x&63;
  int t = blockIdx.x*4+wid;
  const float* row = h + (long)t*H_;
  float v[16]; float ss=0.f;
  #pragma unroll
  for(int j=0;j<16;j++){ v[j]=row[j*64+lane]; ss+=v[j]*v[j]; }
  ss = wsum(ss);
  float rstd = rsqrtf(ss/(float)H_+1e-6f);
  float a0=0,a1=0,a2=0,a3=0;
  #pragma unroll
  for(int j=0;j<16;j++){
    int idx=j*64+lane;
    float xv = v[j]*rstd*lw[idx];
    float4 g4 = ((const float4*)gate)[idx];
    a0 += xv*g4.x; a1 += xv*g4.y; a2 += xv*g4.z; a3 += xv*g4.w;
  }
  a0=wsum(a0); a1=wsum(a1); a2=wsum(a2); a3=wsum(a3);
  if(lane==0){
    float p[4]={a0,a1,a2,a3};
    float m = fmaxf(fmaxf(p[0],p[1]),fmaxf(p[2],p[3]));
    float s=0; for(int e=0;e<4;e++){ p[e]=__expf(p[e]-m); s+=p[e]; }
    for(int e=0;e<4;e++) p[e]/=s;
    int i1=0; for(int e=1;e<4;e++) if(p[e]>p[i1]) i1=e;
    int i2=-1; for(int e=0;e<4;e++){ if(e==i1) continue; if(i2<0||p[e]>p[i2]) i2=e; }
    float* c = comb + (long)t*4;
    for(int e=0;e<4;e++) c[e] = (e==i1||e==i2)? p[e] : 0.f;
    int p1 = atomicAdd(&cnt[i1],1); lists[i1*T_+p1]=t;
    int p2 = atomicAdd(&cnt[i2],1); lists[i2*T_+p2]=t;
    epos[t] = make_int2((p1<<2)|i1, (p2<<2)|i2);
  }
}

// ---------------- transpose+split: fp32 [R][C] -> bf16 hi(+lo) [C][R] ----------------
__global__ void k_transpose(const float* __restrict__ in, u16* __restrict__ hi, u16* __restrict__ lo,
                            int R, int C, long zi, long zo){
  __shared__ float tile[32][33];
  in += (long)blockIdx.z*zi; hi += (long)blockIdx.z*zo; if(lo) lo += (long)blockIdx.z*zo;
  int c0 = blockIdx.x*32, r0 = blockIdx.y*32;
  int tx = threadIdx.x, ty = threadIdx.y;
  #pragma unroll
  for(int i=0;i<4;i++) tile[ty+8*i][tx] = in[(long)(r0+ty+8*i)*C + c0+tx];
  __syncthreads();
  #pragma unroll
  for(int i=0;i<4;i++){
    int cc=ty+8*i; float v = tile[tx][cc];
    u16 hv = f2b(v);
    long idx = (long)(c0+cc)*R + r0+tx;
    hi[idx] = hv;
    if(lo) lo[idx] = f2b(v - b2f(hv));
  }
}

// ---------------- all per-layer weight transposes in ONE launch (block-id decoded) ----------------
__global__ void k_wtrans(const float* __restrict__ Wq, const float* __restrict__ Wk,
                         const float* __restrict__ Wv, const float* __restrict__ Wo,
                         const float* __restrict__ Wg, const float* __restrict__ Wu,
                         const float* __restrict__ Wd,
                         u16* __restrict__ qkvh, u16* __restrict__ qkvl,
                         u16* __restrict__ oh, u16* __restrict__ ol,
                         u16* __restrict__ gh, u16* __restrict__ gl_,
                         u16* __restrict__ uh, u16* __restrict__ ul,
                         u16* __restrict__ dh, u16* __restrict__ dl)
{
  __shared__ float tile[32][33];
  int id = blockIdx.x;
  const float* in; u16 *hi, *lo; int R, C, bx, by;
  if(id < 1024){ in=Wq; hi=qkvh; lo=qkvl; R=1024; C=1024; bx=id&31; by=id>>5; }
  else if(id < 1536){ id-=1024; in=Wk; hi=qkvh+1048576; lo=qkvl+1048576; R=1024; C=512; bx=id&15; by=id>>4; }
  else if(id < 2048){ id-=1536; in=Wv; hi=qkvh+1572864; lo=qkvl+1572864; R=1024; C=512; bx=id&15; by=id>>4; }
  else if(id < 3072){ id-=2048; in=Wo; hi=oh; lo=ol; R=1024; C=1024; bx=id&31; by=id>>5; }
  else if(id < 11264){ id-=3072; int z=id>>11, r2=id&2047;
    in=Wg+(size_t)z*H_*I_; hi=gh+(size_t)z*I_*H_; lo=gl_+(size_t)z*I_*H_;
    R=1024; C=2048; bx=r2&63; by=r2>>6; }
  else if(id < 19456){ id-=11264; int z=id>>11, r2=id&2047;
    in=Wu+(size_t)z*H_*I_; hi=uh+(size_t)z*I_*H_; lo=ul+(size_t)z*I_*H_;
    R=1024; C=2048; bx=r2&63; by=r2>>6; }
  else { id-=19456; int z=id>>11, r2=id&2047;
    in=Wd+(size_t)z*I_*H_; hi=dh+(size_t)z*H_*I_; lo=dl+(size_t)z*H_*I_;
    R=2048; C=1024; bx=r2&31; by=r2>>5; }
  int c0=bx*32, r0=by*32, tx=threadIdx.x, ty=threadIdx.y;
  #pragma unroll
  for(int i=0;i<4;i++) tile[ty+8*i][tx] = in[(long)(r0+ty+8*i)*C + c0+tx];
  __syncthreads();
  #pragma unroll
  for(int i=0;i<4;i++){
    int cc=ty+8*i; float v = tile[tx][cc];
    u16 hv = f2b(v);
    long idx = (long)(c0+cc)*R + r0+tx;
    hi[idx] = hv;
    lo[idx] = f2b(v - b2f(hv));
  }
}

// ---------------- MoE combine: h[t] += c1*eo[e1,p1] + c2*eo[e2,p2] ----------------
__global__ void k_combine(float* __restrict__ h, const float* __restrict__ eo,
                          const int2* __restrict__ epos, const float* __restrict__ comb){
  int t = blockIdx.x, c = threadIdx.x;
  int2 ep = epos[t];
  int e1 = ep.x&3, p1 = ep.x>>2, e2 = ep.y&3, p2 = ep.y>>2;
  float c1 = comb[t*4+e1], c2 = comb[t*4+e2];
  float4 a = ((const float4*)(eo + (long)(e1*T_+p1)*H_))[c];
  float4 b = ((const float4*)(eo + (long)(e2*T_+p2)*H_))[c];
  float4* hp = (float4*)(h + (long)t*H_) + c;
  float4 hv = *hp;
  hv.x += c1*a.x + c2*b.x; hv.y += c1*a.y + c2*b.y;
  hv.z += c1*a.z + c2*b.z; hv.w += c1*a.w + c2*b.w;
  *hp = hv;
}

// ---------------- fused flash attention (QBLK=64, 2 blocks/CU) ----------------
// grid (qt=16, h=16, b=2), 256 threads = 4 waves; wave w owns q rows w*16..+15, ALL 128 keys.
__global__ __launch_bounds__(256) void k_flash(
  const u16* __restrict__ qh_g, const u16* __restrict__ ql_g,
  const u16* __restrict__ kh_g, const u16* __restrict__ kl_g,
  const u16* __restrict__ vth_g, const u16* __restrict__ vtl_g,
  u16* __restrict__ oh_g, u16* __restrict__ ol_g)
{
  __shared__ alignas(16) u16 Qh[4096], Ql[4096];     // [2 hf][64 q][32]
  __shared__ alignas(16) u16 KVh[8192], KVl[8192];   // K: [2 hf][128 key][32] | V: [4 ks][64 d][32]
  __shared__ alignas(16) u16 Ph[8192], Pl[8192];     // [4 ks][64 q][32]
  const int qt = blockIdx.x, hh = blockIdx.y, b = blockIdx.z;
  const int hk = hh>>1;
  const int lane = threadIdx.x&63, w = threadIdx.x>>6;
  const int rA = lane&15, kg = (lane>>4)*8;

  // load Q tile once: rows b*1024+qt*64+row, cols hh*64..+64
  {
    const u16* qp = qh_g + ((long)(b*1024+qt*64))*NHD + hh*64;
    const u16* qp2= ql_g + ((long)(b*1024+qt*64))*NHD + hh*64;
    #pragma unroll
    for(int s=0;s<2;s++){
      int idx=s*4+w, hf=idx>>2, g=idx&3;
      int row = g*16 + (lane>>2);
      int c8  = hf*32 + (lane&3)*8;
      gl16(qp  + (long)row*NHD + c8, &Qh[hf*2048 + g*512]);
      gl16(qp2 + (long)row*NHD + c8, &Ql[hf*2048 + g*512]);
    }
  }

  f32x4 Oa[4];
  float mrun[4], lrun[4];
  #pragma unroll
  for(int jn=0;jn<4;jn++){ f32x4 zv={0.f,0.f,0.f,0.f}; Oa[jn]=zv; }
  #pragma unroll
  for(int r=0;r<4;r++){ mrun[r]=-3.0e38f; lrun[r]=0.f; }

  const int ktend = (qt>>1)+1;
  for(int kt=0; kt<ktend; kt++){
    __syncthreads();   // prev PV reads of KV done
    // stage K planes [hf][128 key][32]
    {
      const u16* kp = kh_g + ((long)(b*1024+kt*128))*KVD + hk*64;
      const u16* kp2= kl_g + ((long)(b*1024+kt*128))*KVD + hk*64;
      #pragma unroll
      for(int s=0;s<4;s++){
        int idx=s*4+w, hf=idx>>3, g=idx&7;
        int row = g*16 + (lane>>2);
        int c8  = hf*32 + (lane&3)*8;
        gl16(kp  + (long)row*KVD + c8, &KVh[hf*4096 + g*512]);
        gl16(kp2 + (long)row*KVD + c8, &KVl[hf*4096 + g*512]);
      }
    }
    __syncthreads();   // K ready

    // S = Q K^T (split, 3 MFMA): 1 q-frag x 8 key-frags per wave
    f32x4 Sf[8];
    #pragma unroll
    for(int j=0;j<8;j++){ f32x4 zv={0.f,0.f,0.f,0.f}; Sf[j]=zv; }
    #pragma unroll
    for(int k2=0;k2<2;k2++){
      s16x8 ah,al,bh[8],bl[8];
      int q = w*16+rA;
      ah=*(const s16x8*)&Qh[k2*2048 + q*32 + kg];
      al=*(const s16x8*)&Ql[k2*2048 + q*32 + kg];
      #pragma unroll
      for(int j=0;j<8;j++){
        int ky = j*16+rA;
        bh[j]=*(const s16x8*)&KVh[k2*4096 + ky*32 + kg];
        bl[j]=*(const s16x8*)&KVl[k2*4096 + ky*32 + kg];
      }
      #pragma unroll
      for(int j=0;j<8;j++){
        Sf[j]=__builtin_amdgcn_mfma_f32_16x16x32_bf16(ah,bh[j],Sf[j],0,0,0);
        Sf[j]=__builtin_amdgcn_mfma_f32_16x16x32_bf16(ah,bl[j],Sf[j],0,0,0);
        Sf[j]=__builtin_amdgcn_mfma_f32_16x16x32_bf16(al,bh[j],Sf[j],0,0,0);
      }
    }

    // scale + causal mask (last tile only)
    const bool last = (kt==ktend-1);
    #pragma unroll
    for(int j=0;j<8;j++)
      #pragma unroll
      for(int r=0;r<4;r++){
        float sv = Sf[j][r]*0.125f;
        if(last){
          int qr = qt*64 + w*16 + ((lane>>4)<<2) + r;
          int ky = kt*128 + j*16 + (lane&15);
          if(ky>qr) sv = -3.0e38f;
        }
        Sf[j][r]=sv;
      }

    // full-row max
    float mt[4];
    #pragma unroll
    for(int r=0;r<4;r++){
      float v = Sf[0][r];
      #pragma unroll
      for(int j=1;j<8;j++) v = fmaxf(v, Sf[j][r]);
      v=fmaxf(v,__shfl_xor(v,1)); v=fmaxf(v,__shfl_xor(v,2));
      v=fmaxf(v,__shfl_xor(v,4)); v=fmaxf(v,__shfl_xor(v,8));
      mt[r]=v;
    }

    // online update: rescale O, l
    #pragma unroll
    for(int r=0;r<4;r++){
      float mo=mrun[r];
      float mn=fmaxf(mo,mt[r]);
      float al_=__expf(mo-mn);
      mrun[r]=mn;
      lrun[r]*=al_;
      #pragma unroll
      for(int jn=0;jn<4;jn++) Oa[jn][r]*=al_;
    }

    // P = exp(S-m): accumulate l, write split planes to LDS [ks][q][32]
    float ls[4];
    #pragma unroll
    for(int r=0;r<4;r++) ls[r]=0.f;
    #pragma unroll
    for(int j=0;j<8;j++)
      #pragma unroll
      for(int r=0;r<4;r++){
        int q  = w*16+((lane>>4)<<2)+r;
        int ky = j*16+(lane&15);
        float pv=__expf(Sf[j][r]-mrun[r]);
        ls[r]+=pv;
        u16 hv=f2b(pv);
        int a=(ky>>5)*2048 + q*32 + (ky&31);
        Ph[a]=hv; Pl[a]=f2b(pv-b2f(hv));
      }
    #pragma unroll
    for(int r=0;r<4;r++){
      float v=ls[r];
      v+=__shfl_xor(v,1); v+=__shfl_xor(v,2); v+=__shfl_xor(v,4); v+=__shfl_xor(v,8);
      lrun[r]+=v;
    }
    __syncthreads();   // P visible; K reads done -> KV reusable

    // stage V planes [ks][d][32] (reuse KV buffers)
    {
      const u16* vp = vth_g + (long)b*((long)KVD*S_) + (long)(hk*64)*S_ + kt*128;
      const u16* vp2= vtl_g + (long)b*((long)KVD*S_) + (long)(hk*64)*S_ + kt*128;
      #pragma unroll
      for(int s=0;s<4;s++){
        int idx=s*4+w, ks=idx>>2, g=idx&3;
        int dr = g*16 + (lane>>2);
        int k8 = (lane&3)*8;
        gl16(vp  + (long)dr*S_ + ks*32 + k8, &KVh[ks*2048 + g*512]);
        gl16(vp2 + (long)dr*S_ + ks*32 + k8, &KVl[ks*2048 + g*512]);
      }
    }
    __syncthreads();   // V ready

    // O += P·V (split, 3 MFMA)
    #pragma unroll
    for(int ks=0;ks<4;ks++){
      s16x8 pah,pal,vbh[4],vbl[4];
      int q = w*16+rA;
      pah=*(const s16x8*)&Ph[ks*2048 + q*32 + kg];
      pal=*(const s16x8*)&Pl[ks*2048 + q*32 + kg];
      #pragma unroll
      for(int jn=0;jn<4;jn++){
        int d = jn*16+rA;
        vbh[jn]=*(const s16x8*)&KVh[ks*2048 + d*32 + kg];
        vbl[jn]=*(const s16x8*)&KVl[ks*2048 + d*32 + kg];
      }
      #pragma unroll
      for(int jn=0;jn<4;jn++){
        Oa[jn]=__builtin_amdgcn_mfma_f32_16x16x32_bf16(pah,vbh[jn],Oa[jn],0,0,0);
        Oa[jn]=__builtin_amdgcn_mfma_f32_16x16x32_bf16(pah,vbl[jn],Oa[jn],0,0,0);
        Oa[jn]=__builtin_amdgcn_mfma_f32_16x16x32_bf16(pal,vbh[jn],Oa[jn],0,0,0);
      }
    }
  }

  // epilogue: O /= l, split-store to o planes
  #pragma unroll
  for(int jn=0;jn<4;jn++)
    #pragma unroll
    for(int r=0;r<4;r++){
      long t = (long)b*1024 + qt*64 + w*16+((lane>>4)<<2)+r;
      int col = hh*64 + jn*16 + (lane&15);
      float ov = Oa[jn][r] / lrun[r];
      u16 hv=f2b(ov);
      oh_g[t*NHD+col]=hv;
      ol_g[t*NHD+col]=f2b(ov-b2f(hv));
    }
}

// ---------------- fused QKV GEMM (gload staging): x @ [Wq|Wk|Wv] -> split planes ----------------
__global__ __launch_bounds__(256) void k_qkv(
  const u16* __restrict__ xhi, const u16* __restrict__ xlo,
  const u16* __restrict__ Bh, const u16* __restrict__ Bl,
  u16* __restrict__ qhi, u16* __restrict__ qlo,
  u16* __restrict__ khi, u16* __restrict__ klo,
  u16* __restrict__ vthi, u16* __restrict__ vtlo)
{
  constexpr int BK=32;
  __shared__ alignas(16) u16 As[2*128*32], Bs[2*128*32];
  const int m0=blockIdx.x*128, n0=blockIdx.y*128;
  const int tid=threadIdx.x, lane=tid&63, w=tid>>6, wr=w>>1, wc=w&1;
  const int col8 = (lane&3)*8, rsub = lane>>2;
  f32x4 acc[4][4];
  #pragma unroll
  for(int i=0;i<4;i++)
    #pragma unroll
    for(int j=0;j<4;j++){ f32x4 zv={0.f,0.f,0.f,0.f}; acc[i][j]=zv; }

  for(int kt=0;kt<H_/BK;kt++){
    const int k0=kt*BK;
    __syncthreads();
    #pragma unroll
    for(int s=0;s<2;s++){
      int ch = s*4+w; int row = ch*16 + rsub;
      gl16(xhi + (long)(m0+row)*H_ + k0+col8, &As[ch*512]);
      gl16(xlo + (long)(m0+row)*H_ + k0+col8, &As[4096+ch*512]);
      gl16(Bh  + (long)(n0+row)*H_ + k0+col8, &Bs[ch*512]);
      gl16(Bl  + (long)(n0+row)*H_ + k0+col8, &Bs[4096+ch*512]);
    }
    __syncthreads();
    s16x8 ah[4],al[4],bh[4],bl[4];
    const int rA=lane&15, kg=(lane>>4)*8;
    #pragma unroll
    for(int i=0;i<4;i++){
      ah[i]=*(const s16x8*)&As[(wr*64+i*16+rA)*32+kg];
      al[i]=*(const s16x8*)&As[4096+(wr*64+i*16+rA)*32+kg];
    }
    #pragma unroll
    for(int j=0;j<4;j++){
      bh[j]=*(const s16x8*)&Bs[(wc*64+j*16+rA)*32+kg];
      bl[j]=*(const s16x8*)&Bs[4096+(wc*64+j*16+rA)*32+kg];
    }
    #pragma unroll
    for(int i=0;i<4;i++)
      #pragma unroll
      for(int j=0;j<4;j++){
        acc[i][j]=__builtin_amdgcn_mfma_f32_16x16x32_bf16(ah[i],bh[j],acc[i][j],0,0,0);
        acc[i][j]=__builtin_amdgcn_mfma_f32_16x16x32_bf16(ah[i],bl[j],acc[i][j],0,0,0);
        acc[i][j]=__builtin_amdgcn_mfma_f32_16x16x32_bf16(al[i],bh[j],acc[i][j],0,0,0);
      }
  }

  #pragma unroll
  for(int i=0;i<4;i++){
    #pragma unroll
    for(int j=0;j<4;j++){
      const int gm0 = m0 + wr*64 + i*16 + ((lane>>4)<<2);
      const int gn  = n0 + wc*64 + j*16 + (lane&15);
      #pragma unroll
      for(int r=0;r<4;r++){
        const int gm = gm0+r;
        float v = acc[i][j][r];
        u16 hv = f2b(v);
        u16 lv = f2b(v - b2f(hv));
        if(gn < 1024){
          long idx=(long)gm*NHD+gn; qhi[idx]=hv; qlo[idx]=lv;
        } else if(gn < 1536){
          long idx=(long)gm*KVD+(gn-1024); khi[idx]=hv; klo[idx]=lv;
        } else {
          long idx=((long)(gm>>10)<<19) + (long)(gn-1536)*S_ + (gm&1023);
          vthi[idx]=hv; vtlo[idx]=lv;
        }
      }
    }
  }
}

// ---------------- fused MoE up+gate (gload): silu(x@Wg)*(x@Wu) -> gu planes ----------------
__global__ __launch_bounds__(256) void k_moe_ug(
  const u16* __restrict__ xhi, const u16* __restrict__ xlo,
  const u16* __restrict__ Wuh, const u16* __restrict__ Wul,
  const u16* __restrict__ Wgh, const u16* __restrict__ Wgl,
  u16* __restrict__ guh, u16* __restrict__ gul,
  const int* __restrict__ lists, const int* __restrict__ cntp)
{
  constexpr int BK=32;
  const int e = blockIdx.x>>4, m0=(blockIdx.x&15)*128;
  const int ce = cntp[e];
  if(m0>=ce) return;
  const int n0 = blockIdx.y*64;
  const int* ridx = lists + e*T_;
  const u16* Buh_g = Wuh + (size_t)e*H_*I_;
  const u16* Bul_g = Wul + (size_t)e*H_*I_;
  const u16* Bgh_g = Wgh + (size_t)e*H_*I_;
  const u16* Bgl_g = Wgl + (size_t)e*H_*I_;
  __shared__ alignas(16) u16 Ah[128*32], Al[128*32];
  __shared__ alignas(16) u16 Buh[64*32], Bul[64*32], Bgh[64*32], Bgl[64*32];
  const int tid=threadIdx.x, lane=tid&63, w=tid>>6;
  const int wr=w>>1, wc=w&1;
  const int col8=(lane&3)*8, rsub=lane>>2;
  int arA[2];
  #pragma unroll
  for(int s=0;s<2;s++){ int idx=m0 + (s*4+w)*16 + rsub; arA[s]=ridx[idx<ce?idx:ce-1]; }
  const int brow = n0 + w*16 + rsub;
  f32x4 au[4][2], ag[4][2];
  #pragma unroll
  for(int i=0;i<4;i++)
    #pragma unroll
    for(int j=0;j<2;j++){ f32x4 zv={0.f,0.f,0.f,0.f}; au[i][j]=zv; ag[i][j]=zv; }

  for(int kt=0;kt<H_/BK;kt++){
    const int k0=kt*BK;
    __syncthreads();
    #pragma unroll
    for(int s=0;s<2;s++){
      int ch=s*4+w;
      gl16(xhi + (long)arA[s]*H_ + k0+col8, &Ah[ch*512]);
      gl16(xlo + (long)arA[s]*H_ + k0+col8, &Al[ch*512]);
    }
    gl16(Buh_g + (long)brow*H_ + k0+col8, &Buh[w*512]);
    gl16(Bul_g + (long)brow*H_ + k0+col8, &Bul[w*512]);
    gl16(Bgh_g + (long)brow*H_ + k0+col8, &Bgh[w*512]);
    gl16(Bgl_g + (long)brow*H_ + k0+col8, &Bgl[w*512]);
    __syncthreads();
    s16x8 fah[4],fal[4],fbuh[2],fbul[2],fbgh[2],fbgl[2];
    const int rA=lane&15, kg=(lane>>4)*8;
    #pragma unroll
    for(int i=0;i<4;i++){
      fah[i]=*(const s16x8*)&Ah[(wr*64+i*16+rA)*32+kg];
      fal[i]=*(const s16x8*)&Al[(wr*64+i*16+rA)*32+kg];
    }
    #pragma unroll
    for(int j=0;j<2;j++){
      fbuh[j]=*(const s16x8*)&Buh[(wc*32+j*16+rA)*32+kg];
      fbul[j]=*(const s16x8*)&Bul[(wc*32+j*16+rA)*32+kg];
      fbgh[j]=*(const s16x8*)&Bgh[(wc*32+j*16+rA)*32+kg];
      fbgl[j]=*(const s16x8*)&Bgl[(wc*32+j*16+rA)*32+kg];
    }
    #pragma unroll
    for(int i=0;i<4;i++)
      #pragma unroll
      for(int j=0;j<2;j++){
        au[i][j]=__builtin_amdgcn_mfma_f32_16x16x32_bf16(fah[i],fbuh[j],au[i][j],0,0,0);
        au[i][j]=__builtin_amdgcn_mfma_f32_16x16x32_bf16(fah[i],fbul[j],au[i][j],0,0,0);
        au[i][j]=__builtin_amdgcn_mfma_f32_16x16x32_bf16(fal[i],fbuh[j],au[i][j],0,0,0);
        ag[i][j]=__builtin_amdgcn_mfma_f32_16x16x32_bf16(fah[i],fbgh[j],ag[i][j],0,0,0);
        ag[i][j]=__builtin_amdgcn_mfma_f32_16x16x32_bf16(fah[i],fbgl[j],ag[i][j],0,0,0);
        ag[i][j]=__builtin_amdgcn_mfma_f32_16x16x32_bf16(fal[i],fbgh[j],ag[i][j],0,0,0);
      }
  }

  #pragma unroll
  for(int i=0;i<4;i++){
    #pragma unroll
    for(int j=0;j<2;j++){
      const int gm0 = m0 + wr*64 + i*16 + ((lane>>4)<<2);
      const int gn  = n0 + wc*32 + j*16 + (lane&15);
      #pragma unroll
      for(int r=0;r<4;r++){
        const int gm = gm0+r;
        if(gm<ce){
          float uu=au[i][j][r], gg=ag[i][j][r];
          float val = (gg/(1.f+__expf(-gg)))*uu;
          long idx = (long)(e*T_+gm)*I_ + gn;
          u16 hv=f2b(val);
          guh[idx]=hv; gul[idx]=f2b(val-b2f(hv));
        }
      }
    }
  }
}

// ---------------- generic MFMA GEMM (A,B = bf16 planes, gload staging) ----------------
// SPL: bf16x2 split; EPI: 1=f32*scale, 2=f32 +=, 7=f32 compact expert slot,
//      8=f32 via LDS coalesced, 9=split planes; CM: 0/1/2; GATH: 0=dense, 3=expert-slot
// SWZ: XCD-bijective block swizzle (same-n0 blocks colocate per XCD)
template<int BM,int BN,int WM,int WN,bool SPL,int EPI,int CM,int GATH,bool SWZ>
__launch_bounds__(WM*WN*64)
__global__ void k_gemm(const u16* __restrict__ Ahip, const u16* __restrict__ Alop,
                       const u16* __restrict__ Bhip, const u16* __restrict__ Blop,
                       void* __restrict__ Cp, void* __restrict__ auxp,
                       const int* __restrict__ cntp,
                       int Kdim, int lda, int ldb, int ldc,
                       long zA, long zB, int zBdiv, long zC,
                       float scale)
{
  constexpr int NT = WM*WN*64;
  constexpr int Wv = NT/64;
  constexpr int BK = 32;
  constexpr int WMT = BM/WM, WNT = BN/WN;
  constexpr int MF = WMT/16, NF = WNT/16;
  constexpr int ACn = BM/(16*Wv);
  constexpr int BCn = BN/(16*Wv);
  static_assert(ACn>=1 && BCn>=1, "chunks");
  __shared__ alignas(16) u16 As[(SPL?2:1)*BM*32];
  __shared__ alignas(16) u16 Bs[(SPL?2:1)*BN*32];
  __shared__ float Cs[EPI==8?WM:1][EPI==8?16:1][EPI==8?(BN+4):1];
  int m0, n0, eid_ = 0, cnt = 0;
  if constexpr (GATH==3){
    eid_ = blockIdx.x>>4; m0 = (blockIdx.x&15)*BM;
    cnt = cntp[eid_]; if(m0>=cnt) return;
    n0 = blockIdx.y*BN;
  } else if constexpr (SWZ){
    int nx = gridDim.x;
    int l = blockIdx.y*nx + blockIdx.x;
    int q = (nx*gridDim.y)>>3;       // requires nwg % 8 == 0
    int wid = (l&7)*q + (l>>3);
    m0 = (wid % nx)*BM; n0 = (wid / nx)*BN;
  } else {
    m0 = blockIdx.x*BM; n0 = blockIdx.y*BN;
  }
  if (CM==1 && n0 > m0) return;
  const int z = blockIdx.z;
  const int tid = threadIdx.x, lane = tid&63, w = tid>>6;
  const int wr = w/WN, wc = w%WN;
  const int col8 = (lane&3)*8, rsub = lane>>2;
  const u16* Ahi = Ahip + (long)z*zA + (GATH==3 ? (long)eid_*T_*lda : 0);
  const u16* Alo = SPL ? (Alop + (long)z*zA + (GATH==3 ? (long)eid_*T_*lda : 0)) : (const u16*)nullptr;
  const u16* Bh  = Bhip + (long)(z/zBdiv)*zB + (GATH==3 ? (long)eid_*zB : 0);
  const u16* Bl  = SPL ? (Blop + (long)(z/zBdiv)*zB + (GATH==3 ? (long)eid_*zB : 0)) : (const u16*)nullptr;

  f32x4 acc[MF][NF];
  #pragma unroll
  for(int i=0;i<MF;i++)
    #pragma unroll
    for(int j=0;j<NF;j++){ f32x4 zv={0.f,0.f,0.f,0.f}; acc[i][j]=zv; }

  int ktend = Kdim/BK;
  if (CM==2){ int lim=(m0+BM)/BK; if(lim<ktend) ktend=lim; }

  for(int kt=0;kt<ktend;kt++){
    const int k0 = kt*BK;
    __syncthreads();
    #pragma unroll
    for(int s=0;s<ACn;s++){
      int ch = s*Wv + w;
      int arow = m0 + ch*16 + rsub;
      if constexpr (GATH==3){ arow = arow < cnt ? arow : cnt-1; }
      gl16(Ahi + (long)arow*lda + k0+col8, &As[ch*512]);
      if constexpr (SPL) gl16(Alo + (long)arow*lda + k0+col8, &As[BM*32 + ch*512]);
    }
    #pragma unroll
    for(int s=0;s<BCn;s++){
      int ch = s*Wv + w;
      int brow = n0 + ch*16 + rsub;
      gl16(Bh + (long)brow*ldb + k0+col8, &Bs[ch*512]);
      if constexpr (SPL) gl16(Bl + (long)brow*ldb + k0+col8, &Bs[BN*32 + ch*512]);
    }
    __syncthreads();
    s16x8 ah[MF], al[MF], bh[NF], bl[NF];
    const int rA = lane&15, kg=(lane>>4)*8;
    #pragma unroll
    for(int i=0;i<MF;i++){
      ah[i]=*(const s16x8*)&As[(wr*WMT+i*16+rA)*32+kg];
      if constexpr (SPL) al[i]=*(const s16x8*)&As[BM*32+(wr*WMT+i*16+rA)*32+kg];
    }
    #pragma unroll
    for(int j=0;j<NF;j++){
      bh[j]=*(const s16x8*)&Bs[(wc*WNT+j*16+rA)*32+kg];
      if constexpr (SPL) bl[j]=*(const s16x8*)&Bs[BN*32+(wc*WNT+j*16+rA)*32+kg];
    }
    #pragma unroll
    for(int i=0;i<MF;i++)
      #pragma unroll
      for(int j=0;j<NF;j++){
        acc[i][j]=__builtin_amdgcn_mfma_f32_16x16x32_bf16(ah[i],bh[j],acc[i][j],0,0,0);
        if constexpr (SPL){
          acc[i][j]=__builtin_amdgcn_mfma_f32_16x16x32_bf16(ah[i],bl[j],acc[i][j],0,0,0);
          acc[i][j]=__builtin_amdgcn_mfma_f32_16x16x32_bf16(al[i],bh[j],acc[i][j],0,0,0);
        }
      }
  }

  if constexpr (EPI==8){
    float* C = (float*)Cp + (long)z*zC;
    #pragma unroll
    for(int i=0;i<MF;i++){
      __syncthreads();
      #pragma unroll
      for(int j=0;j<NF;j++)
        #pragma unroll
        for(int r=0;r<4;r++)
          Cs[wr][((lane>>4)<<2)+r][wc*WNT + j*16 + (lane&15)] = acc[i][j][r]*scale;
      __syncthreads();
      const int rrow = tid>>3;
      const int wri = rrow>>4, r16 = rrow&15;
      const long gm = m0 + wri*WMT + i*16 + r16;
      #pragma unroll
      for(int s=0;s<BN/32;s++){
        int c0 = ((tid&7) + s*8)*4;
        float4 vv = { Cs[wri][r16][c0], Cs[wri][r16][c0+1], Cs[wri][r16][c0+2], Cs[wri][r16][c0+3] };
        *(float4*)(C + gm*ldc + n0 + c0) = vv;
      }
    }
    return;
  }

  #pragma unroll
  for(int i=0;i<MF;i++){
    #pragma unroll
    for(int j=0;j<NF;j++){
      const int gm0 = m0 + wr*WMT + i*16 + ((lane>>4)<<2);
      const int gn  = n0 + wc*WNT + j*16 + (lane&15);
      #pragma unroll
      for(int r=0;r<4;r++){
        const int gm = gm0+r;
        const float v = acc[i][j][r];
        const bool live = (GATH==0) || (gm < cnt);
        if constexpr (EPI==1){
          if(live) ((float*)Cp + (long)z*zC)[(long)gm*ldc+gn] = v*scale;
        } else if constexpr (EPI==2){
          float* C = (float*)Cp; C[(long)gm*ldc+gn] += v;
        } else if constexpr (EPI==7){
          if(live) ((float*)Cp)[(long)(eid_*T_+gm)*ldc+gn] = v*scale;
        } else if constexpr (EPI==9){
          u16* Ch = (u16*)Cp + (long)z*zC;
          u16* Cl = (u16*)auxp + (long)z*zC;
          long idx = (long)gm*ldc+gn;
          u16 hv = f2b(v);
          Ch[idx]=hv; Cl[idx]=f2b(v-b2f(hv));
        }
      }
    }
  }
}

extern "C" void kernel_launch(void* const* d_in, const int* in_sizes, int n_in,
                              void* d_out, int out_size, void* d_ws, size_t ws_size,
                              hipStream_t stream)
{
  (void)in_sizes; (void)n_in; (void)out_size;
  const int*   ids   = (const int*)d_in[0];
  const float* emb   = (const float*)d_in[1];
  const float* Wq    = (const float*)d_in[2];
  const float* Wk    = (const float*)d_in[3];
  const float* Wv    = (const float*)d_in[4];
  const float* Wo    = (const float*)d_in[5];
  const float* ln1   = (const float*)d_in[6];
  const float* ln2   = (const float*)d_in[7];
  const float* gate  = (const float*)d_in[8];
  const float* Wg    = (const float*)d_in[9];
  const float* Wu    = (const float*)d_in[10];
  const float* Wd    = (const float*)d_in[11];
  const float* normw = (const float*)d_in[12];
  const float* lmh   = (const float*)d_in[13];

  char* p = (char*)d_ws;
  auto carve = [&](size_t bytes)->void*{ void* r=p; p += (bytes+255)&~(size_t)255; return r; };
  float* h    = (float*)carve((size_t)T_*H_*4);
  u16*   xhi  = (u16*)  carve((size_t)T_*H_*2);
  u16*   xlo  = (u16*)  carve((size_t)T_*H_*2);
  u16*   qhi  = (u16*)  carve((size_t)T_*NHD*2);
  u16*   qlo  = (u16*)  carve((size_t)T_*NHD*2);
  u16*   khi  = (u16*)  carve((size_t)T_*KVD*2);
  u16*   klo  = (u16*)  carve((size_t)T_*KVD*2);
  u16*   vthi = (u16*)  carve((size_t)T_*KVD*2);
  u16*   vtlo = (u16*)  carve((size_t)T_*KVD*2);
  u16*   ohi  = (u16*)  carve((size_t)T_*NHD*2);
  u16*   olo  = (u16*)  carve((size_t)T_*NHD*2);
  float* comb = (float*)carve((size_t)T_*4*4);
  int*   cnt  = (int*)  carve((size_t)16*4);
  int*   lists= (int*)  carve((size_t)4*T_*4);
  int2*  epos = (int2*) carve((size_t)T_*8);
  char*  U    = (char*) carve((size_t)112*1024*1024);
  u16*   wp   = (u16*)  carve((size_t)56623104*2);
  if ((size_t)(p - (char*)d_ws) > ws_size) return;

  u16*   guh  = (u16*)U;
  u16*   gul  = (u16*)(U + 33554432);
  float* eo   = (float*)(U + 67108864);

  u16 *WqkvTh = wp,          *WqkvTl = wp+2097152;   // [2048][1024]: q rows 0-1023, k 1024-1535, v 1536-2047
  u16 *WoTh = wp+4194304,    *WoTl = wp+5242880;
  u16 *WgTh = wp+6291456,    *WgTl = wp+14680064;
  u16 *WuTh = wp+23068672,   *WuTl = wp+31457280;
  u16 *WdTh = wp+39845888,   *WdTl = wp+48234496;

  dim3 tb(32,8);

  k_embed<<<T_,256,0,stream>>>(ids, emb, h);
  k_zero<<<1,64,0,stream>>>(cnt);

  for(int l=0;l<4;l++){
    k_wtrans<<<27648,tb,0,stream>>>(
      Wq+(size_t)l*H_*NHD, Wk+(size_t)l*H_*KVD, Wv+(size_t)l*H_*KVD, Wo+(size_t)l*NHD*H_,
      Wg+(size_t)l*4*H_*I_, Wu+(size_t)l*4*H_*I_, Wd+(size_t)l*4*I_*H_,
      WqkvTh, WqkvTl, WoTh, WoTl, WgTh, WgTl, WuTh, WuTl, WdTh, WdTl);

    k_rms_sp<<<T_/4,256,0,stream>>>(h, ln1+(size_t)l*H_, xhi, xlo);

    k_qkv<<<dim3(16,16),256,0,stream>>>(xhi, xlo, WqkvTh, WqkvTl, qhi, qlo, khi, klo, vthi, vtlo);

    // fused flash attention (QBLK=64, 2 blocks/CU)
    k_flash<<<dim3(16,16,2),256,0,stream>>>(qhi, qlo, khi, klo, vthi, vtlo, ohi, olo);

    // o @ Wo += h
    k_gemm<64,128,2,2,true,2,0,0,false><<<dim3(32,8,1),256,0,stream>>>(
      ohi, olo, WoTh, WoTl, h, nullptr, nullptr, NHD, NHD, NHD, H_, 0,0,1,0, 0.f);

    k_router<<<T_/4,256,0,stream>>>(h, ln2+(size_t)l*H_, gate+(size_t)l*H_*4, comb, lists, cnt+l*4, epos);
    k_rms_sp<<<T_/4,256,0,stream>>>(h, ln2+(size_t)l*H_, xhi, xlo);

    k_moe_ug<<<dim3(64,32),256,0,stream>>>(xhi, xlo, WuTh, WuTl, WgTh, WgTl, guh, gul, lists, cnt+l*4);
    k_gemm<128,128,2,2,true,7,0,3,false><<<dim3(64,8),256,0,stream>>>(
      guh, gul, WdTh, WdTl, eo, nullptr, cnt+l*4, I_, I_, I_, H_, 0, (long)I_*H_, 1, 0, 1.f);
    k_combine<<<T_,256,0,stream>>>(h, eo, epos, comb);
  }

  k_rms_sp<<<T_/4,256,0,stream>>>(h, normw, xhi, xlo);
  k_transpose<<<dim3(1000,32),tb,0,stream>>>(lmh, wp, nullptr, H_, V_, 0,0);
  // lm_head: single-plane A, XCD-swizzled for B L2 locality, LDS-coalesced f32 store
  k_gemm<128,128,2,2,false,8,0,0,true><<<dim3(16,250,1),256,0,stream>>>(
    xhi, nullptr, wp, nullptr, (float*)d_out, nullptr, nullptr, H_, H_, H_, V_, 0,0,1,0, 1.f);
}